// Round 8
// baseline (1064.398 us; speedup 1.0000x reference)
//
#include <hip/hip_runtime.h>

#define N_TOK 32768
#define DIM   256
#define NEMB  8192

#define MARGIN_A  0.2f    // f16-MFMA tier: provable-trust margin
#define MARGIN_T2 0.008f  // f16-2split tier: worst-case error ~2e-3 -> 2eps < 0.008
#define MARGIN_B  0.0625f // fp32 tier (path B): flag for f64 refine below this
#define GROUP 8
#define KSPLIT 4

typedef _Float16 f16;
typedef __attribute__((ext_vector_type(4))) _Float16 f16x4;
typedef __attribute__((ext_vector_type(8))) _Float16 f16x8;
typedef __attribute__((ext_vector_type(4))) float     f32x4;

// ---------------------------------------------------------------------------
// Kernel 1: per-code squared norms  enorm[k] = sum_d E[d][k]^2   (f32, exact)
// ---------------------------------------------------------------------------
__global__ void enorm_kernel(const float* __restrict__ E, float* __restrict__ enorm) {
    int k = blockIdx.x * blockDim.x + threadIdx.x;
    float s = 0.f;
#pragma unroll 8
    for (int d = 0; d < DIM; ++d) {
        float e = E[d * NEMB + k];
        s = fmaf(e, e, s);
    }
    enorm[k] = s;
}

// ---------------------------------------------------------------------------
// Kernel 2: transpose E [256][8192] f32 -> ET [8192][256] f16 (hi),
// optional ETlo = f16(E - hi), optional ET32 = f32 transposed copy (gather).
// ---------------------------------------------------------------------------
__global__ __launch_bounds__(256) void cvt3_kernel(const float* __restrict__ E,
                                                   f16* __restrict__ ET,
                                                   f16* __restrict__ ETlo,
                                                   float* __restrict__ ET32,
                                                   int wlo, int wf32) {
    __shared__ float shf[64][65];
    const int tid = threadIdx.x;
    const int k0 = (blockIdx.x & 127) * 64;
    const int d0 = (blockIdx.x >> 7) * 64;
#pragma unroll
    for (int i = 0; i < 16; ++i) {
        int flat = i * 256 + tid;
        int k = flat & 63, d = flat >> 6;
        shf[k][d] = E[(size_t)(d0 + d) * NEMB + k0 + k];   // coalesced in k
    }
    __syncthreads();
#pragma unroll
    for (int i = 0; i < 16; ++i) {
        int flat = i * 256 + tid;
        int d = flat & 63, kk = flat >> 6;
        float v = shf[kk][d];
        f16 hi = (f16)v;
        ET[(size_t)(k0 + kk) * DIM + d0 + d] = hi;               // coalesced in d
        if (wlo)  ETlo[(size_t)(k0 + kk) * DIM + d0 + d] = (f16)(v - (float)hi);
        if (wf32) ET32[(size_t)(k0 + kk) * DIM + d0 + d] = v;
    }
}

// ---------------------------------------------------------------------------
__device__ __forceinline__ void gload_lds16(const void* g, void* l) {
    __builtin_amdgcn_global_load_lds(
        (const __attribute__((address_space(1))) unsigned int*)g,
        (__attribute__((address_space(3))) unsigned int*)l, 16, 0, 0);
}

// ---------------------------------------------------------------------------
// Kernel 3: f16 MFMA GEMM-argmin v6.
// 256 blocks x 1024 thr (16 waves, 4/SIMD).  Code dim split in halves within
// the block: waves 0-7 scan codes [0,4096), waves 8-15 scan [4096,8192), each
// half with its own 2x32KB dbuf (128KB total).  Per wave per barrier: 1 tile
// (32 MFMA) — same math/swizzle as measured-good v4/v5 -> identical scores.
// Merge: shfl_xor butterfly + 12KB LDS cross-(cs,half) merge.
// ---------------------------------------------------------------------------
__global__ __launch_bounds__(1024, 4) void argmin_f16v6_kernel(
        const float* __restrict__ X, const f16* __restrict__ ET,
        const float* __restrict__ enorm,
        int* __restrict__ idx1o, int* __restrict__ idx2o, int* __restrict__ flago) {
    __shared__ char smem[131072];  // half0 dbuf [0,64K); half1 dbuf [64K,128K)

    const int tid  = threadIdx.x;         // 0..1023
    const int w    = tid >> 6;            // wave 0..15
    const int l    = tid & 63;
    const int l15  = l & 15, l4 = l >> 4;
    const int half = w >> 3;              // code half 0/1
    const int w8   = w & 7;
    const int h    = w8 & 1;              // row half (64 rows)
    const int cs   = w8 >> 1;             // code strip (16 codes)
    const int r0   = blockIdx.x * 128;

    // ---- Phase A: stage X rows [r0, r0+128) as f16 [128][256] in LDS ----
    {
        const float4* X4 = (const float4*)(X + (size_t)r0 * DIM);
        f16* xs = (f16*)smem;
#pragma unroll
        for (int i = 0; i < 8; ++i) {
            int flat4 = tid + i * 1024;           // 0..8191
            float4 v = X4[flat4];                 // coalesced
            int row = flat4 >> 6, d4 = flat4 & 63;
            f16x4 p = {(f16)v.x, (f16)v.y, (f16)v.z, (f16)v.w};
            *(f16x4*)(xs + row * 256 + d4 * 4) = p;
        }
    }
    __syncthreads();

    f16x8 Afr[4][8];
    {
        const f16* xs = (const f16*)smem;
#pragma unroll
        for (int mt = 0; mt < 4; ++mt)
#pragma unroll
            for (int c = 0; c < 8; ++c)
                Afr[mt][c] = *(const f16x8*)(xs + (h * 64 + mt * 16 + l15) * 256 + c * 32 + l4 * 8);
    }
    __syncthreads();

    float m1v[4][4], m2v[4][4];
    int   i1v[4][4];
#pragma unroll
    for (int mt = 0; mt < 4; ++mt)
#pragma unroll
        for (int rg = 0; rg < 4; ++rg) {
            m1v[mt][rg] = 3.4e38f; m2v[mt][rg] = 3.4e38f; i1v[mt][rg] = 0x7fffffff;
        }

    // stage tile kt (local 0..63) of this wave's half into buffer buf.
    auto stage = [&](int kt, int buf) {
#pragma unroll
        for (int j = 0; j < 4; ++j) {
            const int code = w8 * 8 + j * 2 + (l >> 5);        // local code 0..63
            const f16* src = ET + ((size_t)(half * 4096 + kt * 64 + code)) * 256
                               + (((l & 31) ^ (code & 7)) << 3);
            char* dst = smem + half * 65536 + buf * 32768 + (w8 * 8 + j * 2) * 512;
            gload_lds16(src, dst);
        }
    };

    const int codeL = cs * 16 + l15;
    stage(0, 0);
    int p = 0;
    for (int kt = 0; kt < 64; ++kt) {
        __syncthreads();                             // buf[p] staged (both halves)
        if (kt + 1 < 64) stage(kt + 1, p ^ 1);

        f32x4 acc[4];
#pragma unroll
        for (int mt = 0; mt < 4; ++mt) acc[mt] = (f32x4){0.f, 0.f, 0.f, 0.f};

        const f16* bb = (const f16*)(smem + half * 65536 + p * 32768);
#pragma unroll
        for (int c = 0; c < 8; ++c) {
            const int g = (c * 4 + l4) ^ (l15 & 7);  // swizzled granule
            f16x8 b = *(const f16x8*)(bb + codeL * 256 + g * 8);
#pragma unroll
            for (int mt = 0; mt < 4; ++mt)
                acc[mt] = __builtin_amdgcn_mfma_f32_16x16x32_f16(Afr[mt][c], b, acc[mt], 0, 0, 0);
        }

        const int code = half * 4096 + kt * 64 + codeL;   // ascending per lane
        const float en = enorm[code];
#pragma unroll
        for (int mt = 0; mt < 4; ++mt)
#pragma unroll
            for (int rg = 0; rg < 4; ++rg) {
                float v = fmaf(-2.f, acc[mt][rg], en);
                bool cl = v < m1v[mt][rg];
                m2v[mt][rg] = fminf(m2v[mt][rg], fmaxf(m1v[mt][rg], v));
                i1v[mt][rg] = cl ? code : i1v[mt][rg];
                m1v[mt][rg] = fminf(m1v[mt][rg], v);
            }
        p ^= 1;
    }

    // ---- merge step 1: shfl_xor butterfly over l15 within 16-lane groups ----
#pragma unroll
    for (int off = 1; off < 16; off <<= 1) {
#pragma unroll
        for (int mt = 0; mt < 4; ++mt)
#pragma unroll
            for (int rg = 0; rg < 4; ++rg) {
                float om1 = __shfl_xor(m1v[mt][rg], off);
                int   oi1 = __shfl_xor(i1v[mt][rg], off);
                float om2 = __shfl_xor(m2v[mt][rg], off);
                bool sw = (om1 < m1v[mt][rg]) ||
                          (om1 == m1v[mt][rg] && oi1 < i1v[mt][rg]);
                float hi = sw ? m1v[mt][rg] : om1;
                m1v[mt][rg] = sw ? om1 : m1v[mt][rg];
                i1v[mt][rg] = sw ? oi1 : i1v[mt][rg];
                m2v[mt][rg] = fminf(fminf(m2v[mt][rg], om2), hi);
            }
    }

    // ---- merge step 2: 12KB LDS cross-(cs,half) merge ----
    __syncthreads();   // all dbuf reads done; safe to alias [0,12K)
    float* sm1 = (float*)smem;              // [128][8]
    int*   si1 = (int*)(smem + 4096);
    float* sm2 = (float*)(smem + 8192);
    if (l15 == 0) {
#pragma unroll
        for (int mt = 0; mt < 4; ++mt)
#pragma unroll
            for (int rg = 0; rg < 4; ++rg) {
                int row = h * 64 + mt * 16 + l4 * 4 + rg;   // 0..127
                int e   = half * 4 + cs;                    // 0..7
                sm1[row * 8 + e] = m1v[mt][rg];
                si1[row * 8 + e] = i1v[mt][rg];
                sm2[row * 8 + e] = m2v[mt][rg];
            }
    }
    __syncthreads();
    if (tid < 128) {
        float M1 = 3.4e38f, M2 = 3.4e38f;
        int   I1 = 0x7fffffff;
#pragma unroll
        for (int e = 0; e < 8; ++e) {
            float v = sm1[tid * 8 + e]; int vi = si1[tid * 8 + e];
            if (v < M1 || (v == M1 && vi < I1)) { M2 = M1; M1 = v; I1 = vi; }
            else M2 = fminf(M2, v);
            M2 = fminf(M2, sm2[tid * 8 + e]);
        }
        int r = r0 + tid;
        idx1o[r] = I1;
        idx2o[r] = I1;
        flago[r] = (M2 - M1 < MARGIN_A) ? -1 : 0;
    }
}

// ---------------------------------------------------------------------------
// Kernel 4: deterministic ordered compaction of flagged (-1) rows.
// ---------------------------------------------------------------------------
__global__ __launch_bounds__(256) void compact_kernel(const int* __restrict__ flago,
        int* __restrict__ list, int* __restrict__ countp) {
    __shared__ int cnts[256], bases[256];
    const int tid = threadIdx.x;
    int c = 0;
    for (int i = 0; i < N_TOK / 256; ++i)
        c += (flago[tid * (N_TOK / 256) + i] < 0) ? 1 : 0;
    cnts[tid] = c;
    __syncthreads();
    if (tid == 0) {
        int run = 0;
        for (int t = 0; t < 256; ++t) { bases[t] = run; run += cnts[t]; }
        countp[0] = run;
    }
    __syncthreads();
    int o = bases[tid];
    for (int i = 0; i < N_TOK / 256; ++i) {
        int r = tid * (N_TOK / 256) + i;
        if (flago[r] < 0) list[o++] = r;
    }
}

// ---------------------------------------------------------------------------
// Kernel 5 (path A): f16 two-split MFMA rescan (top-3 + top-2 idx) — proven.
// ---------------------------------------------------------------------------
__global__ __launch_bounds__(512) void rescan_split_kernel(
        const float* __restrict__ X, const f16* __restrict__ ET,
        const f16* __restrict__ ETlo, const float* __restrict__ enorm,
        const int* __restrict__ list, const int* __restrict__ countp,
        float* __restrict__ pm1, float* __restrict__ pm2, float* __restrict__ pm3,
        int* __restrict__ pi1, int* __restrict__ pi2) {
    __shared__ char smem[131072];
    const int cnt = countp[0];
    const int rb  = blockIdx.x >> 3;
    const int ks  = blockIdx.x & 7;
    if (rb * 64 >= cnt) return;

    const int tid = threadIdx.x, w = tid >> 6, l = tid & 63;
    const int l15 = l & 15, l4 = l >> 4;
    const int h = w & 1, cs = w >> 1;

    f16x8 Ah[2][8], Al[2][8];
#pragma unroll
    for (int mt = 0; mt < 2; ++mt) {
        int jg  = rb * 64 + h * 32 + mt * 16 + l15;
        int row = list[jg < cnt ? jg : cnt - 1];
        const float* xp = X + (size_t)row * DIM + l4 * 8;
#pragma unroll
        for (int c = 0; c < 8; ++c) {
            float4 v0 = *(const float4*)(xp + c * 32);
            float4 v1 = *(const float4*)(xp + c * 32 + 4);
            float xv[8] = {v0.x, v0.y, v0.z, v0.w, v1.x, v1.y, v1.z, v1.w};
            f16x8 hi, lo;
#pragma unroll
            for (int i = 0; i < 8; ++i) {
                f16 hv = (f16)xv[i];
                hi[i] = hv;
                lo[i] = (f16)(xv[i] - (float)hv);
            }
            Ah[mt][c] = hi; Al[mt][c] = lo;
        }
    }

    float m1v[2][4], m2v[2][4], m3v[2][4];
    int   i1v[2][4], i2v[2][4];
#pragma unroll
    for (int mt = 0; mt < 2; ++mt)
#pragma unroll
        for (int rg = 0; rg < 4; ++rg) {
            m1v[mt][rg] = 3.4e38f; m2v[mt][rg] = 3.4e38f; m3v[mt][rg] = 3.4e38f;
            i1v[mt][rg] = 0x7fffffff; i2v[mt][rg] = 0x7fffffff;
        }

    auto stage = [&](int kt, int buf) {        // kt local 0..15
        const int tile = ks * 16 + kt;
#pragma unroll
        for (int j = 0; j < 4; ++j) {
            const int code = w * 8 + j * 2 + (l >> 5);
            size_t off = ((size_t)tile * 64 + code) * 256 + (((l & 31) ^ (code & 7)) << 3);
            char* dsth = smem + buf * 65536 + (w * 8 + j * 2) * 512;
            gload_lds16(ET + off, dsth);
            gload_lds16(ETlo + off, dsth + 32768);
        }
    };

    const int codeL = cs * 16 + l15;
    stage(0, 0);
    int p = 0;
    for (int kt = 0; kt < 16; ++kt) {
        __syncthreads();
        if (kt + 1 < 16) stage(kt + 1, p ^ 1);

        f32x4 acc[2];
#pragma unroll
        for (int mt = 0; mt < 2; ++mt) acc[mt] = (f32x4){0.f, 0.f, 0.f, 0.f};

        const f16* bh = (const f16*)(smem + p * 65536);
        const f16* bl = (const f16*)(smem + p * 65536 + 32768);
#pragma unroll
        for (int c = 0; c < 8; ++c) {
            const int g = (c * 4 + l4) ^ (l15 & 7);
            f16x8 vh = *(const f16x8*)(bh + codeL * 256 + g * 8);
            f16x8 vl = *(const f16x8*)(bl + codeL * 256 + g * 8);
#pragma unroll
            for (int mt = 0; mt < 2; ++mt) {
                acc[mt] = __builtin_amdgcn_mfma_f32_16x16x32_f16(Ah[mt][c], vh, acc[mt], 0, 0, 0);
                acc[mt] = __builtin_amdgcn_mfma_f32_16x16x32_f16(Ah[mt][c], vl, acc[mt], 0, 0, 0);
                acc[mt] = __builtin_amdgcn_mfma_f32_16x16x32_f16(Al[mt][c], vh, acc[mt], 0, 0, 0);
            }
        }

        const int code = (ks * 16 + kt) * 64 + codeL;
        const float en = enorm[code];
#pragma unroll
        for (int mt = 0; mt < 2; ++mt)
#pragma unroll
            for (int rg = 0; rg < 4; ++rg) {
                float v = fmaf(-2.f, acc[mt][rg], en);
                if (v < m1v[mt][rg]) {
                    m3v[mt][rg] = m2v[mt][rg];
                    m2v[mt][rg] = m1v[mt][rg]; i2v[mt][rg] = i1v[mt][rg];
                    m1v[mt][rg] = v;           i1v[mt][rg] = code;
                } else if (v < m2v[mt][rg]) {
                    m3v[mt][rg] = m2v[mt][rg];
                    m2v[mt][rg] = v;           i2v[mt][rg] = code;
                } else if (v < m3v[mt][rg]) {
                    m3v[mt][rg] = v;
                }
            }
        p ^= 1;
    }

    __syncthreads();
    float* Mm1 = (float*)smem;                 // [64][64]
    int*   Mi1 = (int*)(smem + 16384);
    float* Mm2 = (float*)(smem + 32768);
    int*   Mi2 = (int*)(smem + 49152);
    float* Mm3 = (float*)(smem + 65536);
#pragma unroll
    for (int mt = 0; mt < 2; ++mt)
#pragma unroll
        for (int rg = 0; rg < 4; ++rg) {
            int row = h * 32 + mt * 16 + l4 * 4 + rg;   // 0..63
            int e   = cs * 16 + l15;
            Mm1[row * 64 + e] = m1v[mt][rg];
            Mi1[row * 64 + e] = i1v[mt][rg];
            Mm2[row * 64 + e] = m2v[mt][rg];
            Mi2[row * 64 + e] = i2v[mt][rg];
            Mm3[row * 64 + e] = m3v[mt][rg];
        }
    __syncthreads();
    if (tid < 64) {
        float a1 = 3.4e38f, a2 = 3.4e38f, a3 = 3.4e38f;
        int   ai1 = 0x7fffffff, ai2 = 0x7fffffff;
        for (int e = 0; e < 64; ++e) {
            float b1 = Mm1[tid * 64 + e], b2 = Mm2[tid * 64 + e], b3 = Mm3[tid * 64 + e];
            int   bi1 = Mi1[tid * 64 + e], bi2 = Mi2[tid * 64 + e];
            if (b1 < a1 || (b1 == a1 && bi1 < ai1)) { a3 = a2; a2 = a1; ai2 = ai1; a1 = b1; ai1 = bi1; }
            else if (b1 < a2 || (b1 == a2 && bi1 < ai2)) { a3 = a2; a2 = b1; ai2 = bi1; }
            else if (b1 < a3) a3 = b1;
            if (b2 < a1 || (b2 == a1 && bi2 < ai1)) { a3 = a2; a2 = a1; ai2 = ai1; a1 = b2; ai1 = bi2; }
            else if (b2 < a2 || (b2 == a2 && bi2 < ai2)) { a3 = a2; a2 = b2; ai2 = bi2; }
            else if (b2 < a3) a3 = b2;
            if (b3 < a3) a3 = b3;
        }
        int jg = rb * 64 + tid;
        if (jg < cnt) {
            pm1[jg * 8 + ks] = a1; pm2[jg * 8 + ks] = a2; pm3[jg * 8 + ks] = a3;
            pi1[jg * 8 + ks] = ai1; pi2[jg * 8 + ks] = ai2;
        }
    }
}

// ---------------------------------------------------------------------------
// Kernel 6 (path A): merge 8 code-split top-3 partials -> flags 0/1/2.
// ---------------------------------------------------------------------------
__global__ void merge3_kernel(const int* __restrict__ list, const int* __restrict__ countp,
        const float* __restrict__ pm1, const float* __restrict__ pm2,
        const float* __restrict__ pm3,
        const int* __restrict__ pi1, const int* __restrict__ pi2,
        int* __restrict__ idx1o, int* __restrict__ idx2o, int* __restrict__ flago) {
    const int gid = blockIdx.x * 256 + threadIdx.x;
    if (gid >= countp[0]) return;
    float a1 = 3.4e38f, a2 = 3.4e38f, a3 = 3.4e38f;
    int   ai1 = 0x7fffffff, ai2 = 0x7fffffff;
#pragma unroll
    for (int ks = 0; ks < 8; ++ks) {
        float b1 = pm1[gid * 8 + ks], b2 = pm2[gid * 8 + ks], b3 = pm3[gid * 8 + ks];
        int   bi1 = pi1[gid * 8 + ks], bi2 = pi2[gid * 8 + ks];
        if (b1 < a1 || (b1 == a1 && bi1 < ai1)) { a3 = a2; a2 = a1; ai2 = ai1; a1 = b1; ai1 = bi1; }
        else if (b1 < a2 || (b1 == a2 && bi1 < ai2)) { a3 = a2; a2 = b1; ai2 = bi1; }
        else if (b1 < a3) a3 = b1;
        if (b2 < a1 || (b2 == a1 && bi2 < ai1)) { a3 = a2; a2 = a1; ai2 = ai1; a1 = b2; ai1 = bi2; }
        else if (b2 < a2 || (b2 == a2 && bi2 < ai2)) { a3 = a2; a2 = b2; ai2 = bi2; }
        else if (b2 < a3) a3 = b2;
        if (b3 < a3) a3 = b3;
    }
    const int row = list[gid];
    int fl = 0;
    if (a2 - a1 < MARGIN_T2) fl = (a3 - a1 < MARGIN_T2) ? 2 : 1;
    idx1o[row] = ai1; idx2o[row] = ai2; flago[row] = fl;
}

// ---------------------------------------------------------------------------
// Kernel 5B/6B (path B, proven): grouped fp32 rescan + merge.
// ---------------------------------------------------------------------------
__global__ __launch_bounds__(256) void rescan_group_kernel(
        const float* __restrict__ X, const float* __restrict__ E,
        const float* __restrict__ enorm,
        const int* __restrict__ list, const int* __restrict__ countp,
        float* __restrict__ pm1, float* __restrict__ pm2, float* __restrict__ pm3,
        int* __restrict__ pi1, int* __restrict__ pi2) {
    const int cnt = countp[0];
    const int rc  = blockIdx.x >> 2;
    const int ks  = blockIdx.x & 3;
    if (rc * GROUP >= cnt) return;
    const int tid = threadIdx.x;
    __shared__ int rows_s[GROUP];
    __shared__ float sm1[256], sm2[256], sm3[256];
    __shared__ int   si1[256], si2[256];
    if (tid < GROUP) {
        int j = rc * GROUP + tid;
        rows_s[tid] = list[j < cnt ? j : cnt - 1];
    }
    __syncthreads();
    int rowsg[GROUP];
#pragma unroll
    for (int rr = 0; rr < GROUP; ++rr)
        rowsg[rr] = __builtin_amdgcn_readfirstlane(rows_s[rr]);

    float m1[GROUP], m2[GROUP], m3[GROUP];
    int   i1[GROUP], i2[GROUP];
#pragma unroll
    for (int rr = 0; rr < GROUP; ++rr) {
        m1[rr] = 3.4e38f; m2[rr] = 3.4e38f; m3[rr] = 3.4e38f;
        i1[rr] = 0x7fffffff; i2[rr] = 0x7fffffff;
    }
    for (int j = 0; j < 8; ++j) {
        const int k = ks * 2048 + j * 256 + tid;
        float acc[GROUP];
#pragma unroll
        for (int rr = 0; rr < GROUP; ++rr) acc[rr] = 0.f;
#pragma unroll 1
        for (int dc = 0; dc < 8; ++dc) {
            float ev[32];
#pragma unroll
            for (int i = 0; i < 32; ++i) ev[i] = E[(size_t)(dc * 32 + i) * NEMB + k];
#pragma unroll
            for (int rr = 0; rr < GROUP; ++rr) {
                const float* xp = X + (size_t)rowsg[rr] * DIM + dc * 32;
#pragma unroll
                for (int i = 0; i < 32; ++i) acc[rr] = fmaf(ev[i], xp[i], acc[rr]);
            }
        }
        const float en = enorm[k];
#pragma unroll
        for (int rr = 0; rr < GROUP; ++rr) {
            float v = fmaf(-2.f, acc[rr], en);
            if (v < m1[rr])      { m3[rr] = m2[rr]; m2[rr] = m1[rr]; i2[rr] = i1[rr]; m1[rr] = v; i1[rr] = k; }
            else if (v < m2[rr]) { m3[rr] = m2[rr]; m2[rr] = v; i2[rr] = k; }
            else if (v < m3[rr]) { m3[rr] = v; }
        }
    }
#pragma unroll 1
    for (int rr = 0; rr < GROUP; ++rr) {
        sm1[tid] = m1[rr]; sm2[tid] = m2[rr]; sm3[tid] = m3[rr];
        si1[tid] = i1[rr]; si2[tid] = i2[rr];
        __syncthreads();
        for (int st = 128; st > 0; st >>= 1) {
            if (tid < st) {
                float a1 = sm1[tid], a2 = sm2[tid], a3 = sm3[tid];
                int   ai1 = si1[tid], ai2 = si2[tid];
                float b1 = sm1[tid + st], b2 = sm2[tid + st], b3 = sm3[tid + st];
                int   bi1 = si1[tid + st], bi2 = si2[tid + st];
                if (b1 < a1 || (b1 == a1 && bi1 < ai1)) { a3 = a2; a2 = a1; ai2 = ai1; a1 = b1; ai1 = bi1; }
                else if (b1 < a2 || (b1 == a2 && bi1 < ai2)) { a3 = a2; a2 = b1; ai2 = bi1; }
                else if (b1 < a3) a3 = b1;
                if (b2 < a1 || (b2 == a1 && bi2 < ai1)) { a3 = a2; a2 = a1; ai2 = ai1; a1 = b2; ai1 = bi2; }
                else if (b2 < a2 || (b2 == a2 && bi2 < ai2)) { a3 = a2; a2 = b2; ai2 = bi2; }
                else if (b2 < a3) a3 = b2;
                if (b3 < a3) a3 = b3;
                sm1[tid] = a1; sm2[tid] = a2; sm3[tid] = a3; si1[tid] = ai1; si2[tid] = ai2;
            }
            __syncthreads();
        }
        if (tid == 0) {
            int jg = rc * GROUP + rr;
            if (jg < cnt) {
                pm1[jg * KSPLIT + ks] = sm1[0]; pm2[jg * KSPLIT + ks] = sm2[0];
                pm3[jg * KSPLIT + ks] = sm3[0];
                pi1[jg * KSPLIT + ks] = si1[0]; pi2[jg * KSPLIT + ks] = si2[0];
            }
        }
        __syncthreads();
    }
}

__global__ void merge_kernel(const int* __restrict__ list, const int* __restrict__ countp,
        const float* __restrict__ pm1, const float* __restrict__ pm2,
        const float* __restrict__ pm3,
        const int* __restrict__ pi1, const int* __restrict__ pi2,
        int* __restrict__ idx1o, int* __restrict__ idx2o, int* __restrict__ flago) {
    const int gid = blockIdx.x * 256 + threadIdx.x;
    if (gid >= countp[0]) return;
    float a1 = 3.4e38f, a2 = 3.4e38f, a3 = 3.4e38f;
    int   ai1 = 0x7fffffff, ai2 = 0x7fffffff;
#pragma unroll
    for (int ks = 0; ks < KSPLIT; ++ks) {
        float b1 = pm1[gid * KSPLIT + ks], b2 = pm2[gid * KSPLIT + ks], b3 = pm3[gid * KSPLIT + ks];
        int   bi1 = pi1[gid * KSPLIT + ks], bi2 = pi2[gid * KSPLIT + ks];
        if (b1 < a1 || (b1 == a1 && bi1 < ai1)) { a3 = a2; a2 = a1; ai2 = ai1; a1 = b1; ai1 = bi1; }
        else if (b1 < a2 || (b1 == a2 && bi1 < ai2)) { a3 = a2; a2 = b1; ai2 = bi1; }
        else if (b1 < a3) a3 = b1;
        if (b2 < a1 || (b2 == a1 && bi2 < ai1)) { a3 = a2; a2 = a1; ai2 = ai1; a1 = b2; ai1 = bi2; }
        else if (b2 < a2 || (b2 == a2 && bi2 < ai2)) { a3 = a2; a2 = b2; ai2 = bi2; }
        else if (b2 < a3) a3 = b2;
        if (b3 < a3) a3 = b3;
    }
    const int row = list[gid];
    int fl = 0;
    if (a2 - a1 < MARGIN_B) fl = (a3 - a1 < MARGIN_B) ? 2 : 1;
    idx1o[row] = ai1; idx2o[row] = ai2; flago[row] = fl;
}

// ---------------------------------------------------------------------------
// Fallback fp32 argmin (round-1, proven) — used only if ws is tiny.
// ---------------------------------------------------------------------------
#define BM 64
#define BN 128
#define DC 32
#define TM 4
#define TN 8
__global__ __launch_bounds__(256, 2) void argmin_f32_kernel(
        const float* __restrict__ X, const float* __restrict__ E,
        const float* __restrict__ enorm,
        int* __restrict__ idx1o, int* __restrict__ idx2o, int* __restrict__ flago) {
    __shared__ float As[DIM * BM];
    __shared__ float Bs[DC * BN];
    const int tid = threadIdx.x;
    const int r0  = blockIdx.x * BM;
    {
        const float4* X4 = (const float4*)(X + (size_t)r0 * DIM);
#pragma unroll
        for (int i = 0; i < 16; ++i) {
            int flat = tid + i * 256;
            int row = flat >> 6, c4 = flat & 63;
            float4 v = X4[flat];
            int d = c4 * 4;
            As[(d + 0) * BM + row] = v.x;
            As[(d + 1) * BM + row] = v.y;
            As[(d + 2) * BM + row] = v.z;
            As[(d + 3) * BM + row] = v.w;
        }
    }
    const int tc = tid & 15;
    const int tr = tid >> 4;
    float m1[TM], m2[TM], m3[TM];
    int   i1[TM], i2[TM];
#pragma unroll
    for (int j = 0; j < TM; ++j) { m1[j] = m2[j] = m3[j] = 3.4e38f; i1[j] = i2[j] = 0x7fffffff; }
    for (int kt = 0; kt < NEMB; kt += BN) {
        float acc[TM][TN];
#pragma unroll
        for (int j = 0; j < TM; ++j)
#pragma unroll
            for (int i = 0; i < TN; ++i) acc[j][i] = 0.f;
        for (int dc = 0; dc < DIM; dc += DC) {
            __syncthreads();
            const float4* E4 = (const float4*)E;
#pragma unroll
            for (int i = 0; i < 4; ++i) {
                int flat = tid + i * 256;
                int dd = flat >> 5, k4 = flat & 31;
                float4 v = E4[(size_t)(dc + dd) * (NEMB / 4) + (kt >> 2) + k4];
                *(float4*)&Bs[dd * BN + k4 * 4] = v;
            }
            __syncthreads();
#pragma unroll
            for (int dd = 0; dd < DC; ++dd) {
                float4 av = *(const float4*)&As[(dc + dd) * BM + tr * TM];
                float4 b0 = *(const float4*)&Bs[dd * BN + tc * TN];
                float4 b1 = *(const float4*)&Bs[dd * BN + tc * TN + 4];
                float a[TM] = {av.x, av.y, av.z, av.w};
                float b[TN] = {b0.x, b0.y, b0.z, b0.w, b1.x, b1.y, b1.z, b1.w};
#pragma unroll
                for (int j = 0; j < TM; ++j)
#pragma unroll
                    for (int i = 0; i < TN; ++i)
                        acc[j][i] = fmaf(a[j], b[i], acc[j][i]);
            }
        }
        float4 e0 = *(const float4*)&enorm[kt + tc * TN];
        float4 e1 = *(const float4*)&enorm[kt + tc * TN + 4];
        float en[TN] = {e0.x, e0.y, e0.z, e0.w, e1.x, e1.y, e1.z, e1.w};
#pragma unroll
        for (int j = 0; j < TM; ++j) {
#pragma unroll
            for (int i = 0; i < TN; ++i) {
                float v = en[i] - 2.f * acc[j][i];
                int k = kt + tc * TN + i;
                if (v < m1[j]) { m3[j] = m2[j]; m2[j] = m1[j]; i2[j] = i1[j]; m1[j] = v; i1[j] = k; }
                else if (v < m2[j]) { m3[j] = m2[j]; m2[j] = v; i2[j] = k; }
                else if (v < m3[j]) { m3[j] = v; }
            }
        }
    }
    __syncthreads();
    float* Mm1 = As;
    float* Mm2 = As + 1024;
    float* Mm3 = As + 2048;
    int*   Mi1 = (int*)(As + 3072);
    int*   Mi2 = (int*)(As + 4096);
#pragma unroll
    for (int j = 0; j < TM; ++j) {
        int row = tr * TM + j;
        Mm1[row * 16 + tc] = m1[j];
        Mm2[row * 16 + tc] = m2[j];
        Mm3[row * 16 + tc] = m3[j];
        Mi1[row * 16 + tc] = i1[j];
        Mi2[row * 16 + tc] = i2[j];
    }
    __syncthreads();
    if (tid < BM) {
        float M1 = 3.4e38f, M2 = 3.4e38f, M3 = 3.4e38f;
        int I1 = 0x7fffffff, I2 = 0x7fffffff;
        for (int e = 0; e < 16; ++e) {
            float v = Mm1[tid * 16 + e]; int vi = Mi1[tid * 16 + e];
            if (v < M1 || (v == M1 && vi < I1)) { M3 = M2; M2 = M1; I2 = I1; M1 = v; I1 = vi; }
            else if (v < M2 || (v == M2 && vi < I2)) { M3 = M2; M2 = v; I2 = vi; }
            else if (v < M3) { M3 = v; }
            v = Mm2[tid * 16 + e]; vi = Mi2[tid * 16 + e];
            if (v < M1 || (v == M1 && vi < I1)) { M3 = M2; M2 = M1; I2 = I1; M1 = v; I1 = vi; }
            else if (v < M2 || (v == M2 && vi < I2)) { M3 = M2; M2 = v; I2 = vi; }
            else if (v < M3) { M3 = v; }
            v = Mm3[tid * 16 + e];
            if (v < M3) M3 = v;
        }
        int r = r0 + tid;
        int fl = 0;
        if (M2 - M1 < MARGIN_B) fl = (M3 - M1 < MARGIN_B) ? 2 : 1;
        idx1o[r] = I1; idx2o[r] = I2; flago[r] = fl;
    }
}

// ---------------------------------------------------------------------------
// Kernel 7: f64 refinement (flag 1 = 2-candidate, 2 = full row rescan).
// ---------------------------------------------------------------------------
__global__ __launch_bounds__(256) void refine_kernel(
        const float* __restrict__ X, const float* __restrict__ E,
        int* __restrict__ idx1o, const int* __restrict__ idx2o,
        const int* __restrict__ flago) {
    __shared__ double redA[256];
    __shared__ double redB[256];
    __shared__ int    redI[256];
    const int tid = threadIdx.x;
    for (int rr = 0; rr < 8; ++rr) {
        int r = blockIdx.x * 8 + rr;
        int flag = flago[r];
        if (flag == 0) continue;
        if (flag == 1) {
            int a = idx1o[r], b = idx2o[r];
            double x  = (double)X[(size_t)r * DIM + tid];
            double ea = (double)E[(size_t)tid * NEMB + a];
            double eb = (double)E[(size_t)tid * NEMB + b];
            redA[tid] = ea * (ea - 2.0 * x);
            redB[tid] = eb * (eb - 2.0 * x);
            __syncthreads();
            for (int s = 128; s > 0; s >>= 1) {
                if (tid < s) { redA[tid] += redA[tid + s]; redB[tid] += redB[tid + s]; }
                __syncthreads();
            }
            if (tid == 0) {
                double sa = redA[0], sb = redB[0];
                idx1o[r] = (sb < sa || (sb == sa && b < a)) ? b : a;
            }
            __syncthreads();
        } else {
            double bm = 1e300; int bi = 0x7fffffff;
            for (int k = tid; k < NEMB; k += 256) {
                double s = 0.0;
                for (int d = 0; d < DIM; ++d) {
                    double e = (double)E[(size_t)d * NEMB + k];
                    double x = (double)X[(size_t)r * DIM + d];
                    s += e * (e - 2.0 * x);
                }
                if (s < bm) { bm = s; bi = k; }
            }
            redA[tid] = bm; redI[tid] = bi;
            __syncthreads();
            for (int s = 128; s > 0; s >>= 1) {
                if (tid < s) {
                    if (redA[tid + s] < redA[tid] ||
                        (redA[tid + s] == redA[tid] && redI[tid + s] < redI[tid])) {
                        redA[tid] = redA[tid + s]; redI[tid] = redI[tid + s];
                    }
                }
                __syncthreads();
            }
            if (tid == 0) idx1o[r] = redI[0];
            __syncthreads();
        }
    }
}

// ---------------------------------------------------------------------------
// Kernel 8: gather + loss partials.  v1: strided E columns (fallback).
// ---------------------------------------------------------------------------
__global__ __launch_bounds__(256) void gather_kernel(
        const float* __restrict__ X, const float* __restrict__ E,
        const int* __restrict__ idx,
        float* __restrict__ outq, float* __restrict__ outidxf,
        double* __restrict__ partials) {
    __shared__ double red[256];
    const int tid = threadIdx.x;
    const int row = blockIdx.x * 4 + (tid >> 6);
    const int d0  = (tid & 63) * 4;
    const int k   = idx[row];
    float4 x = *(const float4*)&X[(size_t)row * DIM + d0];
    float q0 = E[(size_t)(d0 + 0) * NEMB + k];
    float q1 = E[(size_t)(d0 + 1) * NEMB + k];
    float q2 = E[(size_t)(d0 + 2) * NEMB + k];
    float q3 = E[(size_t)(d0 + 3) * NEMB + k];
    float4 q = {q0, q1, q2, q3};
    *(float4*)&outq[(size_t)row * DIM + d0] = q;
    if ((tid & 63) == 0) outidxf[row] = (float)k;
    double s = 0.0, t;
    t = (double)q0 - (double)x.x; s += t * t;
    t = (double)q1 - (double)x.y; s += t * t;
    t = (double)q2 - (double)x.z; s += t * t;
    t = (double)q3 - (double)x.w; s += t * t;
    red[tid] = s;
    __syncthreads();
    for (int st = 128; st > 0; st >>= 1) {
        if (tid < st) red[tid] += red[tid + st];
        __syncthreads();
    }
    if (tid == 0) partials[blockIdx.x] = red[0];
}

// v2: coalesced reads from transposed f32 copy ET32 [8192][256].
__global__ __launch_bounds__(256) void gather2_kernel(
        const float* __restrict__ X, const float* __restrict__ ET32,
        const int* __restrict__ idx,
        float* __restrict__ outq, float* __restrict__ outidxf,
        double* __restrict__ partials) {
    __shared__ double red[256];
    const int tid = threadIdx.x;
    const int row = blockIdx.x * 4 + (tid >> 6);
    const int d0  = (tid & 63) * 4;
    const int k   = idx[row];
    float4 x = *(const float4*)&X[(size_t)row * DIM + d0];
    float4 q = *(const float4*)&ET32[(size_t)k * DIM + d0];   // coalesced row read
    *(float4*)&outq[(size_t)row * DIM + d0] = q;
    if ((tid & 63) == 0) outidxf[row] = (float)k;
    double s = 0.0, t;
    t = (double)q.x - (double)x.x; s += t * t;
    t = (double)q.y - (double)x.y; s += t * t;
    t = (double)q.z - (double)x.z; s += t * t;
    t = (double)q.w - (double)x.w; s += t * t;
    red[tid] = s;
    __syncthreads();
    for (int st = 128; st > 0; st >>= 1) {
        if (tid < st) red[tid] += red[tid + st];
        __syncthreads();
    }
    if (tid == 0) partials[blockIdx.x] = red[0];
}

// ---------------------------------------------------------------------------
// Kernel 9: deterministic final loss reduction.
// ---------------------------------------------------------------------------
__global__ __launch_bounds__(256) void loss_kernel(const double* __restrict__ partials,
                                                   float* __restrict__ outloss) {
    __shared__ double red[256];
    const int tid = threadIdx.x;
    double s = 0.0;
    for (int i = tid; i < N_TOK / 4; i += 256) s += partials[i];
    red[tid] = s;
    __syncthreads();
    for (int st = 128; st > 0; st >>= 1) {
        if (tid < st) red[tid] += red[tid + st];
        __syncthreads();
    }
    if (tid == 0)
        outloss[0] = (float)(0.25 * red[0] / (double)((size_t)N_TOK * DIM));
}

// ---------------------------------------------------------------------------
extern "C" void kernel_launch(void* const* d_in, const int* in_sizes, int n_in,
                              void* d_out, int out_size, void* d_ws, size_t ws_size,
                              hipStream_t stream) {
    const float* X = (const float*)d_in[0];   // [32768, 256]
    const float* E = (const float*)d_in[1];   // [256, 8192]

    float* outq    = (float*)d_out;
    float* outloss = outq + (size_t)N_TOK * DIM;
    float* outidx  = outloss + 1;

    char* base = (char*)d_ws;
    float*  enorm    = (float*)base;                          // 32 KB
    int*    idx1     = (int*)(base + 32768);                  // 128 KB
    int*    idx2     = (int*)(base + 163840);                 // 128 KB
    int*    flag     = (int*)(base + 294912);                 // 128 KB
    double* partials = (double*)(base + 425984);              // 64 KB
    f16*    ET       = (f16*)(base + 524288);                 // 4 MB
    // path B aliases (overlay ET region post-argmin)
    char*   etbase   = base + 524288;
    int*    listB    = (int*)etbase;
    int*    countB   = (int*)(etbase + 131072);
    float*  pm1B     = (float*)(etbase + 132096);
    float*  pm2B     = (float*)(etbase + 132096 + 524288);
    float*  pm3B     = (float*)(etbase + 132096 + 1048576);
    int*    pi1B     = (int*)  (etbase + 132096 + 1572864);
    int*    pi2B     = (int*)  (etbase + 132096 + 2097152);
    // path A extras
    f16*    ETlo     = (f16*)(base + 4718592);                // 4 MB
    int*    listA    = (int*)(base + 8912896);                // 128 KB
    int*    countA   = (int*)(base + 9043968);                // 1 KB
    float*  ET32     = (float*)(base + 9044992);              // 8 MB (optional)
    // path A partial top-3 arrays: scratch in d_out's outq region (32 MB,
    // overwritten by gather afterwards).
    float*  pm1A     = outq;
    float*  pm2A     = outq + 262144;
    float*  pm3A     = outq + 524288;
    int*    pi1A     = (int*)(outq + 786432);
    int*    pi2A     = (int*)(outq + 1048576);
    const size_t NEED_B  = 4718592;
    const size_t NEED_A  = 12190720;
    const size_t NEED_A2 = 9044992 + (size_t)NEMB * DIM * sizeof(float); // 17433600

    enorm_kernel<<<NEMB / 256, 256, 0, stream>>>(E, enorm);
    if (ws_size >= NEED_A) {
        const int wf32 = (ws_size >= NEED_A2) ? 1 : 0;
        cvt3_kernel        <<<512,        256, 0, stream>>>(E, ET, ETlo, ET32, 1, wf32);
        argmin_f16v6_kernel<<<N_TOK / 128, 1024, 0, stream>>>(X, ET, enorm, idx1, idx2, flag);
        compact_kernel     <<<1,          256, 0, stream>>>(flag, listA, countA);
        rescan_split_kernel<<<512 * 8,    512, 0, stream>>>(X, ET, ETlo, enorm, listA, countA,
                                                            pm1A, pm2A, pm3A, pi1A, pi2A);
        merge3_kernel      <<<N_TOK / 256, 256, 0, stream>>>(listA, countA, pm1A, pm2A, pm3A,
                                                             pi1A, pi2A, idx1, idx2, flag);
        refine_kernel<<<N_TOK / 8, 256, 0, stream>>>(X, E, idx1, idx2, flag);
        if (wf32)
            gather2_kernel<<<N_TOK / 4, 256, 0, stream>>>(X, ET32, idx1, outq, outidx, partials);
        else
            gather_kernel <<<N_TOK / 4, 256, 0, stream>>>(X, E, idx1, outq, outidx, partials);
    } else if (ws_size >= NEED_B) {
        cvt3_kernel        <<<512,        256, 0, stream>>>(E, ET, ET, (float*)ET, 0, 0);
        argmin_f16v6_kernel<<<N_TOK / 128, 1024, 0, stream>>>(X, ET, enorm, idx1, idx2, flag);
        compact_kernel     <<<1,          256, 0, stream>>>(flag, listB, countB);
        rescan_group_kernel<<<(N_TOK / GROUP) * KSPLIT, 256, 0, stream>>>(X, E, enorm, listB, countB,
                                                                          pm1B, pm2B, pm3B, pi1B, pi2B);
        merge_kernel       <<<N_TOK / 256, 256, 0, stream>>>(listB, countB, pm1B, pm2B, pm3B,
                                                             pi1B, pi2B, idx1, idx2, flag);
        refine_kernel<<<N_TOK / 8, 256, 0, stream>>>(X, E, idx1, idx2, flag);
        gather_kernel<<<N_TOK / 4, 256, 0, stream>>>(X, E, idx1, outq, outidx, partials);
    } else {
        argmin_f32_kernel  <<<N_TOK / BM, 256, 0, stream>>>(X, E, enorm, idx1, idx2, flag);
        refine_kernel<<<N_TOK / 8, 256, 0, stream>>>(X, E, idx1, idx2, flag);
        gather_kernel<<<N_TOK / 4, 256, 0, stream>>>(X, E, idx1, outq, outidx, partials);
    }
    loss_kernel  <<<1,         256, 0, stream>>>(partials, outloss);
}

// Round 9
// 373.878 us; speedup vs baseline: 2.8469x; 2.8469x over previous
//
#include <hip/hip_runtime.h>

#define N_TOK 32768
#define DIM   256
#define NEMB  8192

#define MARGIN_A  0.2f    // f16-MFMA tier: provable-trust margin
#define MARGIN_T2 0.008f  // f16-2split tier: worst-case error ~2e-3 -> 2eps < 0.008
#define MARGIN_B  0.0625f // fp32 tier (path B): flag for f64 refine below this
#define GROUP 8
#define KSPLIT 4

typedef _Float16 f16;
typedef __attribute__((ext_vector_type(4))) _Float16 f16x4;
typedef __attribute__((ext_vector_type(8))) _Float16 f16x8;
typedef __attribute__((ext_vector_type(4))) float     f32x4;

// ---------------------------------------------------------------------------
// Kernel 1: per-code squared norms  enorm[k] = sum_d E[d][k]^2   (f32, exact)
// ---------------------------------------------------------------------------
__global__ void enorm_kernel(const float* __restrict__ E, float* __restrict__ enorm) {
    int k = blockIdx.x * blockDim.x + threadIdx.x;
    float s = 0.f;
#pragma unroll 8
    for (int d = 0; d < DIM; ++d) {
        float e = E[d * NEMB + k];
        s = fmaf(e, e, s);
    }
    enorm[k] = s;
}

// ---------------------------------------------------------------------------
// Kernel 2: transpose E [256][8192] f32 -> ET [8192][256] f16 (hi),
// optional ETlo = f16(E - hi), optional ET32 = f32 transposed copy (gather).
// ---------------------------------------------------------------------------
__global__ __launch_bounds__(256) void cvt3_kernel(const float* __restrict__ E,
                                                   f16* __restrict__ ET,
                                                   f16* __restrict__ ETlo,
                                                   float* __restrict__ ET32,
                                                   int wlo, int wf32) {
    __shared__ float shf[64][65];
    const int tid = threadIdx.x;
    const int k0 = (blockIdx.x & 127) * 64;
    const int d0 = (blockIdx.x >> 7) * 64;
#pragma unroll
    for (int i = 0; i < 16; ++i) {
        int flat = i * 256 + tid;
        int k = flat & 63, d = flat >> 6;
        shf[k][d] = E[(size_t)(d0 + d) * NEMB + k0 + k];   // coalesced in k
    }
    __syncthreads();
#pragma unroll
    for (int i = 0; i < 16; ++i) {
        int flat = i * 256 + tid;
        int d = flat & 63, kk = flat >> 6;
        float v = shf[kk][d];
        f16 hi = (f16)v;
        ET[(size_t)(k0 + kk) * DIM + d0 + d] = hi;               // coalesced in d
        if (wlo)  ETlo[(size_t)(k0 + kk) * DIM + d0 + d] = (f16)(v - (float)hi);
        if (wf32) ET32[(size_t)(k0 + kk) * DIM + d0 + d] = v;
    }
}

// ---------------------------------------------------------------------------
__device__ __forceinline__ void gload_lds16(const void* g, void* l) {
    __builtin_amdgcn_global_load_lds(
        (const __attribute__((address_space(1))) unsigned int*)g,
        (__attribute__((address_space(3))) unsigned int*)l, 16, 0, 0);
}

// ---------------------------------------------------------------------------
// Kernel 3: f16 MFMA GEMM-argmin v7.
// 512 blocks x 512 thr (8 waves).  BM=64 rows/block, mt=2 -> Afr[2][8] = 64
// VGPRs (total live ~115 <= 128 cap from launch_bounds(512,2) under observed
// CUDA-semantics arg2).  LDS 64KB (X-stage aliases dbuf) -> 2 blocks/CU = 4
// waves/SIMD; independent per-block barriers overlap stalls across blocks.
// Tile/swizzle/epilogue/merge math identical to proven v4/v5.
// ---------------------------------------------------------------------------
__global__ __launch_bounds__(512, 2) void argmin_f16v7_kernel(
        const float* __restrict__ X, const f16* __restrict__ ET,
        const float* __restrict__ enorm,
        int* __restrict__ idx1o, int* __restrict__ idx2o, int* __restrict__ flago) {
    __shared__ char smem[65536];   // dbuf 2x32KB; X-stage aliases [0,32K)

    const int tid = threadIdx.x;          // 0..511
    const int w   = tid >> 6;             // wave 0..7
    const int l   = tid & 63;
    const int l15 = l & 15, l4 = l >> 4;
    const int h   = w & 1;                // row half (32 rows)
    const int cs  = w >> 1;               // code strip (16 codes)
    const int r0  = blockIdx.x * 64;

    // ---- Phase A: stage X rows [r0, r0+64) as f16 [64][256] in LDS ----
    // 64 rows x 64 float4/row = 4096 float4; 512 thr -> 8 iterations.
    {
        const float4* X4 = (const float4*)(X + (size_t)r0 * DIM);
        f16* xs = (f16*)smem;
#pragma unroll
        for (int i = 0; i < 8; ++i) {
            int flat4 = tid + i * 512;            // 0..4095
            float4 v = X4[flat4];                 // coalesced
            int row = flat4 >> 6, d4 = flat4 & 63;
            f16x4 p = {(f16)v.x, (f16)v.y, (f16)v.z, (f16)v.w};
            *(f16x4*)(xs + row * 256 + d4 * 4) = p;
        }
    }
    __syncthreads();

    // ---- A fragments: rows r0 + h*32 + mt*16 + l15 ----
    f16x8 Afr[2][8];
    {
        const f16* xs = (const f16*)smem;
#pragma unroll
        for (int mt = 0; mt < 2; ++mt)
#pragma unroll
            for (int c = 0; c < 8; ++c)
                Afr[mt][c] = *(const f16x8*)(xs + (h * 32 + mt * 16 + l15) * 256 + c * 32 + l4 * 8);
    }
    __syncthreads();   // X region free; dbuf may now overwrite it

    float m1v[2][4], m2v[2][4];
    int   i1v[2][4];
#pragma unroll
    for (int mt = 0; mt < 2; ++mt)
#pragma unroll
        for (int rg = 0; rg < 4; ++rg) {
            m1v[mt][rg] = 3.4e38f; m2v[mt][rg] = 3.4e38f; i1v[mt][rg] = 0x7fffffff;
        }

    // stage tile kt (64 codes x 256 dims = 32KB): wave w stages codes
    // [w*8, w*8+8) as 4 calls x 2 code rows (1KB each), XOR-(code&7) swizzle.
    auto stage = [&](int kt, int buf) {
#pragma unroll
        for (int j = 0; j < 4; ++j) {
            const int code = w * 8 + j * 2 + (l >> 5);         // local code 0..63
            const f16* src = ET + ((size_t)kt * 64 + code) * 256
                               + (((l & 31) ^ (code & 7)) << 3);
            char* dst = smem + buf * 32768 + (w * 8 + j * 2) * 512;  // wave-uniform
            gload_lds16(src, dst);
        }
    };

    const int codeL = cs * 16 + l15;
    stage(0, 0);
    int p = 0;
    for (int kt = 0; kt < 128; ++kt) {
        __syncthreads();                             // buf[p] staged
        if (kt + 1 < 128) stage(kt + 1, p ^ 1);

        f32x4 acc[2];
#pragma unroll
        for (int mt = 0; mt < 2; ++mt) acc[mt] = (f32x4){0.f, 0.f, 0.f, 0.f};

        const f16* bb = (const f16*)(smem + p * 32768);
#pragma unroll
        for (int c = 0; c < 8; ++c) {
            const int g = (c * 4 + l4) ^ (l15 & 7);  // swizzled granule
            f16x8 b = *(const f16x8*)(bb + codeL * 256 + g * 8);
#pragma unroll
            for (int mt = 0; mt < 2; ++mt)
                acc[mt] = __builtin_amdgcn_mfma_f32_16x16x32_f16(Afr[mt][c], b, acc[mt], 0, 0, 0);
        }

        const int code = kt * 64 + codeL;            // ascending per lane
        const float en = enorm[code];
#pragma unroll
        for (int mt = 0; mt < 2; ++mt)
#pragma unroll
            for (int rg = 0; rg < 4; ++rg) {
                float v = fmaf(-2.f, acc[mt][rg], en);
                bool cl = v < m1v[mt][rg];
                m2v[mt][rg] = fminf(m2v[mt][rg], fmaxf(m1v[mt][rg], v));
                i1v[mt][rg] = cl ? code : i1v[mt][rg];
                m1v[mt][rg] = fminf(m1v[mt][rg], v);
            }
        p ^= 1;
    }

    // ---- merge step 1: shfl_xor butterfly over l15 within 16-lane groups ----
#pragma unroll
    for (int off = 1; off < 16; off <<= 1) {
#pragma unroll
        for (int mt = 0; mt < 2; ++mt)
#pragma unroll
            for (int rg = 0; rg < 4; ++rg) {
                float om1 = __shfl_xor(m1v[mt][rg], off);
                int   oi1 = __shfl_xor(i1v[mt][rg], off);
                float om2 = __shfl_xor(m2v[mt][rg], off);
                bool sw = (om1 < m1v[mt][rg]) ||
                          (om1 == m1v[mt][rg] && oi1 < i1v[mt][rg]);
                float hi = sw ? m1v[mt][rg] : om1;
                m1v[mt][rg] = sw ? om1 : m1v[mt][rg];
                i1v[mt][rg] = sw ? oi1 : i1v[mt][rg];
                m2v[mt][rg] = fminf(fminf(m2v[mt][rg], om2), hi);
            }
    }

    // ---- merge step 2: 3KB LDS cross-strip (4 cs) merge ----
    __syncthreads();   // all dbuf reads done; safe to alias [0,3K)
    float* sm1 = (float*)smem;              // [64][4]
    int*   si1 = (int*)(smem + 1024);
    float* sm2 = (float*)(smem + 2048);
    if (l15 == 0) {
#pragma unroll
        for (int mt = 0; mt < 2; ++mt)
#pragma unroll
            for (int rg = 0; rg < 4; ++rg) {
                int row = h * 32 + mt * 16 + l4 * 4 + rg;   // 0..63
                sm1[row * 4 + cs] = m1v[mt][rg];
                si1[row * 4 + cs] = i1v[mt][rg];
                sm2[row * 4 + cs] = m2v[mt][rg];
            }
    }
    __syncthreads();
    if (tid < 64) {
        float M1 = 3.4e38f, M2 = 3.4e38f;
        int   I1 = 0x7fffffff;
#pragma unroll
        for (int e = 0; e < 4; ++e) {
            float v = sm1[tid * 4 + e]; int vi = si1[tid * 4 + e];
            if (v < M1 || (v == M1 && vi < I1)) { M2 = M1; M1 = v; I1 = vi; }
            else M2 = fminf(M2, v);
            M2 = fminf(M2, sm2[tid * 4 + e]);
        }
        int r = r0 + tid;
        idx1o[r] = I1;
        idx2o[r] = I1;
        flago[r] = (M2 - M1 < MARGIN_A) ? -1 : 0;
    }
}

// ---------------------------------------------------------------------------
// Kernel 4: deterministic ordered compaction of flagged (-1) rows.
// ---------------------------------------------------------------------------
__global__ __launch_bounds__(256) void compact_kernel(const int* __restrict__ flago,
        int* __restrict__ list, int* __restrict__ countp) {
    __shared__ int cnts[256], bases[256];
    const int tid = threadIdx.x;
    int c = 0;
    for (int i = 0; i < N_TOK / 256; ++i)
        c += (flago[tid * (N_TOK / 256) + i] < 0) ? 1 : 0;
    cnts[tid] = c;
    __syncthreads();
    if (tid == 0) {
        int run = 0;
        for (int t = 0; t < 256; ++t) { bases[t] = run; run += cnts[t]; }
        countp[0] = run;
    }
    __syncthreads();
    int o = bases[tid];
    for (int i = 0; i < N_TOK / 256; ++i) {
        int r = tid * (N_TOK / 256) + i;
        if (flago[r] < 0) list[o++] = r;
    }
}

// ---------------------------------------------------------------------------
// Kernel 5 (path A): f16 two-split MFMA rescan (top-3 + top-2 idx) — proven.
// ---------------------------------------------------------------------------
__global__ __launch_bounds__(512) void rescan_split_kernel(
        const float* __restrict__ X, const f16* __restrict__ ET,
        const f16* __restrict__ ETlo, const float* __restrict__ enorm,
        const int* __restrict__ list, const int* __restrict__ countp,
        float* __restrict__ pm1, float* __restrict__ pm2, float* __restrict__ pm3,
        int* __restrict__ pi1, int* __restrict__ pi2) {
    __shared__ char smem[131072];
    const int cnt = countp[0];
    const int rb  = blockIdx.x >> 3;
    const int ks  = blockIdx.x & 7;
    if (rb * 64 >= cnt) return;

    const int tid = threadIdx.x, w = tid >> 6, l = tid & 63;
    const int l15 = l & 15, l4 = l >> 4;
    const int h = w & 1, cs = w >> 1;

    f16x8 Ah[2][8], Al[2][8];
#pragma unroll
    for (int mt = 0; mt < 2; ++mt) {
        int jg  = rb * 64 + h * 32 + mt * 16 + l15;
        int row = list[jg < cnt ? jg : cnt - 1];
        const float* xp = X + (size_t)row * DIM + l4 * 8;
#pragma unroll
        for (int c = 0; c < 8; ++c) {
            float4 v0 = *(const float4*)(xp + c * 32);
            float4 v1 = *(const float4*)(xp + c * 32 + 4);
            float xv[8] = {v0.x, v0.y, v0.z, v0.w, v1.x, v1.y, v1.z, v1.w};
            f16x8 hi, lo;
#pragma unroll
            for (int i = 0; i < 8; ++i) {
                f16 hv = (f16)xv[i];
                hi[i] = hv;
                lo[i] = (f16)(xv[i] - (float)hv);
            }
            Ah[mt][c] = hi; Al[mt][c] = lo;
        }
    }

    float m1v[2][4], m2v[2][4], m3v[2][4];
    int   i1v[2][4], i2v[2][4];
#pragma unroll
    for (int mt = 0; mt < 2; ++mt)
#pragma unroll
        for (int rg = 0; rg < 4; ++rg) {
            m1v[mt][rg] = 3.4e38f; m2v[mt][rg] = 3.4e38f; m3v[mt][rg] = 3.4e38f;
            i1v[mt][rg] = 0x7fffffff; i2v[mt][rg] = 0x7fffffff;
        }

    auto stage = [&](int kt, int buf) {        // kt local 0..15
        const int tile = ks * 16 + kt;
#pragma unroll
        for (int j = 0; j < 4; ++j) {
            const int code = w * 8 + j * 2 + (l >> 5);
            size_t off = ((size_t)tile * 64 + code) * 256 + (((l & 31) ^ (code & 7)) << 3);
            char* dsth = smem + buf * 65536 + (w * 8 + j * 2) * 512;
            gload_lds16(ET + off, dsth);
            gload_lds16(ETlo + off, dsth + 32768);
        }
    };

    const int codeL = cs * 16 + l15;
    stage(0, 0);
    int p = 0;
    for (int kt = 0; kt < 16; ++kt) {
        __syncthreads();
        if (kt + 1 < 16) stage(kt + 1, p ^ 1);

        f32x4 acc[2];
#pragma unroll
        for (int mt = 0; mt < 2; ++mt) acc[mt] = (f32x4){0.f, 0.f, 0.f, 0.f};

        const f16* bh = (const f16*)(smem + p * 65536);
        const f16* bl = (const f16*)(smem + p * 65536 + 32768);
#pragma unroll
        for (int c = 0; c < 8; ++c) {
            const int g = (c * 4 + l4) ^ (l15 & 7);
            f16x8 vh = *(const f16x8*)(bh + codeL * 256 + g * 8);
            f16x8 vl = *(const f16x8*)(bl + codeL * 256 + g * 8);
#pragma unroll
            for (int mt = 0; mt < 2; ++mt) {
                acc[mt] = __builtin_amdgcn_mfma_f32_16x16x32_f16(Ah[mt][c], vh, acc[mt], 0, 0, 0);
                acc[mt] = __builtin_amdgcn_mfma_f32_16x16x32_f16(Ah[mt][c], vl, acc[mt], 0, 0, 0);
                acc[mt] = __builtin_amdgcn_mfma_f32_16x16x32_f16(Al[mt][c], vh, acc[mt], 0, 0, 0);
            }
        }

        const int code = (ks * 16 + kt) * 64 + codeL;
        const float en = enorm[code];
#pragma unroll
        for (int mt = 0; mt < 2; ++mt)
#pragma unroll
            for (int rg = 0; rg < 4; ++rg) {
                float v = fmaf(-2.f, acc[mt][rg], en);
                if (v < m1v[mt][rg]) {
                    m3v[mt][rg] = m2v[mt][rg];
                    m2v[mt][rg] = m1v[mt][rg]; i2v[mt][rg] = i1v[mt][rg];
                    m1v[mt][rg] = v;           i1v[mt][rg] = code;
                } else if (v < m2v[mt][rg]) {
                    m3v[mt][rg] = m2v[mt][rg];
                    m2v[mt][rg] = v;           i2v[mt][rg] = code;
                } else if (v < m3v[mt][rg]) {
                    m3v[mt][rg] = v;
                }
            }
        p ^= 1;
    }

    __syncthreads();
    float* Mm1 = (float*)smem;                 // [64][64]
    int*   Mi1 = (int*)(smem + 16384);
    float* Mm2 = (float*)(smem + 32768);
    int*   Mi2 = (int*)(smem + 49152);
    float* Mm3 = (float*)(smem + 65536);
#pragma unroll
    for (int mt = 0; mt < 2; ++mt)
#pragma unroll
        for (int rg = 0; rg < 4; ++rg) {
            int row = h * 32 + mt * 16 + l4 * 4 + rg;   // 0..63
            int e   = cs * 16 + l15;
            Mm1[row * 64 + e] = m1v[mt][rg];
            Mi1[row * 64 + e] = i1v[mt][rg];
            Mm2[row * 64 + e] = m2v[mt][rg];
            Mi2[row * 64 + e] = i2v[mt][rg];
            Mm3[row * 64 + e] = m3v[mt][rg];
        }
    __syncthreads();
    if (tid < 64) {
        float a1 = 3.4e38f, a2 = 3.4e38f, a3 = 3.4e38f;
        int   ai1 = 0x7fffffff, ai2 = 0x7fffffff;
        for (int e = 0; e < 64; ++e) {
            float b1 = Mm1[tid * 64 + e], b2 = Mm2[tid * 64 + e], b3 = Mm3[tid * 64 + e];
            int   bi1 = Mi1[tid * 64 + e], bi2 = Mi2[tid * 64 + e];
            if (b1 < a1 || (b1 == a1 && bi1 < ai1)) { a3 = a2; a2 = a1; ai2 = ai1; a1 = b1; ai1 = bi1; }
            else if (b1 < a2 || (b1 == a2 && bi1 < ai2)) { a3 = a2; a2 = b1; ai2 = bi1; }
            else if (b1 < a3) a3 = b1;
            if (b2 < a1 || (b2 == a1 && bi2 < ai1)) { a3 = a2; a2 = a1; ai2 = ai1; a1 = b2; ai1 = bi2; }
            else if (b2 < a2 || (b2 == a2 && bi2 < ai2)) { a3 = a2; a2 = b2; ai2 = bi2; }
            else if (b2 < a3) a3 = b2;
            if (b3 < a3) a3 = b3;
        }
        int jg = rb * 64 + tid;
        if (jg < cnt) {
            pm1[jg * 8 + ks] = a1; pm2[jg * 8 + ks] = a2; pm3[jg * 8 + ks] = a3;
            pi1[jg * 8 + ks] = ai1; pi2[jg * 8 + ks] = ai2;
        }
    }
}

// ---------------------------------------------------------------------------
// Kernel 6 (path A): merge 8 code-split top-3 partials -> flags 0/1/2.
// ---------------------------------------------------------------------------
__global__ void merge3_kernel(const int* __restrict__ list, const int* __restrict__ countp,
        const float* __restrict__ pm1, const float* __restrict__ pm2,
        const float* __restrict__ pm3,
        const int* __restrict__ pi1, const int* __restrict__ pi2,
        int* __restrict__ idx1o, int* __restrict__ idx2o, int* __restrict__ flago) {
    const int gid = blockIdx.x * 256 + threadIdx.x;
    if (gid >= countp[0]) return;
    float a1 = 3.4e38f, a2 = 3.4e38f, a3 = 3.4e38f;
    int   ai1 = 0x7fffffff, ai2 = 0x7fffffff;
#pragma unroll
    for (int ks = 0; ks < 8; ++ks) {
        float b1 = pm1[gid * 8 + ks], b2 = pm2[gid * 8 + ks], b3 = pm3[gid * 8 + ks];
        int   bi1 = pi1[gid * 8 + ks], bi2 = pi2[gid * 8 + ks];
        if (b1 < a1 || (b1 == a1 && bi1 < ai1)) { a3 = a2; a2 = a1; ai2 = ai1; a1 = b1; ai1 = bi1; }
        else if (b1 < a2 || (b1 == a2 && bi1 < ai2)) { a3 = a2; a2 = b1; ai2 = bi1; }
        else if (b1 < a3) a3 = b1;
        if (b2 < a1 || (b2 == a1 && bi2 < ai1)) { a3 = a2; a2 = a1; ai2 = ai1; a1 = b2; ai1 = bi2; }
        else if (b2 < a2 || (b2 == a2 && bi2 < ai2)) { a3 = a2; a2 = b2; ai2 = bi2; }
        else if (b2 < a3) a3 = b2;
        if (b3 < a3) a3 = b3;
    }
    const int row = list[gid];
    int fl = 0;
    if (a2 - a1 < MARGIN_T2) fl = (a3 - a1 < MARGIN_T2) ? 2 : 1;
    idx1o[row] = ai1; idx2o[row] = ai2; flago[row] = fl;
}

// ---------------------------------------------------------------------------
// Kernel 5B/6B (path B, proven): grouped fp32 rescan + merge.
// ---------------------------------------------------------------------------
__global__ __launch_bounds__(256) void rescan_group_kernel(
        const float* __restrict__ X, const float* __restrict__ E,
        const float* __restrict__ enorm,
        const int* __restrict__ list, const int* __restrict__ countp,
        float* __restrict__ pm1, float* __restrict__ pm2, float* __restrict__ pm3,
        int* __restrict__ pi1, int* __restrict__ pi2) {
    const int cnt = countp[0];
    const int rc  = blockIdx.x >> 2;
    const int ks  = blockIdx.x & 3;
    if (rc * GROUP >= cnt) return;
    const int tid = threadIdx.x;
    __shared__ int rows_s[GROUP];
    __shared__ float sm1[256], sm2[256], sm3[256];
    __shared__ int   si1[256], si2[256];
    if (tid < GROUP) {
        int j = rc * GROUP + tid;
        rows_s[tid] = list[j < cnt ? j : cnt - 1];
    }
    __syncthreads();
    int rowsg[GROUP];
#pragma unroll
    for (int rr = 0; rr < GROUP; ++rr)
        rowsg[rr] = __builtin_amdgcn_readfirstlane(rows_s[rr]);

    float m1[GROUP], m2[GROUP], m3[GROUP];
    int   i1[GROUP], i2[GROUP];
#pragma unroll
    for (int rr = 0; rr < GROUP; ++rr) {
        m1[rr] = 3.4e38f; m2[rr] = 3.4e38f; m3[rr] = 3.4e38f;
        i1[rr] = 0x7fffffff; i2[rr] = 0x7fffffff;
    }
    for (int j = 0; j < 8; ++j) {
        const int k = ks * 2048 + j * 256 + tid;
        float acc[GROUP];
#pragma unroll
        for (int rr = 0; rr < GROUP; ++rr) acc[rr] = 0.f;
#pragma unroll 1
        for (int dc = 0; dc < 8; ++dc) {
            float ev[32];
#pragma unroll
            for (int i = 0; i < 32; ++i) ev[i] = E[(size_t)(dc * 32 + i) * NEMB + k];
#pragma unroll
            for (int rr = 0; rr < GROUP; ++rr) {
                const float* xp = X + (size_t)rowsg[rr] * DIM + dc * 32;
#pragma unroll
                for (int i = 0; i < 32; ++i) acc[rr] = fmaf(ev[i], xp[i], acc[rr]);
            }
        }
        const float en = enorm[k];
#pragma unroll
        for (int rr = 0; rr < GROUP; ++rr) {
            float v = fmaf(-2.f, acc[rr], en);
            if (v < m1[rr])      { m3[rr] = m2[rr]; m2[rr] = m1[rr]; i2[rr] = i1[rr]; m1[rr] = v; i1[rr] = k; }
            else if (v < m2[rr]) { m3[rr] = m2[rr]; m2[rr] = v; i2[rr] = k; }
            else if (v < m3[rr]) { m3[rr] = v; }
        }
    }
#pragma unroll 1
    for (int rr = 0; rr < GROUP; ++rr) {
        sm1[tid] = m1[rr]; sm2[tid] = m2[rr]; sm3[tid] = m3[rr];
        si1[tid] = i1[rr]; si2[tid] = i2[rr];
        __syncthreads();
        for (int st = 128; st > 0; st >>= 1) {
            if (tid < st) {
                float a1 = sm1[tid], a2 = sm2[tid], a3 = sm3[tid];
                int   ai1 = si1[tid], ai2 = si2[tid];
                float b1 = sm1[tid + st], b2 = sm2[tid + st], b3 = sm3[tid + st];
                int   bi1 = si1[tid + st], bi2 = si2[tid + st];
                if (b1 < a1 || (b1 == a1 && bi1 < ai1)) { a3 = a2; a2 = a1; ai2 = ai1; a1 = b1; ai1 = bi1; }
                else if (b1 < a2 || (b1 == a2 && bi1 < ai2)) { a3 = a2; a2 = b1; ai2 = bi1; }
                else if (b1 < a3) a3 = b1;
                if (b2 < a1 || (b2 == a1 && bi2 < ai1)) { a3 = a2; a2 = a1; ai2 = ai1; a1 = b2; ai1 = bi2; }
                else if (b2 < a2 || (b2 == a2 && bi2 < ai2)) { a3 = a2; a2 = b2; ai2 = bi2; }
                else if (b2 < a3) a3 = b2;
                if (b3 < a3) a3 = b3;
                sm1[tid] = a1; sm2[tid] = a2; sm3[tid] = a3; si1[tid] = ai1; si2[tid] = ai2;
            }
            __syncthreads();
        }
        if (tid == 0) {
            int jg = rc * GROUP + rr;
            if (jg < cnt) {
                pm1[jg * KSPLIT + ks] = sm1[0]; pm2[jg * KSPLIT + ks] = sm2[0];
                pm3[jg * KSPLIT + ks] = sm3[0];
                pi1[jg * KSPLIT + ks] = si1[0]; pi2[jg * KSPLIT + ks] = si2[0];
            }
        }
        __syncthreads();
    }
}

__global__ void merge_kernel(const int* __restrict__ list, const int* __restrict__ countp,
        const float* __restrict__ pm1, const float* __restrict__ pm2,
        const float* __restrict__ pm3,
        const int* __restrict__ pi1, const int* __restrict__ pi2,
        int* __restrict__ idx1o, int* __restrict__ idx2o, int* __restrict__ flago) {
    const int gid = blockIdx.x * 256 + threadIdx.x;
    if (gid >= countp[0]) return;
    float a1 = 3.4e38f, a2 = 3.4e38f, a3 = 3.4e38f;
    int   ai1 = 0x7fffffff, ai2 = 0x7fffffff;
#pragma unroll
    for (int ks = 0; ks < KSPLIT; ++ks) {
        float b1 = pm1[gid * KSPLIT + ks], b2 = pm2[gid * KSPLIT + ks], b3 = pm3[gid * KSPLIT + ks];
        int   bi1 = pi1[gid * KSPLIT + ks], bi2 = pi2[gid * KSPLIT + ks];
        if (b1 < a1 || (b1 == a1 && bi1 < ai1)) { a3 = a2; a2 = a1; ai2 = ai1; a1 = b1; ai1 = bi1; }
        else if (b1 < a2 || (b1 == a2 && bi1 < ai2)) { a3 = a2; a2 = b1; ai2 = bi1; }
        else if (b1 < a3) a3 = b1;
        if (b2 < a1 || (b2 == a1 && bi2 < ai1)) { a3 = a2; a2 = a1; ai2 = ai1; a1 = b2; ai1 = bi2; }
        else if (b2 < a2 || (b2 == a2 && bi2 < ai2)) { a3 = a2; a2 = b2; ai2 = bi2; }
        else if (b2 < a3) a3 = b2;
        if (b3 < a3) a3 = b3;
    }
    const int row = list[gid];
    int fl = 0;
    if (a2 - a1 < MARGIN_B) fl = (a3 - a1 < MARGIN_B) ? 2 : 1;
    idx1o[row] = ai1; idx2o[row] = ai2; flago[row] = fl;
}

// ---------------------------------------------------------------------------
// Fallback fp32 argmin (round-1, proven) — used only if ws is tiny.
// ---------------------------------------------------------------------------
#define BM 64
#define BN 128
#define DC 32
#define TM 4
#define TN 8
__global__ __launch_bounds__(256, 2) void argmin_f32_kernel(
        const float* __restrict__ X, const float* __restrict__ E,
        const float* __restrict__ enorm,
        int* __restrict__ idx1o, int* __restrict__ idx2o, int* __restrict__ flago) {
    __shared__ float As[DIM * BM];
    __shared__ float Bs[DC * BN];
    const int tid = threadIdx.x;
    const int r0  = blockIdx.x * BM;
    {
        const float4* X4 = (const float4*)(X + (size_t)r0 * DIM);
#pragma unroll
        for (int i = 0; i < 16; ++i) {
            int flat = tid + i * 256;
            int row = flat >> 6, c4 = flat & 63;
            float4 v = X4[flat];
            int d = c4 * 4;
            As[(d + 0) * BM + row] = v.x;
            As[(d + 1) * BM + row] = v.y;
            As[(d + 2) * BM + row] = v.z;
            As[(d + 3) * BM + row] = v.w;
        }
    }
    const int tc = tid & 15;
    const int tr = tid >> 4;
    float m1[TM], m2[TM], m3[TM];
    int   i1[TM], i2[TM];
#pragma unroll
    for (int j = 0; j < TM; ++j) { m1[j] = m2[j] = m3[j] = 3.4e38f; i1[j] = i2[j] = 0x7fffffff; }
    for (int kt = 0; kt < NEMB; kt += BN) {
        float acc[TM][TN];
#pragma unroll
        for (int j = 0; j < TM; ++j)
#pragma unroll
            for (int i = 0; i < TN; ++i) acc[j][i] = 0.f;
        for (int dc = 0; dc < DIM; dc += DC) {
            __syncthreads();
            const float4* E4 = (const float4*)E;
#pragma unroll
            for (int i = 0; i < 4; ++i) {
                int flat = tid + i * 256;
                int dd = flat >> 5, k4 = flat & 31;
                float4 v = E4[(size_t)(dc + dd) * (NEMB / 4) + (kt >> 2) + k4];
                *(float4*)&Bs[dd * BN + k4 * 4] = v;
            }
            __syncthreads();
#pragma unroll
            for (int dd = 0; dd < DC; ++dd) {
                float4 av = *(const float4*)&As[(dc + dd) * BM + tr * TM];
                float4 b0 = *(const float4*)&Bs[dd * BN + tc * TN];
                float4 b1 = *(const float4*)&Bs[dd * BN + tc * TN + 4];
                float a[TM] = {av.x, av.y, av.z, av.w};
                float b[TN] = {b0.x, b0.y, b0.z, b0.w, b1.x, b1.y, b1.z, b1.w};
#pragma unroll
                for (int j = 0; j < TM; ++j)
#pragma unroll
                    for (int i = 0; i < TN; ++i)
                        acc[j][i] = fmaf(a[j], b[i], acc[j][i]);
            }
        }
        float4 e0 = *(const float4*)&enorm[kt + tc * TN];
        float4 e1 = *(const float4*)&enorm[kt + tc * TN + 4];
        float en[TN] = {e0.x, e0.y, e0.z, e0.w, e1.x, e1.y, e1.z, e1.w};
#pragma unroll
        for (int j = 0; j < TM; ++j) {
#pragma unroll
            for (int i = 0; i < TN; ++i) {
                float v = en[i] - 2.f * acc[j][i];
                int k = kt + tc * TN + i;
                if (v < m1[j]) { m3[j] = m2[j]; m2[j] = m1[j]; i2[j] = i1[j]; m1[j] = v; i1[j] = k; }
                else if (v < m2[j]) { m3[j] = m2[j]; m2[j] = v; i2[j] = k; }
                else if (v < m3[j]) { m3[j] = v; }
            }
        }
    }
    __syncthreads();
    float* Mm1 = As;
    float* Mm2 = As + 1024;
    float* Mm3 = As + 2048;
    int*   Mi1 = (int*)(As + 3072);
    int*   Mi2 = (int*)(As + 4096);
#pragma unroll
    for (int j = 0; j < TM; ++j) {
        int row = tr * TM + j;
        Mm1[row * 16 + tc] = m1[j];
        Mm2[row * 16 + tc] = m2[j];
        Mm3[row * 16 + tc] = m3[j];
        Mi1[row * 16 + tc] = i1[j];
        Mi2[row * 16 + tc] = i2[j];
    }
    __syncthreads();
    if (tid < BM) {
        float M1 = 3.4e38f, M2 = 3.4e38f, M3 = 3.4e38f;
        int I1 = 0x7fffffff, I2 = 0x7fffffff;
        for (int e = 0; e < 16; ++e) {
            float v = Mm1[tid * 16 + e]; int vi = Mi1[tid * 16 + e];
            if (v < M1 || (v == M1 && vi < I1)) { M3 = M2; M2 = M1; I2 = I1; M1 = v; I1 = vi; }
            else if (v < M2 || (v == M2 && vi < I2)) { M3 = M2; M2 = v; I2 = vi; }
            else if (v < M3) { M3 = v; }
            v = Mm2[tid * 16 + e]; vi = Mi2[tid * 16 + e];
            if (v < M1 || (v == M1 && vi < I1)) { M3 = M2; M2 = M1; I2 = I1; M1 = v; I1 = vi; }
            else if (v < M2 || (v == M2 && vi < I2)) { M3 = M2; M2 = v; I2 = vi; }
            else if (v < M3) { M3 = v; }
            v = Mm3[tid * 16 + e];
            if (v < M3) M3 = v;
        }
        int r = r0 + tid;
        int fl = 0;
        if (M2 - M1 < MARGIN_B) fl = (M3 - M1 < MARGIN_B) ? 2 : 1;
        idx1o[r] = I1; idx2o[r] = I2; flago[r] = fl;
    }
}

// ---------------------------------------------------------------------------
// Kernel 7: f64 refinement (flag 1 = 2-candidate, 2 = full row rescan).
// ---------------------------------------------------------------------------
__global__ __launch_bounds__(256) void refine_kernel(
        const float* __restrict__ X, const float* __restrict__ E,
        int* __restrict__ idx1o, const int* __restrict__ idx2o,
        const int* __restrict__ flago) {
    __shared__ double redA[256];
    __shared__ double redB[256];
    __shared__ int    redI[256];
    const int tid = threadIdx.x;
    for (int rr = 0; rr < 8; ++rr) {
        int r = blockIdx.x * 8 + rr;
        int flag = flago[r];
        if (flag == 0) continue;
        if (flag == 1) {
            int a = idx1o[r], b = idx2o[r];
            double x  = (double)X[(size_t)r * DIM + tid];
            double ea = (double)E[(size_t)tid * NEMB + a];
            double eb = (double)E[(size_t)tid * NEMB + b];
            redA[tid] = ea * (ea - 2.0 * x);
            redB[tid] = eb * (eb - 2.0 * x);
            __syncthreads();
            for (int s = 128; s > 0; s >>= 1) {
                if (tid < s) { redA[tid] += redA[tid + s]; redB[tid] += redB[tid + s]; }
                __syncthreads();
            }
            if (tid == 0) {
                double sa = redA[0], sb = redB[0];
                idx1o[r] = (sb < sa || (sb == sa && b < a)) ? b : a;
            }
            __syncthreads();
        } else {
            double bm = 1e300; int bi = 0x7fffffff;
            for (int k = tid; k < NEMB; k += 256) {
                double s = 0.0;
                for (int d = 0; d < DIM; ++d) {
                    double e = (double)E[(size_t)d * NEMB + k];
                    double x = (double)X[(size_t)r * DIM + d];
                    s += e * (e - 2.0 * x);
                }
                if (s < bm) { bm = s; bi = k; }
            }
            redA[tid] = bm; redI[tid] = bi;
            __syncthreads();
            for (int s = 128; s > 0; s >>= 1) {
                if (tid < s) {
                    if (redA[tid + s] < redA[tid] ||
                        (redA[tid + s] == redA[tid] && redI[tid + s] < redI[tid])) {
                        redA[tid] = redA[tid + s]; redI[tid] = redI[tid + s];
                    }
                }
                __syncthreads();
            }
            if (tid == 0) idx1o[r] = redI[0];
            __syncthreads();
        }
    }
}

// ---------------------------------------------------------------------------
// Kernel 8: gather + loss partials.  v1: strided E columns (fallback).
// ---------------------------------------------------------------------------
__global__ __launch_bounds__(256) void gather_kernel(
        const float* __restrict__ X, const float* __restrict__ E,
        const int* __restrict__ idx,
        float* __restrict__ outq, float* __restrict__ outidxf,
        double* __restrict__ partials) {
    __shared__ double red[256];
    const int tid = threadIdx.x;
    const int row = blockIdx.x * 4 + (tid >> 6);
    const int d0  = (tid & 63) * 4;
    const int k   = idx[row];
    float4 x = *(const float4*)&X[(size_t)row * DIM + d0];
    float q0 = E[(size_t)(d0 + 0) * NEMB + k];
    float q1 = E[(size_t)(d0 + 1) * NEMB + k];
    float q2 = E[(size_t)(d0 + 2) * NEMB + k];
    float q3 = E[(size_t)(d0 + 3) * NEMB + k];
    float4 q = {q0, q1, q2, q3};
    *(float4*)&outq[(size_t)row * DIM + d0] = q;
    if ((tid & 63) == 0) outidxf[row] = (float)k;
    double s = 0.0, t;
    t = (double)q0 - (double)x.x; s += t * t;
    t = (double)q1 - (double)x.y; s += t * t;
    t = (double)q2 - (double)x.z; s += t * t;
    t = (double)q3 - (double)x.w; s += t * t;
    red[tid] = s;
    __syncthreads();
    for (int st = 128; st > 0; st >>= 1) {
        if (tid < st) red[tid] += red[tid + st];
        __syncthreads();
    }
    if (tid == 0) partials[blockIdx.x] = red[0];
}

// v2: coalesced reads from transposed f32 copy ET32 [8192][256].
__global__ __launch_bounds__(256) void gather2_kernel(
        const float* __restrict__ X, const float* __restrict__ ET32,
        const int* __restrict__ idx,
        float* __restrict__ outq, float* __restrict__ outidxf,
        double* __restrict__ partials) {
    __shared__ double red[256];
    const int tid = threadIdx.x;
    const int row = blockIdx.x * 4 + (tid >> 6);
    const int d0  = (tid & 63) * 4;
    const int k   = idx[row];
    float4 x = *(const float4*)&X[(size_t)row * DIM + d0];
    float4 q = *(const float4*)&ET32[(size_t)k * DIM + d0];   // coalesced row read
    *(float4*)&outq[(size_t)row * DIM + d0] = q;
    if ((tid & 63) == 0) outidxf[row] = (float)k;
    double s = 0.0, t;
    t = (double)q.x - (double)x.x; s += t * t;
    t = (double)q.y - (double)x.y; s += t * t;
    t = (double)q.z - (double)x.z; s += t * t;
    t = (double)q.w - (double)x.w; s += t * t;
    red[tid] = s;
    __syncthreads();
    for (int st = 128; st > 0; st >>= 1) {
        if (tid < st) red[tid] += red[tid + st];
        __syncthreads();
    }
    if (tid == 0) partials[blockIdx.x] = red[0];
}

// ---------------------------------------------------------------------------
// Kernel 9: deterministic final loss reduction.
// ---------------------------------------------------------------------------
__global__ __launch_bounds__(256) void loss_kernel(const double* __restrict__ partials,
                                                   float* __restrict__ outloss) {
    __shared__ double red[256];
    const int tid = threadIdx.x;
    double s = 0.0;
    for (int i = tid; i < N_TOK / 4; i += 256) s += partials[i];
    red[tid] = s;
    __syncthreads();
    for (int st = 128; st > 0; st >>= 1) {
        if (tid < st) red[tid] += red[tid + st];
        __syncthreads();
    }
    if (tid == 0)
        outloss[0] = (float)(0.25 * red[0] / (double)((size_t)N_TOK * DIM));
}

// ---------------------------------------------------------------------------
extern "C" void kernel_launch(void* const* d_in, const int* in_sizes, int n_in,
                              void* d_out, int out_size, void* d_ws, size_t ws_size,
                              hipStream_t stream) {
    const float* X = (const float*)d_in[0];   // [32768, 256]
    const float* E = (const float*)d_in[1];   // [256, 8192]

    float* outq    = (float*)d_out;
    float* outloss = outq + (size_t)N_TOK * DIM;
    float* outidx  = outloss + 1;

    char* base = (char*)d_ws;
    float*  enorm    = (float*)base;                          // 32 KB
    int*    idx1     = (int*)(base + 32768);                  // 128 KB
    int*    idx2     = (int*)(base + 163840);                 // 128 KB
    int*    flag     = (int*)(base + 294912);                 // 128 KB
    double* partials = (double*)(base + 425984);              // 64 KB
    f16*    ET       = (f16*)(base + 524288);                 // 4 MB
    // path B aliases (overlay ET region post-argmin)
    char*   etbase   = base + 524288;
    int*    listB    = (int*)etbase;
    int*    countB   = (int*)(etbase + 131072);
    float*  pm1B     = (float*)(etbase + 132096);
    float*  pm2B     = (float*)(etbase + 132096 + 524288);
    float*  pm3B     = (float*)(etbase + 132096 + 1048576);
    int*    pi1B     = (int*)  (etbase + 132096 + 1572864);
    int*    pi2B     = (int*)  (etbase + 132096 + 2097152);
    // path A extras
    f16*    ETlo     = (f16*)(base + 4718592);                // 4 MB
    int*    listA    = (int*)(base + 8912896);                // 128 KB
    int*    countA   = (int*)(base + 9043968);                // 1 KB
    float*  ET32     = (float*)(base + 9044992);              // 8 MB (optional)
    // path A partial top-3 arrays: scratch in d_out's outq region (32 MB,
    // overwritten by gather afterwards).
    float*  pm1A     = outq;
    float*  pm2A     = outq + 262144;
    float*  pm3A     = outq + 524288;
    int*    pi1A     = (int*)(outq + 786432);
    int*    pi2A     = (int*)(outq + 1048576);
    const size_t NEED_B  = 4718592;
    const size_t NEED_A  = 12190720;
    const size_t NEED_A2 = 9044992 + (size_t)NEMB * DIM * sizeof(float); // 17433600

    enorm_kernel<<<NEMB / 256, 256, 0, stream>>>(E, enorm);
    if (ws_size >= NEED_A) {
        const int wf32 = (ws_size >= NEED_A2) ? 1 : 0;
        cvt3_kernel        <<<512,        256, 0, stream>>>(E, ET, ETlo, ET32, 1, wf32);
        argmin_f16v7_kernel<<<N_TOK / 64,  512, 0, stream>>>(X, ET, enorm, idx1, idx2, flag);
        compact_kernel     <<<1,          256, 0, stream>>>(flag, listA, countA);
        rescan_split_kernel<<<512 * 8,    512, 0, stream>>>(X, ET, ETlo, enorm, listA, countA,
                                                            pm1A, pm2A, pm3A, pi1A, pi2A);
        merge3_kernel      <<<N_TOK / 256, 256, 0, stream>>>(listA, countA, pm1A, pm2A, pm3A,
                                                             pi1A, pi2A, idx1, idx2, flag);
        refine_kernel<<<N_TOK / 8, 256, 0, stream>>>(X, E, idx1, idx2, flag);
        if (wf32)
            gather2_kernel<<<N_TOK / 4, 256, 0, stream>>>(X, ET32, idx1, outq, outidx, partials);
        else
            gather_kernel <<<N_TOK / 4, 256, 0, stream>>>(X, E, idx1, outq, outidx, partials);
    } else if (ws_size >= NEED_B) {
        cvt3_kernel        <<<512,        256, 0, stream>>>(E, ET, ET, (float*)ET, 0, 0);
        argmin_f16v7_kernel<<<N_TOK / 64,  512, 0, stream>>>(X, ET, enorm, idx1, idx2, flag);
        compact_kernel     <<<1,          256, 0, stream>>>(flag, listB, countB);
        rescan_group_kernel<<<(N_TOK / GROUP) * KSPLIT, 256, 0, stream>>>(X, E, enorm, listB, countB,
                                                                          pm1B, pm2B, pm3B, pi1B, pi2B);
        merge_kernel       <<<N_TOK / 256, 256, 0, stream>>>(listB, countB, pm1B, pm2B, pm3B,
                                                             pi1B, pi2B, idx1, idx2, flag);
        refine_kernel<<<N_TOK / 8, 256, 0, stream>>>(X, E, idx1, idx2, flag);
        gather_kernel<<<N_TOK / 4, 256, 0, stream>>>(X, E, idx1, outq, outidx, partials);
    } else {
        argmin_f32_kernel  <<<N_TOK / BM, 256, 0, stream>>>(X, E, enorm, idx1, idx2, flag);
        refine_kernel<<<N_TOK / 8, 256, 0, stream>>>(X, E, idx1, idx2, flag);
        gather_kernel<<<N_TOK / 4, 256, 0, stream>>>(X, E, idx1, outq, outidx, partials);
    }
    loss_kernel  <<<1,         256, 0, stream>>>(partials, outloss);
}

// Round 10
// 299.057 us; speedup vs baseline: 3.5592x; 1.2502x over previous
//
#include <hip/hip_runtime.h>

#define N_TOK 32768
#define DIM   256
#define NEMB  8192

#define MARGIN_A  0.2f    // f16-MFMA tier: provable-trust margin
#define MARGIN_T2 0.008f  // f16-2split tier: worst-case error ~2e-3 -> 2eps < 0.008
#define MARGIN_B  0.0625f // fp32 tier (path B): flag for f64 refine below this
#define GROUP 8
#define KSPLIT 4

typedef _Float16 f16;
typedef __attribute__((ext_vector_type(4))) _Float16 f16x4;
typedef __attribute__((ext_vector_type(8))) _Float16 f16x8;
typedef __attribute__((ext_vector_type(4))) float     f32x4;

// ---------------------------------------------------------------------------
// Kernel 1: per-code squared norms  enorm[k] = sum_d E[d][k]^2   (f32, exact)
// ---------------------------------------------------------------------------
__global__ void enorm_kernel(const float* __restrict__ E, float* __restrict__ enorm) {
    int k = blockIdx.x * blockDim.x + threadIdx.x;
    float s = 0.f;
#pragma unroll 8
    for (int d = 0; d < DIM; ++d) {
        float e = E[d * NEMB + k];
        s = fmaf(e, e, s);
    }
    enorm[k] = s;
}

// ---------------------------------------------------------------------------
// Kernel 2: transpose E [256][8192] f32 -> ET [8192][256] f16 (hi),
// optional ETlo = f16(E - hi), optional ET32 = f32 transposed copy (gather).
// ---------------------------------------------------------------------------
__global__ __launch_bounds__(256) void cvt3_kernel(const float* __restrict__ E,
                                                   f16* __restrict__ ET,
                                                   f16* __restrict__ ETlo,
                                                   float* __restrict__ ET32,
                                                   int wlo, int wf32) {
    __shared__ float shf[64][65];
    const int tid = threadIdx.x;
    const int k0 = (blockIdx.x & 127) * 64;
    const int d0 = (blockIdx.x >> 7) * 64;
#pragma unroll
    for (int i = 0; i < 16; ++i) {
        int flat = i * 256 + tid;
        int k = flat & 63, d = flat >> 6;
        shf[k][d] = E[(size_t)(d0 + d) * NEMB + k0 + k];   // coalesced in k
    }
    __syncthreads();
#pragma unroll
    for (int i = 0; i < 16; ++i) {
        int flat = i * 256 + tid;
        int d = flat & 63, kk = flat >> 6;
        float v = shf[kk][d];
        f16 hi = (f16)v;
        ET[(size_t)(k0 + kk) * DIM + d0 + d] = hi;               // coalesced in d
        if (wlo)  ETlo[(size_t)(k0 + kk) * DIM + d0 + d] = (f16)(v - (float)hi);
        if (wf32) ET32[(size_t)(k0 + kk) * DIM + d0 + d] = v;
    }
}

// ---------------------------------------------------------------------------
__device__ __forceinline__ void gload_lds16(const void* g, void* l) {
    __builtin_amdgcn_global_load_lds(
        (const __attribute__((address_space(1))) unsigned int*)g,
        (__attribute__((address_space(3))) unsigned int*)l, 16, 0, 0);
}

// ---------------------------------------------------------------------------
// Kernel 3: f16 MFMA GEMM-argmin v8.
// = proven v4 compute structure (BM=128, 8 waves, mt=4, one 32KB tile per
// barrier, 2x32KB dbuf) with LDS cut 96KB->64KB: X-stage aliases the dbuf
// region (as in v4) and the merge uses the v7-validated shfl_xor butterfly
// + 6KB LDS instead of v4's 96KB arrays.  64KB LDS + ~124 VGPR => 2 blocks/CU
// (4 waves/SIMD): independent per-block barriers let one block's MFMA cover
// the other's stage-drain and epilogue VALU.  Math identical to v4/v5.
// ---------------------------------------------------------------------------
__global__ __launch_bounds__(512, 2) void argmin_f16v8_kernel(
        const float* __restrict__ X, const f16* __restrict__ ET,
        const float* __restrict__ enorm,
        int* __restrict__ idx1o, int* __restrict__ idx2o, int* __restrict__ flago) {
    __shared__ char smem[65536];   // X-stage [0,64K) -> dbuf 2x32KB; merge [0,6K)

    const int tid = threadIdx.x;          // 0..511
    const int w   = tid >> 6;             // wave 0..7
    const int l   = tid & 63;
    const int l15 = l & 15, l4 = l >> 4;
    const int h   = w & 1;                // row half (64 rows)
    const int cs  = w >> 1;               // code strip (16 codes)
    const int r0  = blockIdx.x * 128;

    // ---- Phase A: stage X rows [r0, r0+128) as f16 [128][256] in LDS ----
    // 128 rows x 64 float4/row = 8192 float4; 512 thr -> 16 iterations.
    {
        const float4* X4 = (const float4*)(X + (size_t)r0 * DIM);
        f16* xs = (f16*)smem;
#pragma unroll
        for (int i = 0; i < 16; ++i) {
            int flat4 = tid + i * 512;            // 0..8191
            float4 v = X4[flat4];                 // coalesced
            int row = flat4 >> 6, d4 = flat4 & 63;
            f16x4 p = {(f16)v.x, (f16)v.y, (f16)v.z, (f16)v.w};
            *(f16x4*)(xs + row * 256 + d4 * 4) = p;
        }
    }
    __syncthreads();

    // ---- A fragments: rows r0 + h*64 + mt*16 + l15 ----
    f16x8 Afr[4][8];
    {
        const f16* xs = (const f16*)smem;
#pragma unroll
        for (int mt = 0; mt < 4; ++mt)
#pragma unroll
            for (int c = 0; c < 8; ++c)
                Afr[mt][c] = *(const f16x8*)(xs + (h * 64 + mt * 16 + l15) * 256 + c * 32 + l4 * 8);
    }
    __syncthreads();   // X region free; dbuf overwrites it

    float m1v[4][4], m2v[4][4];
    int   i1v[4][4];
#pragma unroll
    for (int mt = 0; mt < 4; ++mt)
#pragma unroll
        for (int rg = 0; rg < 4; ++rg) {
            m1v[mt][rg] = 3.4e38f; m2v[mt][rg] = 3.4e38f; i1v[mt][rg] = 0x7fffffff;
        }

    // stage tile kt (64 codes x 256 dims = 32KB): wave w stages codes
    // [w*8, w*8+8): 4 calls x 2 code rows (1KB each), XOR-(code&7) swizzle.
    auto stage = [&](int kt, int buf) {
#pragma unroll
        for (int j = 0; j < 4; ++j) {
            const int code = w * 8 + j * 2 + (l >> 5);         // local code 0..63
            const f16* src = ET + ((size_t)kt * 64 + code) * 256
                               + (((l & 31) ^ (code & 7)) << 3);
            char* dst = smem + buf * 32768 + (w * 8 + j * 2) * 512;  // wave-uniform
            gload_lds16(src, dst);
        }
    };

    const int codeL = cs * 16 + l15;
    stage(0, 0);
    int p = 0;
    for (int kt = 0; kt < 128; ++kt) {
        __syncthreads();                             // buf[p] staged
        if (kt + 1 < 128) stage(kt + 1, p ^ 1);

        f32x4 acc[4];
#pragma unroll
        for (int mt = 0; mt < 4; ++mt) acc[mt] = (f32x4){0.f, 0.f, 0.f, 0.f};

        const f16* bb = (const f16*)(smem + p * 32768);
#pragma unroll
        for (int c = 0; c < 8; ++c) {
            const int g = (c * 4 + l4) ^ (l15 & 7);  // swizzled granule
            f16x8 b = *(const f16x8*)(bb + codeL * 256 + g * 8);
#pragma unroll
            for (int mt = 0; mt < 4; ++mt)
                acc[mt] = __builtin_amdgcn_mfma_f32_16x16x32_f16(Afr[mt][c], b, acc[mt], 0, 0, 0);
        }

        const int code = kt * 64 + codeL;            // ascending per lane
        const float en = enorm[code];
#pragma unroll
        for (int mt = 0; mt < 4; ++mt)
#pragma unroll
            for (int rg = 0; rg < 4; ++rg) {
                float v = fmaf(-2.f, acc[mt][rg], en);
                bool cl = v < m1v[mt][rg];
                m2v[mt][rg] = fminf(m2v[mt][rg], fmaxf(m1v[mt][rg], v));
                i1v[mt][rg] = cl ? code : i1v[mt][rg];
                m1v[mt][rg] = fminf(m1v[mt][rg], v);
            }
        p ^= 1;
    }

    // ---- merge step 1: shfl_xor butterfly over l15 within 16-lane groups ----
#pragma unroll
    for (int off = 1; off < 16; off <<= 1) {
#pragma unroll
        for (int mt = 0; mt < 4; ++mt)
#pragma unroll
            for (int rg = 0; rg < 4; ++rg) {
                float om1 = __shfl_xor(m1v[mt][rg], off);
                int   oi1 = __shfl_xor(i1v[mt][rg], off);
                float om2 = __shfl_xor(m2v[mt][rg], off);
                bool sw = (om1 < m1v[mt][rg]) ||
                          (om1 == m1v[mt][rg] && oi1 < i1v[mt][rg]);
                float hi = sw ? m1v[mt][rg] : om1;
                m1v[mt][rg] = sw ? om1 : m1v[mt][rg];
                i1v[mt][rg] = sw ? oi1 : i1v[mt][rg];
                m2v[mt][rg] = fminf(fminf(m2v[mt][rg], om2), hi);
            }
    }

    // ---- merge step 2: 6KB LDS cross-strip (4 cs) merge ----
    __syncthreads();   // all dbuf reads done; safe to alias [0,6K)
    float* sm1 = (float*)smem;              // [128][4]
    int*   si1 = (int*)(smem + 2048);
    float* sm2 = (float*)(smem + 4096);
    if (l15 == 0) {
#pragma unroll
        for (int mt = 0; mt < 4; ++mt)
#pragma unroll
            for (int rg = 0; rg < 4; ++rg) {
                int row = h * 64 + mt * 16 + l4 * 4 + rg;   // 0..127
                sm1[row * 4 + cs] = m1v[mt][rg];
                si1[row * 4 + cs] = i1v[mt][rg];
                sm2[row * 4 + cs] = m2v[mt][rg];
            }
    }
    __syncthreads();
    if (tid < 128) {
        float M1 = 3.4e38f, M2 = 3.4e38f;
        int   I1 = 0x7fffffff;
#pragma unroll
        for (int e = 0; e < 4; ++e) {
            float v = sm1[tid * 4 + e]; int vi = si1[tid * 4 + e];
            if (v < M1 || (v == M1 && vi < I1)) { M2 = M1; M1 = v; I1 = vi; }
            else M2 = fminf(M2, v);
            M2 = fminf(M2, sm2[tid * 4 + e]);
        }
        int r = r0 + tid;
        idx1o[r] = I1;
        idx2o[r] = I1;
        flago[r] = (M2 - M1 < MARGIN_A) ? -1 : 0;
    }
}

// ---------------------------------------------------------------------------
// Kernel 4: deterministic ordered compaction of flagged (-1) rows.
// ---------------------------------------------------------------------------
__global__ __launch_bounds__(256) void compact_kernel(const int* __restrict__ flago,
        int* __restrict__ list, int* __restrict__ countp) {
    __shared__ int cnts[256], bases[256];
    const int tid = threadIdx.x;
    int c = 0;
    for (int i = 0; i < N_TOK / 256; ++i)
        c += (flago[tid * (N_TOK / 256) + i] < 0) ? 1 : 0;
    cnts[tid] = c;
    __syncthreads();
    if (tid == 0) {
        int run = 0;
        for (int t = 0; t < 256; ++t) { bases[t] = run; run += cnts[t]; }
        countp[0] = run;
    }
    __syncthreads();
    int o = bases[tid];
    for (int i = 0; i < N_TOK / 256; ++i) {
        int r = tid * (N_TOK / 256) + i;
        if (flago[r] < 0) list[o++] = r;
    }
}

// ---------------------------------------------------------------------------
// Kernel 5 (path A): f16 two-split MFMA rescan (top-3 + top-2 idx) — proven.
// ---------------------------------------------------------------------------
__global__ __launch_bounds__(512) void rescan_split_kernel(
        const float* __restrict__ X, const f16* __restrict__ ET,
        const f16* __restrict__ ETlo, const float* __restrict__ enorm,
        const int* __restrict__ list, const int* __restrict__ countp,
        float* __restrict__ pm1, float* __restrict__ pm2, float* __restrict__ pm3,
        int* __restrict__ pi1, int* __restrict__ pi2) {
    __shared__ char smem[131072];
    const int cnt = countp[0];
    const int rb  = blockIdx.x >> 3;
    const int ks  = blockIdx.x & 7;
    if (rb * 64 >= cnt) return;

    const int tid = threadIdx.x, w = tid >> 6, l = tid & 63;
    const int l15 = l & 15, l4 = l >> 4;
    const int h = w & 1, cs = w >> 1;

    f16x8 Ah[2][8], Al[2][8];
#pragma unroll
    for (int mt = 0; mt < 2; ++mt) {
        int jg  = rb * 64 + h * 32 + mt * 16 + l15;
        int row = list[jg < cnt ? jg : cnt - 1];
        const float* xp = X + (size_t)row * DIM + l4 * 8;
#pragma unroll
        for (int c = 0; c < 8; ++c) {
            float4 v0 = *(const float4*)(xp + c * 32);
            float4 v1 = *(const float4*)(xp + c * 32 + 4);
            float xv[8] = {v0.x, v0.y, v0.z, v0.w, v1.x, v1.y, v1.z, v1.w};
            f16x8 hi, lo;
#pragma unroll
            for (int i = 0; i < 8; ++i) {
                f16 hv = (f16)xv[i];
                hi[i] = hv;
                lo[i] = (f16)(xv[i] - (float)hv);
            }
            Ah[mt][c] = hi; Al[mt][c] = lo;
        }
    }

    float m1v[2][4], m2v[2][4], m3v[2][4];
    int   i1v[2][4], i2v[2][4];
#pragma unroll
    for (int mt = 0; mt < 2; ++mt)
#pragma unroll
        for (int rg = 0; rg < 4; ++rg) {
            m1v[mt][rg] = 3.4e38f; m2v[mt][rg] = 3.4e38f; m3v[mt][rg] = 3.4e38f;
            i1v[mt][rg] = 0x7fffffff; i2v[mt][rg] = 0x7fffffff;
        }

    auto stage = [&](int kt, int buf) {        // kt local 0..15
        const int tile = ks * 16 + kt;
#pragma unroll
        for (int j = 0; j < 4; ++j) {
            const int code = w * 8 + j * 2 + (l >> 5);
            size_t off = ((size_t)tile * 64 + code) * 256 + (((l & 31) ^ (code & 7)) << 3);
            char* dsth = smem + buf * 65536 + (w * 8 + j * 2) * 512;
            gload_lds16(ET + off, dsth);
            gload_lds16(ETlo + off, dsth + 32768);
        }
    };

    const int codeL = cs * 16 + l15;
    stage(0, 0);
    int p = 0;
    for (int kt = 0; kt < 16; ++kt) {
        __syncthreads();
        if (kt + 1 < 16) stage(kt + 1, p ^ 1);

        f32x4 acc[2];
#pragma unroll
        for (int mt = 0; mt < 2; ++mt) acc[mt] = (f32x4){0.f, 0.f, 0.f, 0.f};

        const f16* bh = (const f16*)(smem + p * 65536);
        const f16* bl = (const f16*)(smem + p * 65536 + 32768);
#pragma unroll
        for (int c = 0; c < 8; ++c) {
            const int g = (c * 4 + l4) ^ (l15 & 7);
            f16x8 vh = *(const f16x8*)(bh + codeL * 256 + g * 8);
            f16x8 vl = *(const f16x8*)(bl + codeL * 256 + g * 8);
#pragma unroll
            for (int mt = 0; mt < 2; ++mt) {
                acc[mt] = __builtin_amdgcn_mfma_f32_16x16x32_f16(Ah[mt][c], vh, acc[mt], 0, 0, 0);
                acc[mt] = __builtin_amdgcn_mfma_f32_16x16x32_f16(Ah[mt][c], vl, acc[mt], 0, 0, 0);
                acc[mt] = __builtin_amdgcn_mfma_f32_16x16x32_f16(Al[mt][c], vh, acc[mt], 0, 0, 0);
            }
        }

        const int code = (ks * 16 + kt) * 64 + codeL;
        const float en = enorm[code];
#pragma unroll
        for (int mt = 0; mt < 2; ++mt)
#pragma unroll
            for (int rg = 0; rg < 4; ++rg) {
                float v = fmaf(-2.f, acc[mt][rg], en);
                if (v < m1v[mt][rg]) {
                    m3v[mt][rg] = m2v[mt][rg];
                    m2v[mt][rg] = m1v[mt][rg]; i2v[mt][rg] = i1v[mt][rg];
                    m1v[mt][rg] = v;           i1v[mt][rg] = code;
                } else if (v < m2v[mt][rg]) {
                    m3v[mt][rg] = m2v[mt][rg];
                    m2v[mt][rg] = v;           i2v[mt][rg] = code;
                } else if (v < m3v[mt][rg]) {
                    m3v[mt][rg] = v;
                }
            }
        p ^= 1;
    }

    __syncthreads();
    float* Mm1 = (float*)smem;                 // [64][64]
    int*   Mi1 = (int*)(smem + 16384);
    float* Mm2 = (float*)(smem + 32768);
    int*   Mi2 = (int*)(smem + 49152);
    float* Mm3 = (float*)(smem + 65536);
#pragma unroll
    for (int mt = 0; mt < 2; ++mt)
#pragma unroll
        for (int rg = 0; rg < 4; ++rg) {
            int row = h * 32 + mt * 16 + l4 * 4 + rg;   // 0..63
            int e   = cs * 16 + l15;
            Mm1[row * 64 + e] = m1v[mt][rg];
            Mi1[row * 64 + e] = i1v[mt][rg];
            Mm2[row * 64 + e] = m2v[mt][rg];
            Mi2[row * 64 + e] = i2v[mt][rg];
            Mm3[row * 64 + e] = m3v[mt][rg];
        }
    __syncthreads();
    if (tid < 64) {
        float a1 = 3.4e38f, a2 = 3.4e38f, a3 = 3.4e38f;
        int   ai1 = 0x7fffffff, ai2 = 0x7fffffff;
        for (int e = 0; e < 64; ++e) {
            float b1 = Mm1[tid * 64 + e], b2 = Mm2[tid * 64 + e], b3 = Mm3[tid * 64 + e];
            int   bi1 = Mi1[tid * 64 + e], bi2 = Mi2[tid * 64 + e];
            if (b1 < a1 || (b1 == a1 && bi1 < ai1)) { a3 = a2; a2 = a1; ai2 = ai1; a1 = b1; ai1 = bi1; }
            else if (b1 < a2 || (b1 == a2 && bi1 < ai2)) { a3 = a2; a2 = b1; ai2 = bi1; }
            else if (b1 < a3) a3 = b1;
            if (b2 < a1 || (b2 == a1 && bi2 < ai1)) { a3 = a2; a2 = a1; ai2 = ai1; a1 = b2; ai1 = bi2; }
            else if (b2 < a2 || (b2 == a2 && bi2 < ai2)) { a3 = a2; a2 = b2; ai2 = bi2; }
            else if (b2 < a3) a3 = b2;
            if (b3 < a3) a3 = b3;
        }
        int jg = rb * 64 + tid;
        if (jg < cnt) {
            pm1[jg * 8 + ks] = a1; pm2[jg * 8 + ks] = a2; pm3[jg * 8 + ks] = a3;
            pi1[jg * 8 + ks] = ai1; pi2[jg * 8 + ks] = ai2;
        }
    }
}

// ---------------------------------------------------------------------------
// Kernel 6 (path A): merge 8 code-split top-3 partials -> flags 0/1/2.
// ---------------------------------------------------------------------------
__global__ void merge3_kernel(const int* __restrict__ list, const int* __restrict__ countp,
        const float* __restrict__ pm1, const float* __restrict__ pm2,
        const float* __restrict__ pm3,
        const int* __restrict__ pi1, const int* __restrict__ pi2,
        int* __restrict__ idx1o, int* __restrict__ idx2o, int* __restrict__ flago) {
    const int gid = blockIdx.x * 256 + threadIdx.x;
    if (gid >= countp[0]) return;
    float a1 = 3.4e38f, a2 = 3.4e38f, a3 = 3.4e38f;
    int   ai1 = 0x7fffffff, ai2 = 0x7fffffff;
#pragma unroll
    for (int ks = 0; ks < 8; ++ks) {
        float b1 = pm1[gid * 8 + ks], b2 = pm2[gid * 8 + ks], b3 = pm3[gid * 8 + ks];
        int   bi1 = pi1[gid * 8 + ks], bi2 = pi2[gid * 8 + ks];
        if (b1 < a1 || (b1 == a1 && bi1 < ai1)) { a3 = a2; a2 = a1; ai2 = ai1; a1 = b1; ai1 = bi1; }
        else if (b1 < a2 || (b1 == a2 && bi1 < ai2)) { a3 = a2; a2 = b1; ai2 = bi1; }
        else if (b1 < a3) a3 = b1;
        if (b2 < a1 || (b2 == a1 && bi2 < ai1)) { a3 = a2; a2 = a1; ai2 = ai1; a1 = b2; ai1 = bi2; }
        else if (b2 < a2 || (b2 == a2 && bi2 < ai2)) { a3 = a2; a2 = b2; ai2 = bi2; }
        else if (b2 < a3) a3 = b2;
        if (b3 < a3) a3 = b3;
    }
    const int row = list[gid];
    int fl = 0;
    if (a2 - a1 < MARGIN_T2) fl = (a3 - a1 < MARGIN_T2) ? 2 : 1;
    idx1o[row] = ai1; idx2o[row] = ai2; flago[row] = fl;
}

// ---------------------------------------------------------------------------
// Kernel 5B/6B (path B, proven): grouped fp32 rescan + merge.
// ---------------------------------------------------------------------------
__global__ __launch_bounds__(256) void rescan_group_kernel(
        const float* __restrict__ X, const float* __restrict__ E,
        const float* __restrict__ enorm,
        const int* __restrict__ list, const int* __restrict__ countp,
        float* __restrict__ pm1, float* __restrict__ pm2, float* __restrict__ pm3,
        int* __restrict__ pi1, int* __restrict__ pi2) {
    const int cnt = countp[0];
    const int rc  = blockIdx.x >> 2;
    const int ks  = blockIdx.x & 3;
    if (rc * GROUP >= cnt) return;
    const int tid = threadIdx.x;
    __shared__ int rows_s[GROUP];
    __shared__ float sm1[256], sm2[256], sm3[256];
    __shared__ int   si1[256], si2[256];
    if (tid < GROUP) {
        int j = rc * GROUP + tid;
        rows_s[tid] = list[j < cnt ? j : cnt - 1];
    }
    __syncthreads();
    int rowsg[GROUP];
#pragma unroll
    for (int rr = 0; rr < GROUP; ++rr)
        rowsg[rr] = __builtin_amdgcn_readfirstlane(rows_s[rr]);

    float m1[GROUP], m2[GROUP], m3[GROUP];
    int   i1[GROUP], i2[GROUP];
#pragma unroll
    for (int rr = 0; rr < GROUP; ++rr) {
        m1[rr] = 3.4e38f; m2[rr] = 3.4e38f; m3[rr] = 3.4e38f;
        i1[rr] = 0x7fffffff; i2[rr] = 0x7fffffff;
    }
    for (int j = 0; j < 8; ++j) {
        const int k = ks * 2048 + j * 256 + tid;
        float acc[GROUP];
#pragma unroll
        for (int rr = 0; rr < GROUP; ++rr) acc[rr] = 0.f;
#pragma unroll 1
        for (int dc = 0; dc < 8; ++dc) {
            float ev[32];
#pragma unroll
            for (int i = 0; i < 32; ++i) ev[i] = E[(size_t)(dc * 32 + i) * NEMB + k];
#pragma unroll
            for (int rr = 0; rr < GROUP; ++rr) {
                const float* xp = X + (size_t)rowsg[rr] * DIM + dc * 32;
#pragma unroll
                for (int i = 0; i < 32; ++i) acc[rr] = fmaf(ev[i], xp[i], acc[rr]);
            }
        }
        const float en = enorm[k];
#pragma unroll
        for (int rr = 0; rr < GROUP; ++rr) {
            float v = fmaf(-2.f, acc[rr], en);
            if (v < m1[rr])      { m3[rr] = m2[rr]; m2[rr] = m1[rr]; i2[rr] = i1[rr]; m1[rr] = v; i1[rr] = k; }
            else if (v < m2[rr]) { m3[rr] = m2[rr]; m2[rr] = v; i2[rr] = k; }
            else if (v < m3[rr]) { m3[rr] = v; }
        }
    }
#pragma unroll 1
    for (int rr = 0; rr < GROUP; ++rr) {
        sm1[tid] = m1[rr]; sm2[tid] = m2[rr]; sm3[tid] = m3[rr];
        si1[tid] = i1[rr]; si2[tid] = i2[rr];
        __syncthreads();
        for (int st = 128; st > 0; st >>= 1) {
            if (tid < st) {
                float a1 = sm1[tid], a2 = sm2[tid], a3 = sm3[tid];
                int   ai1 = si1[tid], ai2 = si2[tid];
                float b1 = sm1[tid + st], b2 = sm2[tid + st], b3 = sm3[tid + st];
                int   bi1 = si1[tid + st], bi2 = si2[tid + st];
                if (b1 < a1 || (b1 == a1 && bi1 < ai1)) { a3 = a2; a2 = a1; ai2 = ai1; a1 = b1; ai1 = bi1; }
                else if (b1 < a2 || (b1 == a2 && bi1 < ai2)) { a3 = a2; a2 = b1; ai2 = bi1; }
                else if (b1 < a3) a3 = b1;
                if (b2 < a1 || (b2 == a1 && bi2 < ai1)) { a3 = a2; a2 = a1; ai2 = ai1; a1 = b2; ai1 = bi2; }
                else if (b2 < a2 || (b2 == a2 && bi2 < ai2)) { a3 = a2; a2 = b2; ai2 = bi2; }
                else if (b2 < a3) a3 = b2;
                if (b3 < a3) a3 = b3;
                sm1[tid] = a1; sm2[tid] = a2; sm3[tid] = a3; si1[tid] = ai1; si2[tid] = ai2;
            }
            __syncthreads();
        }
        if (tid == 0) {
            int jg = rc * GROUP + rr;
            if (jg < cnt) {
                pm1[jg * KSPLIT + ks] = sm1[0]; pm2[jg * KSPLIT + ks] = sm2[0];
                pm3[jg * KSPLIT + ks] = sm3[0];
                pi1[jg * KSPLIT + ks] = si1[0]; pi2[jg * KSPLIT + ks] = si2[0];
            }
        }
        __syncthreads();
    }
}

__global__ void merge_kernel(const int* __restrict__ list, const int* __restrict__ countp,
        const float* __restrict__ pm1, const float* __restrict__ pm2,
        const float* __restrict__ pm3,
        const int* __restrict__ pi1, const int* __restrict__ pi2,
        int* __restrict__ idx1o, int* __restrict__ idx2o, int* __restrict__ flago) {
    const int gid = blockIdx.x * 256 + threadIdx.x;
    if (gid >= countp[0]) return;
    float a1 = 3.4e38f, a2 = 3.4e38f, a3 = 3.4e38f;
    int   ai1 = 0x7fffffff, ai2 = 0x7fffffff;
#pragma unroll
    for (int ks = 0; ks < KSPLIT; ++ks) {
        float b1 = pm1[gid * KSPLIT + ks], b2 = pm2[gid * KSPLIT + ks], b3 = pm3[gid * KSPLIT + ks];
        int   bi1 = pi1[gid * KSPLIT + ks], bi2 = pi2[gid * KSPLIT + ks];
        if (b1 < a1 || (b1 == a1 && bi1 < ai1)) { a3 = a2; a2 = a1; ai2 = ai1; a1 = b1; ai1 = bi1; }
        else if (b1 < a2 || (b1 == a2 && bi1 < ai2)) { a3 = a2; a2 = b1; ai2 = bi1; }
        else if (b1 < a3) a3 = b1;
        if (b2 < a1 || (b2 == a1 && bi2 < ai1)) { a3 = a2; a2 = a1; ai2 = ai1; a1 = b2; ai1 = bi2; }
        else if (b2 < a2 || (b2 == a2 && bi2 < ai2)) { a3 = a2; a2 = b2; ai2 = bi2; }
        else if (b2 < a3) a3 = b2;
        if (b3 < a3) a3 = b3;
    }
    const int row = list[gid];
    int fl = 0;
    if (a2 - a1 < MARGIN_B) fl = (a3 - a1 < MARGIN_B) ? 2 : 1;
    idx1o[row] = ai1; idx2o[row] = ai2; flago[row] = fl;
}

// ---------------------------------------------------------------------------
// Fallback fp32 argmin (round-1, proven) — used only if ws is tiny.
// ---------------------------------------------------------------------------
#define BM 64
#define BN 128
#define DC 32
#define TM 4
#define TN 8
__global__ __launch_bounds__(256, 2) void argmin_f32_kernel(
        const float* __restrict__ X, const float* __restrict__ E,
        const float* __restrict__ enorm,
        int* __restrict__ idx1o, int* __restrict__ idx2o, int* __restrict__ flago) {
    __shared__ float As[DIM * BM];
    __shared__ float Bs[DC * BN];
    const int tid = threadIdx.x;
    const int r0  = blockIdx.x * BM;
    {
        const float4* X4 = (const float4*)(X + (size_t)r0 * DIM);
#pragma unroll
        for (int i = 0; i < 16; ++i) {
            int flat = tid + i * 256;
            int row = flat >> 6, c4 = flat & 63;
            float4 v = X4[flat];
            int d = c4 * 4;
            As[(d + 0) * BM + row] = v.x;
            As[(d + 1) * BM + row] = v.y;
            As[(d + 2) * BM + row] = v.z;
            As[(d + 3) * BM + row] = v.w;
        }
    }
    const int tc = tid & 15;
    const int tr = tid >> 4;
    float m1[TM], m2[TM], m3[TM];
    int   i1[TM], i2[TM];
#pragma unroll
    for (int j = 0; j < TM; ++j) { m1[j] = m2[j] = m3[j] = 3.4e38f; i1[j] = i2[j] = 0x7fffffff; }
    for (int kt = 0; kt < NEMB; kt += BN) {
        float acc[TM][TN];
#pragma unroll
        for (int j = 0; j < TM; ++j)
#pragma unroll
            for (int i = 0; i < TN; ++i) acc[j][i] = 0.f;
        for (int dc = 0; dc < DIM; dc += DC) {
            __syncthreads();
            const float4* E4 = (const float4*)E;
#pragma unroll
            for (int i = 0; i < 4; ++i) {
                int flat = tid + i * 256;
                int dd = flat >> 5, k4 = flat & 31;
                float4 v = E4[(size_t)(dc + dd) * (NEMB / 4) + (kt >> 2) + k4];
                *(float4*)&Bs[dd * BN + k4 * 4] = v;
            }
            __syncthreads();
#pragma unroll
            for (int dd = 0; dd < DC; ++dd) {
                float4 av = *(const float4*)&As[(dc + dd) * BM + tr * TM];
                float4 b0 = *(const float4*)&Bs[dd * BN + tc * TN];
                float4 b1 = *(const float4*)&Bs[dd * BN + tc * TN + 4];
                float a[TM] = {av.x, av.y, av.z, av.w};
                float b[TN] = {b0.x, b0.y, b0.z, b0.w, b1.x, b1.y, b1.z, b1.w};
#pragma unroll
                for (int j = 0; j < TM; ++j)
#pragma unroll
                    for (int i = 0; i < TN; ++i)
                        acc[j][i] = fmaf(a[j], b[i], acc[j][i]);
            }
        }
        float4 e0 = *(const float4*)&enorm[kt + tc * TN];
        float4 e1 = *(const float4*)&enorm[kt + tc * TN + 4];
        float en[TN] = {e0.x, e0.y, e0.z, e0.w, e1.x, e1.y, e1.z, e1.w};
#pragma unroll
        for (int j = 0; j < TM; ++j) {
#pragma unroll
            for (int i = 0; i < TN; ++i) {
                float v = en[i] - 2.f * acc[j][i];
                int k = kt + tc * TN + i;
                if (v < m1[j]) { m3[j] = m2[j]; m2[j] = m1[j]; i2[j] = i1[j]; m1[j] = v; i1[j] = k; }
                else if (v < m2[j]) { m3[j] = m2[j]; m2[j] = v; i2[j] = k; }
                else if (v < m3[j]) { m3[j] = v; }
            }
        }
    }
    __syncthreads();
    float* Mm1 = As;
    float* Mm2 = As + 1024;
    float* Mm3 = As + 2048;
    int*   Mi1 = (int*)(As + 3072);
    int*   Mi2 = (int*)(As + 4096);
#pragma unroll
    for (int j = 0; j < TM; ++j) {
        int row = tr * TM + j;
        Mm1[row * 16 + tc] = m1[j];
        Mm2[row * 16 + tc] = m2[j];
        Mm3[row * 16 + tc] = m3[j];
        Mi1[row * 16 + tc] = i1[j];
        Mi2[row * 16 + tc] = i2[j];
    }
    __syncthreads();
    if (tid < BM) {
        float M1 = 3.4e38f, M2 = 3.4e38f, M3 = 3.4e38f;
        int I1 = 0x7fffffff, I2 = 0x7fffffff;
        for (int e = 0; e < 16; ++e) {
            float v = Mm1[tid * 16 + e]; int vi = Mi1[tid * 16 + e];
            if (v < M1 || (v == M1 && vi < I1)) { M3 = M2; M2 = M1; I2 = I1; M1 = v; I1 = vi; }
            else if (v < M2 || (v == M2 && vi < I2)) { M3 = M2; M2 = v; I2 = vi; }
            else if (v < M3) { M3 = v; }
            v = Mm2[tid * 16 + e]; vi = Mi2[tid * 16 + e];
            if (v < M1 || (v == M1 && vi < I1)) { M3 = M2; M2 = M1; I2 = I1; M1 = v; I1 = vi; }
            else if (v < M2 || (v == M2 && vi < I2)) { M3 = M2; M2 = v; I2 = vi; }
            else if (v < M3) { M3 = v; }
            v = Mm3[tid * 16 + e];
            if (v < M3) M3 = v;
        }
        int r = r0 + tid;
        int fl = 0;
        if (M2 - M1 < MARGIN_B) fl = (M3 - M1 < MARGIN_B) ? 2 : 1;
        idx1o[r] = I1; idx2o[r] = I2; flago[r] = fl;
    }
}

// ---------------------------------------------------------------------------
// Kernel 7: f64 refinement (flag 1 = 2-candidate, 2 = full row rescan).
// ---------------------------------------------------------------------------
__global__ __launch_bounds__(256) void refine_kernel(
        const float* __restrict__ X, const float* __restrict__ E,
        int* __restrict__ idx1o, const int* __restrict__ idx2o,
        const int* __restrict__ flago) {
    __shared__ double redA[256];
    __shared__ double redB[256];
    __shared__ int    redI[256];
    const int tid = threadIdx.x;
    for (int rr = 0; rr < 8; ++rr) {
        int r = blockIdx.x * 8 + rr;
        int flag = flago[r];
        if (flag == 0) continue;
        if (flag == 1) {
            int a = idx1o[r], b = idx2o[r];
            double x  = (double)X[(size_t)r * DIM + tid];
            double ea = (double)E[(size_t)tid * NEMB + a];
            double eb = (double)E[(size_t)tid * NEMB + b];
            redA[tid] = ea * (ea - 2.0 * x);
            redB[tid] = eb * (eb - 2.0 * x);
            __syncthreads();
            for (int s = 128; s > 0; s >>= 1) {
                if (tid < s) { redA[tid] += redA[tid + s]; redB[tid] += redB[tid + s]; }
                __syncthreads();
            }
            if (tid == 0) {
                double sa = redA[0], sb = redB[0];
                idx1o[r] = (sb < sa || (sb == sa && b < a)) ? b : a;
            }
            __syncthreads();
        } else {
            double bm = 1e300; int bi = 0x7fffffff;
            for (int k = tid; k < NEMB; k += 256) {
                double s = 0.0;
                for (int d = 0; d < DIM; ++d) {
                    double e = (double)E[(size_t)d * NEMB + k];
                    double x = (double)X[(size_t)r * DIM + d];
                    s += e * (e - 2.0 * x);
                }
                if (s < bm) { bm = s; bi = k; }
            }
            redA[tid] = bm; redI[tid] = bi;
            __syncthreads();
            for (int s = 128; s > 0; s >>= 1) {
                if (tid < s) {
                    if (redA[tid + s] < redA[tid] ||
                        (redA[tid + s] == redA[tid] && redI[tid + s] < redI[tid])) {
                        redA[tid] = redA[tid + s]; redI[tid] = redI[tid + s];
                    }
                }
                __syncthreads();
            }
            if (tid == 0) idx1o[r] = redI[0];
            __syncthreads();
        }
    }
}

// ---------------------------------------------------------------------------
// Kernel 8: gather + loss partials.  v1: strided E columns (fallback).
// ---------------------------------------------------------------------------
__global__ __launch_bounds__(256) void gather_kernel(
        const float* __restrict__ X, const float* __restrict__ E,
        const int* __restrict__ idx,
        float* __restrict__ outq, float* __restrict__ outidxf,
        double* __restrict__ partials) {
    __shared__ double red[256];
    const int tid = threadIdx.x;
    const int row = blockIdx.x * 4 + (tid >> 6);
    const int d0  = (tid & 63) * 4;
    const int k   = idx[row];
    float4 x = *(const float4*)&X[(size_t)row * DIM + d0];
    float q0 = E[(size_t)(d0 + 0) * NEMB + k];
    float q1 = E[(size_t)(d0 + 1) * NEMB + k];
    float q2 = E[(size_t)(d0 + 2) * NEMB + k];
    float q3 = E[(size_t)(d0 + 3) * NEMB + k];
    float4 q = {q0, q1, q2, q3};
    *(float4*)&outq[(size_t)row * DIM + d0] = q;
    if ((tid & 63) == 0) outidxf[row] = (float)k;
    double s = 0.0, t;
    t = (double)q0 - (double)x.x; s += t * t;
    t = (double)q1 - (double)x.y; s += t * t;
    t = (double)q2 - (double)x.z; s += t * t;
    t = (double)q3 - (double)x.w; s += t * t;
    red[tid] = s;
    __syncthreads();
    for (int st = 128; st > 0; st >>= 1) {
        if (tid < st) red[tid] += red[tid + st];
        __syncthreads();
    }
    if (tid == 0) partials[blockIdx.x] = red[0];
}

// v2: coalesced reads from transposed f32 copy ET32 [8192][256].
__global__ __launch_bounds__(256) void gather2_kernel(
        const float* __restrict__ X, const float* __restrict__ ET32,
        const int* __restrict__ idx,
        float* __restrict__ outq, float* __restrict__ outidxf,
        double* __restrict__ partials) {
    __shared__ double red[256];
    const int tid = threadIdx.x;
    const int row = blockIdx.x * 4 + (tid >> 6);
    const int d0  = (tid & 63) * 4;
    const int k   = idx[row];
    float4 x = *(const float4*)&X[(size_t)row * DIM + d0];
    float4 q = *(const float4*)&ET32[(size_t)k * DIM + d0];   // coalesced row read
    *(float4*)&outq[(size_t)row * DIM + d0] = q;
    if ((tid & 63) == 0) outidxf[row] = (float)k;
    double s = 0.0, t;
    t = (double)q.x - (double)x.x; s += t * t;
    t = (double)q.y - (double)x.y; s += t * t;
    t = (double)q.z - (double)x.z; s += t * t;
    t = (double)q.w - (double)x.w; s += t * t;
    red[tid] = s;
    __syncthreads();
    for (int st = 128; st > 0; st >>= 1) {
        if (tid < st) red[tid] += red[tid + st];
        __syncthreads();
    }
    if (tid == 0) partials[blockIdx.x] = red[0];
}

// ---------------------------------------------------------------------------
// Kernel 9: deterministic final loss reduction.
// ---------------------------------------------------------------------------
__global__ __launch_bounds__(256) void loss_kernel(const double* __restrict__ partials,
                                                   float* __restrict__ outloss) {
    __shared__ double red[256];
    const int tid = threadIdx.x;
    double s = 0.0;
    for (int i = tid; i < N_TOK / 4; i += 256) s += partials[i];
    red[tid] = s;
    __syncthreads();
    for (int st = 128; st > 0; st >>= 1) {
        if (tid < st) red[tid] += red[tid + st];
        __syncthreads();
    }
    if (tid == 0)
        outloss[0] = (float)(0.25 * red[0] / (double)((size_t)N_TOK * DIM));
}

// ---------------------------------------------------------------------------
extern "C" void kernel_launch(void* const* d_in, const int* in_sizes, int n_in,
                              void* d_out, int out_size, void* d_ws, size_t ws_size,
                              hipStream_t stream) {
    const float* X = (const float*)d_in[0];   // [32768, 256]
    const float* E = (const float*)d_in[1];   // [256, 8192]

    float* outq    = (float*)d_out;
    float* outloss = outq + (size_t)N_TOK * DIM;
    float* outidx  = outloss + 1;

    char* base = (char*)d_ws;
    float*  enorm    = (float*)base;                          // 32 KB
    int*    idx1     = (int*)(base + 32768);                  // 128 KB
    int*    idx2     = (int*)(base + 163840);                 // 128 KB
    int*    flag     = (int*)(base + 294912);                 // 128 KB
    double* partials = (double*)(base + 425984);              // 64 KB
    f16*    ET       = (f16*)(base + 524288);                 // 4 MB
    // path B aliases (overlay ET region post-argmin)
    char*   etbase   = base + 524288;
    int*    listB    = (int*)etbase;
    int*    countB   = (int*)(etbase + 131072);
    float*  pm1B     = (float*)(etbase + 132096);
    float*  pm2B     = (float*)(etbase + 132096 + 524288);
    float*  pm3B     = (float*)(etbase + 132096 + 1048576);
    int*    pi1B     = (int*)  (etbase + 132096 + 1572864);
    int*    pi2B     = (int*)  (etbase + 132096 + 2097152);
    // path A extras
    f16*    ETlo     = (f16*)(base + 4718592);                // 4 MB
    int*    listA    = (int*)(base + 8912896);                // 128 KB
    int*    countA   = (int*)(base + 9043968);                // 1 KB
    float*  ET32     = (float*)(base + 9044992);              // 8 MB (optional)
    // path A partial top-3 arrays: scratch in d_out's outq region (32 MB,
    // overwritten by gather afterwards).
    float*  pm1A     = outq;
    float*  pm2A     = outq + 262144;
    float*  pm3A     = outq + 524288;
    int*    pi1A     = (int*)(outq + 786432);
    int*    pi2A     = (int*)(outq + 1048576);
    const size_t NEED_B  = 4718592;
    const size_t NEED_A  = 12190720;
    const size_t NEED_A2 = 9044992 + (size_t)NEMB * DIM * sizeof(float); // 17433600

    enorm_kernel<<<NEMB / 256, 256, 0, stream>>>(E, enorm);
    if (ws_size >= NEED_A) {
        const int wf32 = (ws_size >= NEED_A2) ? 1 : 0;
        cvt3_kernel        <<<512,        256, 0, stream>>>(E, ET, ETlo, ET32, 1, wf32);
        argmin_f16v8_kernel<<<N_TOK / 128, 512, 0, stream>>>(X, ET, enorm, idx1, idx2, flag);
        compact_kernel     <<<1,          256, 0, stream>>>(flag, listA, countA);
        rescan_split_kernel<<<512 * 8,    512, 0, stream>>>(X, ET, ETlo, enorm, listA, countA,
                                                            pm1A, pm2A, pm3A, pi1A, pi2A);
        merge3_kernel      <<<N_TOK / 256, 256, 0, stream>>>(listA, countA, pm1A, pm2A, pm3A,
                                                             pi1A, pi2A, idx1, idx2, flag);
        refine_kernel<<<N_TOK / 8, 256, 0, stream>>>(X, E, idx1, idx2, flag);
        if (wf32)
            gather2_kernel<<<N_TOK / 4, 256, 0, stream>>>(X, ET32, idx1, outq, outidx, partials);
        else
            gather_kernel <<<N_TOK / 4, 256, 0, stream>>>(X, E, idx1, outq, outidx, partials);
    } else if (ws_size >= NEED_B) {
        cvt3_kernel        <<<512,        256, 0, stream>>>(E, ET, ET, (float*)ET, 0, 0);
        argmin_f16v8_kernel<<<N_TOK / 128, 512, 0, stream>>>(X, ET, enorm, idx1, idx2, flag);
        compact_kernel     <<<1,          256, 0, stream>>>(flag, listB, countB);
        rescan_group_kernel<<<(N_TOK / GROUP) * KSPLIT, 256, 0, stream>>>(X, E, enorm, listB, countB,
                                                                          pm1B, pm2B, pm3B, pi1B, pi2B);
        merge_kernel       <<<N_TOK / 256, 256, 0, stream>>>(listB, countB, pm1B, pm2B, pm3B,
                                                             pi1B, pi2B, idx1, idx2, flag);
        refine_kernel<<<N_TOK / 8, 256, 0, stream>>>(X, E, idx1, idx2, flag);
        gather_kernel<<<N_TOK / 4, 256, 0, stream>>>(X, E, idx1, outq, outidx, partials);
    } else {
        argmin_f32_kernel  <<<N_TOK / BM, 256, 0, stream>>>(X, E, enorm, idx1, idx2, flag);
        refine_kernel<<<N_TOK / 8, 256, 0, stream>>>(X, E, idx1, idx2, flag);
        gather_kernel<<<N_TOK / 4, 256, 0, stream>>>(X, E, idx1, outq, outidx, partials);
    }
    loss_kernel  <<<1,         256, 0, stream>>>(partials, outloss);
}

// Round 11
// 299.012 us; speedup vs baseline: 3.5597x; 1.0001x over previous
//
#include <hip/hip_runtime.h>

#define N_TOK 32768
#define DIM   256
#define NEMB  8192

#define MARGIN_A  0.2f    // f16-MFMA tier: provable-trust margin
#define MARGIN_T2 0.008f  // f16-2split tier: worst-case error ~2e-3 -> 2eps < 0.008
#define MARGIN_B  0.0625f // fp32 tier (path B): flag for f64 refine below this
#define GROUP 8
#define KSPLIT 4

typedef _Float16 f16;
typedef __attribute__((ext_vector_type(4))) _Float16 f16x4;
typedef __attribute__((ext_vector_type(8))) _Float16 f16x8;
typedef __attribute__((ext_vector_type(4))) float     f32x4;

// ---------------------------------------------------------------------------
// Kernel 1: per-code squared norms  enorm[k] = sum_d E[d][k]^2   (f32, exact)
// ---------------------------------------------------------------------------
__global__ void enorm_kernel(const float* __restrict__ E, float* __restrict__ enorm) {
    int k = blockIdx.x * blockDim.x + threadIdx.x;
    float s = 0.f;
#pragma unroll 8
    for (int d = 0; d < DIM; ++d) {
        float e = E[d * NEMB + k];
        s = fmaf(e, e, s);
    }
    enorm[k] = s;
}

// ---------------------------------------------------------------------------
// Kernel 2: transpose E [256][8192] f32 -> ET [8192][256] f16 (hi),
// optional ETlo = f16(E - hi), optional ET32 = f32 transposed copy (gather).
// ---------------------------------------------------------------------------
__global__ __launch_bounds__(256) void cvt3_kernel(const float* __restrict__ E,
                                                   f16* __restrict__ ET,
                                                   f16* __restrict__ ETlo,
                                                   float* __restrict__ ET32,
                                                   int wlo, int wf32) {
    __shared__ float shf[64][65];
    const int tid = threadIdx.x;
    const int k0 = (blockIdx.x & 127) * 64;
    const int d0 = (blockIdx.x >> 7) * 64;
#pragma unroll
    for (int i = 0; i < 16; ++i) {
        int flat = i * 256 + tid;
        int k = flat & 63, d = flat >> 6;
        shf[k][d] = E[(size_t)(d0 + d) * NEMB + k0 + k];   // coalesced in k
    }
    __syncthreads();
#pragma unroll
    for (int i = 0; i < 16; ++i) {
        int flat = i * 256 + tid;
        int d = flat & 63, kk = flat >> 6;
        float v = shf[kk][d];
        f16 hi = (f16)v;
        ET[(size_t)(k0 + kk) * DIM + d0 + d] = hi;               // coalesced in d
        if (wlo)  ETlo[(size_t)(k0 + kk) * DIM + d0 + d] = (f16)(v - (float)hi);
        if (wf32) ET32[(size_t)(k0 + kk) * DIM + d0 + d] = v;
    }
}

// ---------------------------------------------------------------------------
__device__ __forceinline__ void gload_lds16(const void* g, void* l) {
    __builtin_amdgcn_global_load_lds(
        (const __attribute__((address_space(1))) unsigned int*)g,
        (__attribute__((address_space(3))) unsigned int*)l, 16, 0, 0);
}

// ---------------------------------------------------------------------------
// Kernel 3: f16 MFMA GEMM-argmin v8.
// = proven v4 compute structure (BM=128, 8 waves, mt=4, one 32KB tile per
// barrier, 2x32KB dbuf) with LDS cut 96KB->64KB: X-stage aliases the dbuf
// region (as in v4) and the merge uses the v7-validated shfl_xor butterfly
// + 6KB LDS instead of v4's 96KB arrays.  64KB LDS + ~124 VGPR => 2 blocks/CU
// (4 waves/SIMD): independent per-block barriers let one block's MFMA cover
// the other's stage-drain and epilogue VALU.  Math identical to v4/v5.
// ---------------------------------------------------------------------------
__global__ __launch_bounds__(512, 2) void argmin_f16v8_kernel(
        const float* __restrict__ X, const f16* __restrict__ ET,
        const float* __restrict__ enorm,
        int* __restrict__ idx1o, int* __restrict__ idx2o, int* __restrict__ flago) {
    __shared__ char smem[65536];   // X-stage [0,64K) -> dbuf 2x32KB; merge [0,6K)

    const int tid = threadIdx.x;          // 0..511
    const int w   = tid >> 6;             // wave 0..7
    const int l   = tid & 63;
    const int l15 = l & 15, l4 = l >> 4;
    const int h   = w & 1;                // row half (64 rows)
    const int cs  = w >> 1;               // code strip (16 codes)
    const int r0  = blockIdx.x * 128;

    // ---- Phase A: stage X rows [r0, r0+128) as f16 [128][256] in LDS ----
    // 128 rows x 64 float4/row = 8192 float4; 512 thr -> 16 iterations.
    {
        const float4* X4 = (const float4*)(X + (size_t)r0 * DIM);
        f16* xs = (f16*)smem;
#pragma unroll
        for (int i = 0; i < 16; ++i) {
            int flat4 = tid + i * 512;            // 0..8191
            float4 v = X4[flat4];                 // coalesced
            int row = flat4 >> 6, d4 = flat4 & 63;
            f16x4 p = {(f16)v.x, (f16)v.y, (f16)v.z, (f16)v.w};
            *(f16x4*)(xs + row * 256 + d4 * 4) = p;
        }
    }
    __syncthreads();

    // ---- A fragments: rows r0 + h*64 + mt*16 + l15 ----
    f16x8 Afr[4][8];
    {
        const f16* xs = (const f16*)smem;
#pragma unroll
        for (int mt = 0; mt < 4; ++mt)
#pragma unroll
            for (int c = 0; c < 8; ++c)
                Afr[mt][c] = *(const f16x8*)(xs + (h * 64 + mt * 16 + l15) * 256 + c * 32 + l4 * 8);
    }
    __syncthreads();   // X region free; dbuf overwrites it

    float m1v[4][4], m2v[4][4];
    int   i1v[4][4];
#pragma unroll
    for (int mt = 0; mt < 4; ++mt)
#pragma unroll
        for (int rg = 0; rg < 4; ++rg) {
            m1v[mt][rg] = 3.4e38f; m2v[mt][rg] = 3.4e38f; i1v[mt][rg] = 0x7fffffff;
        }

    // stage tile kt (64 codes x 256 dims = 32KB): wave w stages codes
    // [w*8, w*8+8): 4 calls x 2 code rows (1KB each), XOR-(code&7) swizzle.
    auto stage = [&](int kt, int buf) {
#pragma unroll
        for (int j = 0; j < 4; ++j) {
            const int code = w * 8 + j * 2 + (l >> 5);         // local code 0..63
            const f16* src = ET + ((size_t)kt * 64 + code) * 256
                               + (((l & 31) ^ (code & 7)) << 3);
            char* dst = smem + buf * 32768 + (w * 8 + j * 2) * 512;  // wave-uniform
            gload_lds16(src, dst);
        }
    };

    const int codeL = cs * 16 + l15;
    stage(0, 0);
    int p = 0;
    for (int kt = 0; kt < 128; ++kt) {
        __syncthreads();                             // buf[p] staged
        if (kt + 1 < 128) stage(kt + 1, p ^ 1);

        f32x4 acc[4];
#pragma unroll
        for (int mt = 0; mt < 4; ++mt) acc[mt] = (f32x4){0.f, 0.f, 0.f, 0.f};

        const f16* bb = (const f16*)(smem + p * 32768);
#pragma unroll
        for (int c = 0; c < 8; ++c) {
            const int g = (c * 4 + l4) ^ (l15 & 7);  // swizzled granule
            f16x8 b = *(const f16x8*)(bb + codeL * 256 + g * 8);
#pragma unroll
            for (int mt = 0; mt < 4; ++mt)
                acc[mt] = __builtin_amdgcn_mfma_f32_16x16x32_f16(Afr[mt][c], b, acc[mt], 0, 0, 0);
        }

        const int code = kt * 64 + codeL;            // ascending per lane
        const float en = enorm[code];
#pragma unroll
        for (int mt = 0; mt < 4; ++mt)
#pragma unroll
            for (int rg = 0; rg < 4; ++rg) {
                float v = fmaf(-2.f, acc[mt][rg], en);
                bool cl = v < m1v[mt][rg];
                m2v[mt][rg] = fminf(m2v[mt][rg], fmaxf(m1v[mt][rg], v));
                i1v[mt][rg] = cl ? code : i1v[mt][rg];
                m1v[mt][rg] = fminf(m1v[mt][rg], v);
            }
        p ^= 1;
    }

    // ---- merge step 1: shfl_xor butterfly over l15 within 16-lane groups ----
#pragma unroll
    for (int off = 1; off < 16; off <<= 1) {
#pragma unroll
        for (int mt = 0; mt < 4; ++mt)
#pragma unroll
            for (int rg = 0; rg < 4; ++rg) {
                float om1 = __shfl_xor(m1v[mt][rg], off);
                int   oi1 = __shfl_xor(i1v[mt][rg], off);
                float om2 = __shfl_xor(m2v[mt][rg], off);
                bool sw = (om1 < m1v[mt][rg]) ||
                          (om1 == m1v[mt][rg] && oi1 < i1v[mt][rg]);
                float hi = sw ? m1v[mt][rg] : om1;
                m1v[mt][rg] = sw ? om1 : m1v[mt][rg];
                i1v[mt][rg] = sw ? oi1 : i1v[mt][rg];
                m2v[mt][rg] = fminf(fminf(m2v[mt][rg], om2), hi);
            }
    }

    // ---- merge step 2: 6KB LDS cross-strip (4 cs) merge ----
    __syncthreads();   // all dbuf reads done; safe to alias [0,6K)
    float* sm1 = (float*)smem;              // [128][4]
    int*   si1 = (int*)(smem + 2048);
    float* sm2 = (float*)(smem + 4096);
    if (l15 == 0) {
#pragma unroll
        for (int mt = 0; mt < 4; ++mt)
#pragma unroll
            for (int rg = 0; rg < 4; ++rg) {
                int row = h * 64 + mt * 16 + l4 * 4 + rg;   // 0..127
                sm1[row * 4 + cs] = m1v[mt][rg];
                si1[row * 4 + cs] = i1v[mt][rg];
                sm2[row * 4 + cs] = m2v[mt][rg];
            }
    }
    __syncthreads();
    if (tid < 128) {
        float M1 = 3.4e38f, M2 = 3.4e38f;
        int   I1 = 0x7fffffff;
#pragma unroll
        for (int e = 0; e < 4; ++e) {
            float v = sm1[tid * 4 + e]; int vi = si1[tid * 4 + e];
            if (v < M1 || (v == M1 && vi < I1)) { M2 = M1; M1 = v; I1 = vi; }
            else M2 = fminf(M2, v);
            M2 = fminf(M2, sm2[tid * 4 + e]);
        }
        int r = r0 + tid;
        idx1o[r] = I1;
        idx2o[r] = I1;
        flago[r] = (M2 - M1 < MARGIN_A) ? -1 : 0;
    }
}

// ---------------------------------------------------------------------------
// Kernel 4: deterministic ordered compaction of flagged (-1) rows.
// ---------------------------------------------------------------------------
__global__ __launch_bounds__(256) void compact_kernel(const int* __restrict__ flago,
        int* __restrict__ list, int* __restrict__ countp) {
    __shared__ int cnts[256], bases[256];
    const int tid = threadIdx.x;
    int c = 0;
    for (int i = 0; i < N_TOK / 256; ++i)
        c += (flago[tid * (N_TOK / 256) + i] < 0) ? 1 : 0;
    cnts[tid] = c;
    __syncthreads();
    if (tid == 0) {
        int run = 0;
        for (int t = 0; t < 256; ++t) { bases[t] = run; run += cnts[t]; }
        countp[0] = run;
    }
    __syncthreads();
    int o = bases[tid];
    for (int i = 0; i < N_TOK / 256; ++i) {
        int r = tid * (N_TOK / 256) + i;
        if (flago[r] < 0) list[o++] = r;
    }
}

// ---------------------------------------------------------------------------
// Kernel 5 (path A): f16 two-split MFMA rescan (top-3 + top-2 idx) — proven.
// ---------------------------------------------------------------------------
__global__ __launch_bounds__(512) void rescan_split_kernel(
        const float* __restrict__ X, const f16* __restrict__ ET,
        const f16* __restrict__ ETlo, const float* __restrict__ enorm,
        const int* __restrict__ list, const int* __restrict__ countp,
        float* __restrict__ pm1, float* __restrict__ pm2, float* __restrict__ pm3,
        int* __restrict__ pi1, int* __restrict__ pi2) {
    __shared__ char smem[131072];
    const int cnt = countp[0];
    const int rb  = blockIdx.x >> 3;
    const int ks  = blockIdx.x & 7;
    if (rb * 64 >= cnt) return;

    const int tid = threadIdx.x, w = tid >> 6, l = tid & 63;
    const int l15 = l & 15, l4 = l >> 4;
    const int h = w & 1, cs = w >> 1;

    f16x8 Ah[2][8], Al[2][8];
#pragma unroll
    for (int mt = 0; mt < 2; ++mt) {
        int jg  = rb * 64 + h * 32 + mt * 16 + l15;
        int row = list[jg < cnt ? jg : cnt - 1];
        const float* xp = X + (size_t)row * DIM + l4 * 8;
#pragma unroll
        for (int c = 0; c < 8; ++c) {
            float4 v0 = *(const float4*)(xp + c * 32);
            float4 v1 = *(const float4*)(xp + c * 32 + 4);
            float xv[8] = {v0.x, v0.y, v0.z, v0.w, v1.x, v1.y, v1.z, v1.w};
            f16x8 hi, lo;
#pragma unroll
            for (int i = 0; i < 8; ++i) {
                f16 hv = (f16)xv[i];
                hi[i] = hv;
                lo[i] = (f16)(xv[i] - (float)hv);
            }
            Ah[mt][c] = hi; Al[mt][c] = lo;
        }
    }

    float m1v[2][4], m2v[2][4], m3v[2][4];
    int   i1v[2][4], i2v[2][4];
#pragma unroll
    for (int mt = 0; mt < 2; ++mt)
#pragma unroll
        for (int rg = 0; rg < 4; ++rg) {
            m1v[mt][rg] = 3.4e38f; m2v[mt][rg] = 3.4e38f; m3v[mt][rg] = 3.4e38f;
            i1v[mt][rg] = 0x7fffffff; i2v[mt][rg] = 0x7fffffff;
        }

    auto stage = [&](int kt, int buf) {        // kt local 0..15
        const int tile = ks * 16 + kt;
#pragma unroll
        for (int j = 0; j < 4; ++j) {
            const int code = w * 8 + j * 2 + (l >> 5);
            size_t off = ((size_t)tile * 64 + code) * 256 + (((l & 31) ^ (code & 7)) << 3);
            char* dsth = smem + buf * 65536 + (w * 8 + j * 2) * 512;
            gload_lds16(ET + off, dsth);
            gload_lds16(ETlo + off, dsth + 32768);
        }
    };

    const int codeL = cs * 16 + l15;
    stage(0, 0);
    int p = 0;
    for (int kt = 0; kt < 16; ++kt) {
        __syncthreads();
        if (kt + 1 < 16) stage(kt + 1, p ^ 1);

        f32x4 acc[2];
#pragma unroll
        for (int mt = 0; mt < 2; ++mt) acc[mt] = (f32x4){0.f, 0.f, 0.f, 0.f};

        const f16* bh = (const f16*)(smem + p * 65536);
        const f16* bl = (const f16*)(smem + p * 65536 + 32768);
#pragma unroll
        for (int c = 0; c < 8; ++c) {
            const int g = (c * 4 + l4) ^ (l15 & 7);
            f16x8 vh = *(const f16x8*)(bh + codeL * 256 + g * 8);
            f16x8 vl = *(const f16x8*)(bl + codeL * 256 + g * 8);
#pragma unroll
            for (int mt = 0; mt < 2; ++mt) {
                acc[mt] = __builtin_amdgcn_mfma_f32_16x16x32_f16(Ah[mt][c], vh, acc[mt], 0, 0, 0);
                acc[mt] = __builtin_amdgcn_mfma_f32_16x16x32_f16(Ah[mt][c], vl, acc[mt], 0, 0, 0);
                acc[mt] = __builtin_amdgcn_mfma_f32_16x16x32_f16(Al[mt][c], vh, acc[mt], 0, 0, 0);
            }
        }

        const int code = (ks * 16 + kt) * 64 + codeL;
        const float en = enorm[code];
#pragma unroll
        for (int mt = 0; mt < 2; ++mt)
#pragma unroll
            for (int rg = 0; rg < 4; ++rg) {
                float v = fmaf(-2.f, acc[mt][rg], en);
                if (v < m1v[mt][rg]) {
                    m3v[mt][rg] = m2v[mt][rg];
                    m2v[mt][rg] = m1v[mt][rg]; i2v[mt][rg] = i1v[mt][rg];
                    m1v[mt][rg] = v;           i1v[mt][rg] = code;
                } else if (v < m2v[mt][rg]) {
                    m3v[mt][rg] = m2v[mt][rg];
                    m2v[mt][rg] = v;           i2v[mt][rg] = code;
                } else if (v < m3v[mt][rg]) {
                    m3v[mt][rg] = v;
                }
            }
        p ^= 1;
    }

    __syncthreads();
    float* Mm1 = (float*)smem;                 // [64][64]
    int*   Mi1 = (int*)(smem + 16384);
    float* Mm2 = (float*)(smem + 32768);
    int*   Mi2 = (int*)(smem + 49152);
    float* Mm3 = (float*)(smem + 65536);
#pragma unroll
    for (int mt = 0; mt < 2; ++mt)
#pragma unroll
        for (int rg = 0; rg < 4; ++rg) {
            int row = h * 32 + mt * 16 + l4 * 4 + rg;   // 0..63
            int e   = cs * 16 + l15;
            Mm1[row * 64 + e] = m1v[mt][rg];
            Mi1[row * 64 + e] = i1v[mt][rg];
            Mm2[row * 64 + e] = m2v[mt][rg];
            Mi2[row * 64 + e] = i2v[mt][rg];
            Mm3[row * 64 + e] = m3v[mt][rg];
        }
    __syncthreads();
    if (tid < 64) {
        float a1 = 3.4e38f, a2 = 3.4e38f, a3 = 3.4e38f;
        int   ai1 = 0x7fffffff, ai2 = 0x7fffffff;
        for (int e = 0; e < 64; ++e) {
            float b1 = Mm1[tid * 64 + e], b2 = Mm2[tid * 64 + e], b3 = Mm3[tid * 64 + e];
            int   bi1 = Mi1[tid * 64 + e], bi2 = Mi2[tid * 64 + e];
            if (b1 < a1 || (b1 == a1 && bi1 < ai1)) { a3 = a2; a2 = a1; ai2 = ai1; a1 = b1; ai1 = bi1; }
            else if (b1 < a2 || (b1 == a2 && bi1 < ai2)) { a3 = a2; a2 = b1; ai2 = bi1; }
            else if (b1 < a3) a3 = b1;
            if (b2 < a1 || (b2 == a1 && bi2 < ai1)) { a3 = a2; a2 = a1; ai2 = ai1; a1 = b2; ai1 = bi2; }
            else if (b2 < a2 || (b2 == a2 && bi2 < ai2)) { a3 = a2; a2 = b2; ai2 = bi2; }
            else if (b2 < a3) a3 = b2;
            if (b3 < a3) a3 = b3;
        }
        int jg = rb * 64 + tid;
        if (jg < cnt) {
            pm1[jg * 8 + ks] = a1; pm2[jg * 8 + ks] = a2; pm3[jg * 8 + ks] = a3;
            pi1[jg * 8 + ks] = ai1; pi2[jg * 8 + ks] = ai2;
        }
    }
}

// ---------------------------------------------------------------------------
// Kernel 6 (path A): merge 8 code-split top-3 partials -> flags 0/1/2.
// ---------------------------------------------------------------------------
__global__ void merge3_kernel(const int* __restrict__ list, const int* __restrict__ countp,
        const float* __restrict__ pm1, const float* __restrict__ pm2,
        const float* __restrict__ pm3,
        const int* __restrict__ pi1, const int* __restrict__ pi2,
        int* __restrict__ idx1o, int* __restrict__ idx2o, int* __restrict__ flago) {
    const int gid = blockIdx.x * 256 + threadIdx.x;
    if (gid >= countp[0]) return;
    float a1 = 3.4e38f, a2 = 3.4e38f, a3 = 3.4e38f;
    int   ai1 = 0x7fffffff, ai2 = 0x7fffffff;
#pragma unroll
    for (int ks = 0; ks < 8; ++ks) {
        float b1 = pm1[gid * 8 + ks], b2 = pm2[gid * 8 + ks], b3 = pm3[gid * 8 + ks];
        int   bi1 = pi1[gid * 8 + ks], bi2 = pi2[gid * 8 + ks];
        if (b1 < a1 || (b1 == a1 && bi1 < ai1)) { a3 = a2; a2 = a1; ai2 = ai1; a1 = b1; ai1 = bi1; }
        else if (b1 < a2 || (b1 == a2 && bi1 < ai2)) { a3 = a2; a2 = b1; ai2 = bi1; }
        else if (b1 < a3) a3 = b1;
        if (b2 < a1 || (b2 == a1 && bi2 < ai1)) { a3 = a2; a2 = a1; ai2 = ai1; a1 = b2; ai1 = bi2; }
        else if (b2 < a2 || (b2 == a2 && bi2 < ai2)) { a3 = a2; a2 = b2; ai2 = bi2; }
        else if (b2 < a3) a3 = b2;
        if (b3 < a3) a3 = b3;
    }
    const int row = list[gid];
    int fl = 0;
    if (a2 - a1 < MARGIN_T2) fl = (a3 - a1 < MARGIN_T2) ? 2 : 1;
    idx1o[row] = ai1; idx2o[row] = ai2; flago[row] = fl;
}

// ---------------------------------------------------------------------------
// Kernel 5B/6B (path B, proven): grouped fp32 rescan + merge.
// ---------------------------------------------------------------------------
__global__ __launch_bounds__(256) void rescan_group_kernel(
        const float* __restrict__ X, const float* __restrict__ E,
        const float* __restrict__ enorm,
        const int* __restrict__ list, const int* __restrict__ countp,
        float* __restrict__ pm1, float* __restrict__ pm2, float* __restrict__ pm3,
        int* __restrict__ pi1, int* __restrict__ pi2) {
    const int cnt = countp[0];
    const int rc  = blockIdx.x >> 2;
    const int ks  = blockIdx.x & 3;
    if (rc * GROUP >= cnt) return;
    const int tid = threadIdx.x;
    __shared__ int rows_s[GROUP];
    __shared__ float sm1[256], sm2[256], sm3[256];
    __shared__ int   si1[256], si2[256];
    if (tid < GROUP) {
        int j = rc * GROUP + tid;
        rows_s[tid] = list[j < cnt ? j : cnt - 1];
    }
    __syncthreads();
    int rowsg[GROUP];
#pragma unroll
    for (int rr = 0; rr < GROUP; ++rr)
        rowsg[rr] = __builtin_amdgcn_readfirstlane(rows_s[rr]);

    float m1[GROUP], m2[GROUP], m3[GROUP];
    int   i1[GROUP], i2[GROUP];
#pragma unroll
    for (int rr = 0; rr < GROUP; ++rr) {
        m1[rr] = 3.4e38f; m2[rr] = 3.4e38f; m3[rr] = 3.4e38f;
        i1[rr] = 0x7fffffff; i2[rr] = 0x7fffffff;
    }
    for (int j = 0; j < 8; ++j) {
        const int k = ks * 2048 + j * 256 + tid;
        float acc[GROUP];
#pragma unroll
        for (int rr = 0; rr < GROUP; ++rr) acc[rr] = 0.f;
#pragma unroll 1
        for (int dc = 0; dc < 8; ++dc) {
            float ev[32];
#pragma unroll
            for (int i = 0; i < 32; ++i) ev[i] = E[(size_t)(dc * 32 + i) * NEMB + k];
#pragma unroll
            for (int rr = 0; rr < GROUP; ++rr) {
                const float* xp = X + (size_t)rowsg[rr] * DIM + dc * 32;
#pragma unroll
                for (int i = 0; i < 32; ++i) acc[rr] = fmaf(ev[i], xp[i], acc[rr]);
            }
        }
        const float en = enorm[k];
#pragma unroll
        for (int rr = 0; rr < GROUP; ++rr) {
            float v = fmaf(-2.f, acc[rr], en);
            if (v < m1[rr])      { m3[rr] = m2[rr]; m2[rr] = m1[rr]; i2[rr] = i1[rr]; m1[rr] = v; i1[rr] = k; }
            else if (v < m2[rr]) { m3[rr] = m2[rr]; m2[rr] = v; i2[rr] = k; }
            else if (v < m3[rr]) { m3[rr] = v; }
        }
    }
#pragma unroll 1
    for (int rr = 0; rr < GROUP; ++rr) {
        sm1[tid] = m1[rr]; sm2[tid] = m2[rr]; sm3[tid] = m3[rr];
        si1[tid] = i1[rr]; si2[tid] = i2[rr];
        __syncthreads();
        for (int st = 128; st > 0; st >>= 1) {
            if (tid < st) {
                float a1 = sm1[tid], a2 = sm2[tid], a3 = sm3[tid];
                int   ai1 = si1[tid], ai2 = si2[tid];
                float b1 = sm1[tid + st], b2 = sm2[tid + st], b3 = sm3[tid + st];
                int   bi1 = si1[tid + st], bi2 = si2[tid + st];
                if (b1 < a1 || (b1 == a1 && bi1 < ai1)) { a3 = a2; a2 = a1; ai2 = ai1; a1 = b1; ai1 = bi1; }
                else if (b1 < a2 || (b1 == a2 && bi1 < ai2)) { a3 = a2; a2 = b1; ai2 = bi1; }
                else if (b1 < a3) a3 = b1;
                if (b2 < a1 || (b2 == a1 && bi2 < ai1)) { a3 = a2; a2 = a1; ai2 = ai1; a1 = b2; ai1 = bi2; }
                else if (b2 < a2 || (b2 == a2 && bi2 < ai2)) { a3 = a2; a2 = b2; ai2 = bi2; }
                else if (b2 < a3) a3 = b2;
                if (b3 < a3) a3 = b3;
                sm1[tid] = a1; sm2[tid] = a2; sm3[tid] = a3; si1[tid] = ai1; si2[tid] = ai2;
            }
            __syncthreads();
        }
        if (tid == 0) {
            int jg = rc * GROUP + rr;
            if (jg < cnt) {
                pm1[jg * KSPLIT + ks] = sm1[0]; pm2[jg * KSPLIT + ks] = sm2[0];
                pm3[jg * KSPLIT + ks] = sm3[0];
                pi1[jg * KSPLIT + ks] = si1[0]; pi2[jg * KSPLIT + ks] = si2[0];
            }
        }
        __syncthreads();
    }
}

__global__ void merge_kernel(const int* __restrict__ list, const int* __restrict__ countp,
        const float* __restrict__ pm1, const float* __restrict__ pm2,
        const float* __restrict__ pm3,
        const int* __restrict__ pi1, const int* __restrict__ pi2,
        int* __restrict__ idx1o, int* __restrict__ idx2o, int* __restrict__ flago) {
    const int gid = blockIdx.x * 256 + threadIdx.x;
    if (gid >= countp[0]) return;
    float a1 = 3.4e38f, a2 = 3.4e38f, a3 = 3.4e38f;
    int   ai1 = 0x7fffffff, ai2 = 0x7fffffff;
#pragma unroll
    for (int ks = 0; ks < KSPLIT; ++ks) {
        float b1 = pm1[gid * KSPLIT + ks], b2 = pm2[gid * KSPLIT + ks], b3 = pm3[gid * KSPLIT + ks];
        int   bi1 = pi1[gid * KSPLIT + ks], bi2 = pi2[gid * KSPLIT + ks];
        if (b1 < a1 || (b1 == a1 && bi1 < ai1)) { a3 = a2; a2 = a1; ai2 = ai1; a1 = b1; ai1 = bi1; }
        else if (b1 < a2 || (b1 == a2 && bi1 < ai2)) { a3 = a2; a2 = b1; ai2 = bi1; }
        else if (b1 < a3) a3 = b1;
        if (b2 < a1 || (b2 == a1 && bi2 < ai1)) { a3 = a2; a2 = a1; ai2 = ai1; a1 = b2; ai1 = bi2; }
        else if (b2 < a2 || (b2 == a2 && bi2 < ai2)) { a3 = a2; a2 = b2; ai2 = bi2; }
        else if (b2 < a3) a3 = b2;
        if (b3 < a3) a3 = b3;
    }
    const int row = list[gid];
    int fl = 0;
    if (a2 - a1 < MARGIN_B) fl = (a3 - a1 < MARGIN_B) ? 2 : 1;
    idx1o[row] = ai1; idx2o[row] = ai2; flago[row] = fl;
}

// ---------------------------------------------------------------------------
// Fallback fp32 argmin (round-1, proven) — used only if ws is tiny.
// ---------------------------------------------------------------------------
#define BM 64
#define BN 128
#define DC 32
#define TM 4
#define TN 8
__global__ __launch_bounds__(256, 2) void argmin_f32_kernel(
        const float* __restrict__ X, const float* __restrict__ E,
        const float* __restrict__ enorm,
        int* __restrict__ idx1o, int* __restrict__ idx2o, int* __restrict__ flago) {
    __shared__ float As[DIM * BM];
    __shared__ float Bs[DC * BN];
    const int tid = threadIdx.x;
    const int r0  = blockIdx.x * BM;
    {
        const float4* X4 = (const float4*)(X + (size_t)r0 * DIM);
#pragma unroll
        for (int i = 0; i < 16; ++i) {
            int flat = tid + i * 256;
            int row = flat >> 6, c4 = flat & 63;
            float4 v = X4[flat];
            int d = c4 * 4;
            As[(d + 0) * BM + row] = v.x;
            As[(d + 1) * BM + row] = v.y;
            As[(d + 2) * BM + row] = v.z;
            As[(d + 3) * BM + row] = v.w;
        }
    }
    const int tc = tid & 15;
    const int tr = tid >> 4;
    float m1[TM], m2[TM], m3[TM];
    int   i1[TM], i2[TM];
#pragma unroll
    for (int j = 0; j < TM; ++j) { m1[j] = m2[j] = m3[j] = 3.4e38f; i1[j] = i2[j] = 0x7fffffff; }
    for (int kt = 0; kt < NEMB; kt += BN) {
        float acc[TM][TN];
#pragma unroll
        for (int j = 0; j < TM; ++j)
#pragma unroll
            for (int i = 0; i < TN; ++i) acc[j][i] = 0.f;
        for (int dc = 0; dc < DIM; dc += DC) {
            __syncthreads();
            const float4* E4 = (const float4*)E;
#pragma unroll
            for (int i = 0; i < 4; ++i) {
                int flat = tid + i * 256;
                int dd = flat >> 5, k4 = flat & 31;
                float4 v = E4[(size_t)(dc + dd) * (NEMB / 4) + (kt >> 2) + k4];
                *(float4*)&Bs[dd * BN + k4 * 4] = v;
            }
            __syncthreads();
#pragma unroll
            for (int dd = 0; dd < DC; ++dd) {
                float4 av = *(const float4*)&As[(dc + dd) * BM + tr * TM];
                float4 b0 = *(const float4*)&Bs[dd * BN + tc * TN];
                float4 b1 = *(const float4*)&Bs[dd * BN + tc * TN + 4];
                float a[TM] = {av.x, av.y, av.z, av.w};
                float b[TN] = {b0.x, b0.y, b0.z, b0.w, b1.x, b1.y, b1.z, b1.w};
#pragma unroll
                for (int j = 0; j < TM; ++j)
#pragma unroll
                    for (int i = 0; i < TN; ++i)
                        acc[j][i] = fmaf(a[j], b[i], acc[j][i]);
            }
        }
        float4 e0 = *(const float4*)&enorm[kt + tc * TN];
        float4 e1 = *(const float4*)&enorm[kt + tc * TN + 4];
        float en[TN] = {e0.x, e0.y, e0.z, e0.w, e1.x, e1.y, e1.z, e1.w};
#pragma unroll
        for (int j = 0; j < TM; ++j) {
#pragma unroll
            for (int i = 0; i < TN; ++i) {
                float v = en[i] - 2.f * acc[j][i];
                int k = kt + tc * TN + i;
                if (v < m1[j]) { m3[j] = m2[j]; m2[j] = m1[j]; i2[j] = i1[j]; m1[j] = v; i1[j] = k; }
                else if (v < m2[j]) { m3[j] = m2[j]; m2[j] = v; i2[j] = k; }
                else if (v < m3[j]) { m3[j] = v; }
            }
        }
    }
    __syncthreads();
    float* Mm1 = As;
    float* Mm2 = As + 1024;
    float* Mm3 = As + 2048;
    int*   Mi1 = (int*)(As + 3072);
    int*   Mi2 = (int*)(As + 4096);
#pragma unroll
    for (int j = 0; j < TM; ++j) {
        int row = tr * TM + j;
        Mm1[row * 16 + tc] = m1[j];
        Mm2[row * 16 + tc] = m2[j];
        Mm3[row * 16 + tc] = m3[j];
        Mi1[row * 16 + tc] = i1[j];
        Mi2[row * 16 + tc] = i2[j];
    }
    __syncthreads();
    if (tid < BM) {
        float M1 = 3.4e38f, M2 = 3.4e38f, M3 = 3.4e38f;
        int I1 = 0x7fffffff, I2 = 0x7fffffff;
        for (int e = 0; e < 16; ++e) {
            float v = Mm1[tid * 16 + e]; int vi = Mi1[tid * 16 + e];
            if (v < M1 || (v == M1 && vi < I1)) { M3 = M2; M2 = M1; I2 = I1; M1 = v; I1 = vi; }
            else if (v < M2 || (v == M2 && vi < I2)) { M3 = M2; M2 = v; I2 = vi; }
            else if (v < M3) { M3 = v; }
            v = Mm2[tid * 16 + e]; vi = Mi2[tid * 16 + e];
            if (v < M1 || (v == M1 && vi < I1)) { M3 = M2; M2 = M1; I2 = I1; M1 = v; I1 = vi; }
            else if (v < M2 || (v == M2 && vi < I2)) { M3 = M2; M2 = v; I2 = vi; }
            else if (v < M3) { M3 = v; }
            v = Mm3[tid * 16 + e];
            if (v < M3) M3 = v;
        }
        int r = r0 + tid;
        int fl = 0;
        if (M2 - M1 < MARGIN_B) fl = (M3 - M1 < MARGIN_B) ? 2 : 1;
        idx1o[r] = I1; idx2o[r] = I2; flago[r] = fl;
    }
}

// ---------------------------------------------------------------------------
// Kernel 7: f64 refinement (flag 1 = 2-candidate, 2 = full row rescan).
// ---------------------------------------------------------------------------
__global__ __launch_bounds__(256) void refine_kernel(
        const float* __restrict__ X, const float* __restrict__ E,
        int* __restrict__ idx1o, const int* __restrict__ idx2o,
        const int* __restrict__ flago) {
    __shared__ double redA[256];
    __shared__ double redB[256];
    __shared__ int    redI[256];
    const int tid = threadIdx.x;
    for (int rr = 0; rr < 8; ++rr) {
        int r = blockIdx.x * 8 + rr;
        int flag = flago[r];
        if (flag == 0) continue;
        if (flag == 1) {
            int a = idx1o[r], b = idx2o[r];
            double x  = (double)X[(size_t)r * DIM + tid];
            double ea = (double)E[(size_t)tid * NEMB + a];
            double eb = (double)E[(size_t)tid * NEMB + b];
            redA[tid] = ea * (ea - 2.0 * x);
            redB[tid] = eb * (eb - 2.0 * x);
            __syncthreads();
            for (int s = 128; s > 0; s >>= 1) {
                if (tid < s) { redA[tid] += redA[tid + s]; redB[tid] += redB[tid + s]; }
                __syncthreads();
            }
            if (tid == 0) {
                double sa = redA[0], sb = redB[0];
                idx1o[r] = (sb < sa || (sb == sa && b < a)) ? b : a;
            }
            __syncthreads();
        } else {
            double bm = 1e300; int bi = 0x7fffffff;
            for (int k = tid; k < NEMB; k += 256) {
                double s = 0.0;
                for (int d = 0; d < DIM; ++d) {
                    double e = (double)E[(size_t)d * NEMB + k];
                    double x = (double)X[(size_t)r * DIM + d];
                    s += e * (e - 2.0 * x);
                }
                if (s < bm) { bm = s; bi = k; }
            }
            redA[tid] = bm; redI[tid] = bi;
            __syncthreads();
            for (int s = 128; s > 0; s >>= 1) {
                if (tid < s) {
                    if (redA[tid + s] < redA[tid] ||
                        (redA[tid + s] == redA[tid] && redI[tid + s] < redI[tid])) {
                        redA[tid] = redA[tid + s]; redI[tid] = redI[tid + s];
                    }
                }
                __syncthreads();
            }
            if (tid == 0) idx1o[r] = redI[0];
            __syncthreads();
        }
    }
}

// ---------------------------------------------------------------------------
// Kernel 8: gather + loss partials.  v1: strided E columns (fallback).
// ---------------------------------------------------------------------------
__global__ __launch_bounds__(256) void gather_kernel(
        const float* __restrict__ X, const float* __restrict__ E,
        const int* __restrict__ idx,
        float* __restrict__ outq, float* __restrict__ outidxf,
        double* __restrict__ partials) {
    __shared__ double red[256];
    const int tid = threadIdx.x;
    const int row = blockIdx.x * 4 + (tid >> 6);
    const int d0  = (tid & 63) * 4;
    const int k   = idx[row];
    float4 x = *(const float4*)&X[(size_t)row * DIM + d0];
    float q0 = E[(size_t)(d0 + 0) * NEMB + k];
    float q1 = E[(size_t)(d0 + 1) * NEMB + k];
    float q2 = E[(size_t)(d0 + 2) * NEMB + k];
    float q3 = E[(size_t)(d0 + 3) * NEMB + k];
    float4 q = {q0, q1, q2, q3};
    *(float4*)&outq[(size_t)row * DIM + d0] = q;
    if ((tid & 63) == 0) outidxf[row] = (float)k;
    double s = 0.0, t;
    t = (double)q0 - (double)x.x; s += t * t;
    t = (double)q1 - (double)x.y; s += t * t;
    t = (double)q2 - (double)x.z; s += t * t;
    t = (double)q3 - (double)x.w; s += t * t;
    red[tid] = s;
    __syncthreads();
    for (int st = 128; st > 0; st >>= 1) {
        if (tid < st) red[tid] += red[tid + st];
        __syncthreads();
    }
    if (tid == 0) partials[blockIdx.x] = red[0];
}

// v2: coalesced reads from transposed f32 copy ET32 [8192][256].
__global__ __launch_bounds__(256) void gather2_kernel(
        const float* __restrict__ X, const float* __restrict__ ET32,
        const int* __restrict__ idx,
        float* __restrict__ outq, float* __restrict__ outidxf,
        double* __restrict__ partials) {
    __shared__ double red[256];
    const int tid = threadIdx.x;
    const int row = blockIdx.x * 4 + (tid >> 6);
    const int d0  = (tid & 63) * 4;
    const int k   = idx[row];
    float4 x = *(const float4*)&X[(size_t)row * DIM + d0];
    float4 q = *(const float4*)&ET32[(size_t)k * DIM + d0];   // coalesced row read
    *(float4*)&outq[(size_t)row * DIM + d0] = q;
    if ((tid & 63) == 0) outidxf[row] = (float)k;
    double s = 0.0, t;
    t = (double)q.x - (double)x.x; s += t * t;
    t = (double)q.y - (double)x.y; s += t * t;
    t = (double)q.z - (double)x.z; s += t * t;
    t = (double)q.w - (double)x.w; s += t * t;
    red[tid] = s;
    __syncthreads();
    for (int st = 128; st > 0; st >>= 1) {
        if (tid < st) red[tid] += red[tid + st];
        __syncthreads();
    }
    if (tid == 0) partials[blockIdx.x] = red[0];
}

// ---------------------------------------------------------------------------
// Kernel 9: deterministic final loss reduction.
// ---------------------------------------------------------------------------
__global__ __launch_bounds__(256) void loss_kernel(const double* __restrict__ partials,
                                                   float* __restrict__ outloss) {
    __shared__ double red[256];
    const int tid = threadIdx.x;
    double s = 0.0;
    for (int i = tid; i < N_TOK / 4; i += 256) s += partials[i];
    red[tid] = s;
    __syncthreads();
    for (int st = 128; st > 0; st >>= 1) {
        if (tid < st) red[tid] += red[tid + st];
        __syncthreads();
    }
    if (tid == 0)
        outloss[0] = (float)(0.25 * red[0] / (double)((size_t)N_TOK * DIM));
}

// ---------------------------------------------------------------------------
extern "C" void kernel_launch(void* const* d_in, const int* in_sizes, int n_in,
                              void* d_out, int out_size, void* d_ws, size_t ws_size,
                              hipStream_t stream) {
    const float* X = (const float*)d_in[0];   // [32768, 256]
    const float* E = (const float*)d_in[1];   // [256, 8192]

    float* outq    = (float*)d_out;
    float* outloss = outq + (size_t)N_TOK * DIM;
    float* outidx  = outloss + 1;

    char* base = (char*)d_ws;
    float*  enorm    = (float*)base;                          // 32 KB
    int*    idx1     = (int*)(base + 32768);                  // 128 KB
    int*    idx2     = (int*)(base + 163840);                 // 128 KB
    int*    flag     = (int*)(base + 294912);                 // 128 KB
    double* partials = (double*)(base + 425984);              // 64 KB
    f16*    ET       = (f16*)(base + 524288);                 // 4 MB
    // path B aliases (overlay ET region post-argmin)
    char*   etbase   = base + 524288;
    int*    listB    = (int*)etbase;
    int*    countB   = (int*)(etbase + 131072);
    float*  pm1B     = (float*)(etbase + 132096);
    float*  pm2B     = (float*)(etbase + 132096 + 524288);
    float*  pm3B     = (float*)(etbase + 132096 + 1048576);
    int*    pi1B     = (int*)  (etbase + 132096 + 1572864);
    int*    pi2B     = (int*)  (etbase + 132096 + 2097152);
    // path A extras
    f16*    ETlo     = (f16*)(base + 4718592);                // 4 MB
    int*    listA    = (int*)(base + 8912896);                // 128 KB
    int*    countA   = (int*)(base + 9043968);                // 1 KB
    float*  ET32     = (float*)(base + 9044992);              // 8 MB (optional)
    // path A partial top-3 arrays: scratch in d_out's outq region (32 MB,
    // overwritten by gather afterwards).
    float*  pm1A     = outq;
    float*  pm2A     = outq + 262144;
    float*  pm3A     = outq + 524288;
    int*    pi1A     = (int*)(outq + 786432);
    int*    pi2A     = (int*)(outq + 1048576);
    const size_t NEED_B  = 4718592;
    const size_t NEED_A  = 12190720;
    const size_t NEED_A2 = 9044992 + (size_t)NEMB * DIM * sizeof(float); // 17433600

    enorm_kernel<<<NEMB / 256, 256, 0, stream>>>(E, enorm);
    if (ws_size >= NEED_A) {
        const int wf32 = (ws_size >= NEED_A2) ? 1 : 0;
        cvt3_kernel        <<<512,        256, 0, stream>>>(E, ET, ETlo, ET32, 1, wf32);
        argmin_f16v8_kernel<<<N_TOK / 128, 512, 0, stream>>>(X, ET, enorm, idx1, idx2, flag);
        compact_kernel     <<<1,          256, 0, stream>>>(flag, listA, countA);
        rescan_split_kernel<<<512 * 8,    512, 0, stream>>>(X, ET, ETlo, enorm, listA, countA,
                                                            pm1A, pm2A, pm3A, pi1A, pi2A);
        merge3_kernel      <<<N_TOK / 256, 256, 0, stream>>>(listA, countA, pm1A, pm2A, pm3A,
                                                             pi1A, pi2A, idx1, idx2, flag);
        refine_kernel<<<N_TOK / 8, 256, 0, stream>>>(X, E, idx1, idx2, flag);
        if (wf32)
            gather2_kernel<<<N_TOK / 4, 256, 0, stream>>>(X, ET32, idx1, outq, outidx, partials);
        else
            gather_kernel <<<N_TOK / 4, 256, 0, stream>>>(X, E, idx1, outq, outidx, partials);
    } else if (ws_size >= NEED_B) {
        cvt3_kernel        <<<512,        256, 0, stream>>>(E, ET, ET, (float*)ET, 0, 0);
        argmin_f16v8_kernel<<<N_TOK / 128, 512, 0, stream>>>(X, ET, enorm, idx1, idx2, flag);
        compact_kernel     <<<1,          256, 0, stream>>>(flag, listB, countB);
        rescan_group_kernel<<<(N_TOK / GROUP) * KSPLIT, 256, 0, stream>>>(X, E, enorm, listB, countB,
                                                                          pm1B, pm2B, pm3B, pi1B, pi2B);
        merge_kernel       <<<N_TOK / 256, 256, 0, stream>>>(listB, countB, pm1B, pm2B, pm3B,
                                                             pi1B, pi2B, idx1, idx2, flag);
        refine_kernel<<<N_TOK / 8, 256, 0, stream>>>(X, E, idx1, idx2, flag);
        gather_kernel<<<N_TOK / 4, 256, 0, stream>>>(X, E, idx1, outq, outidx, partials);
    } else {
        argmin_f32_kernel  <<<N_TOK / BM, 256, 0, stream>>>(X, E, enorm, idx1, idx2, flag);
        refine_kernel<<<N_TOK / 8, 256, 0, stream>>>(X, E, idx1, idx2, flag);
        gather_kernel<<<N_TOK / 4, 256, 0, stream>>>(X, E, idx1, outq, outidx, partials);
    }
    loss_kernel  <<<1,         256, 0, stream>>>(partials, outloss);
}

// Round 12
// 298.571 us; speedup vs baseline: 3.5650x; 1.0015x over previous
//
#include <hip/hip_runtime.h>

#define N_TOK 32768
#define DIM   256
#define NEMB  8192

#define MARGIN_A  0.2f    // f16-MFMA tier: provable-trust margin
#define MARGIN_T2 0.008f  // f16-2split tier: worst-case error ~2e-3 -> 2eps < 0.008
#define MARGIN_B  0.0625f // fp32 tier (path B): flag for f64 refine below this
#define GROUP 8
#define KSPLIT 4

typedef _Float16 f16;
typedef __attribute__((ext_vector_type(4))) _Float16 f16x4;
typedef __attribute__((ext_vector_type(8))) _Float16 f16x8;
typedef __attribute__((ext_vector_type(4))) float     f32x4;

// ---------------------------------------------------------------------------
// Kernel 1: per-code squared norms  enorm[k] = sum_d E[d][k]^2   (f32, exact)
// ---------------------------------------------------------------------------
__global__ void enorm_kernel(const float* __restrict__ E, float* __restrict__ enorm) {
    int k = blockIdx.x * blockDim.x + threadIdx.x;
    float s = 0.f;
#pragma unroll 8
    for (int d = 0; d < DIM; ++d) {
        float e = E[d * NEMB + k];
        s = fmaf(e, e, s);
    }
    enorm[k] = s;
}

// ---------------------------------------------------------------------------
// Kernel 2: transpose E [256][8192] f32 -> ET [8192][256] f16 (hi),
// optional ETlo = f16(E - hi), optional ET32 = f32 transposed copy (gather).
// ---------------------------------------------------------------------------
__global__ __launch_bounds__(256) void cvt3_kernel(const float* __restrict__ E,
                                                   f16* __restrict__ ET,
                                                   f16* __restrict__ ETlo,
                                                   float* __restrict__ ET32,
                                                   int wlo, int wf32) {
    __shared__ float shf[64][65];
    const int tid = threadIdx.x;
    const int k0 = (blockIdx.x & 127) * 64;
    const int d0 = (blockIdx.x >> 7) * 64;
#pragma unroll
    for (int i = 0; i < 16; ++i) {
        int flat = i * 256 + tid;
        int k = flat & 63, d = flat >> 6;
        shf[k][d] = E[(size_t)(d0 + d) * NEMB + k0 + k];   // coalesced in k
    }
    __syncthreads();
#pragma unroll
    for (int i = 0; i < 16; ++i) {
        int flat = i * 256 + tid;
        int d = flat & 63, kk = flat >> 6;
        float v = shf[kk][d];
        f16 hi = (f16)v;
        ET[(size_t)(k0 + kk) * DIM + d0 + d] = hi;               // coalesced in d
        if (wlo)  ETlo[(size_t)(k0 + kk) * DIM + d0 + d] = (f16)(v - (float)hi);
        if (wf32) ET32[(size_t)(k0 + kk) * DIM + d0 + d] = v;
    }
}

// ---------------------------------------------------------------------------
__device__ __forceinline__ void gload_lds16(const void* g, void* l) {
    __builtin_amdgcn_global_load_lds(
        (const __attribute__((address_space(1))) unsigned int*)g,
        (__attribute__((address_space(3))) unsigned int*)l, 16, 0, 0);
}

// ---------------------------------------------------------------------------
// Kernel 3: f16 MFMA GEMM-argmin v8.
// = proven v4 compute structure (BM=128, 8 waves, mt=4, one 32KB tile per
// barrier, 2x32KB dbuf) with LDS cut 96KB->64KB: X-stage aliases the dbuf
// region (as in v4) and the merge uses the v7-validated shfl_xor butterfly
// + 6KB LDS instead of v4's 96KB arrays.  64KB LDS + ~124 VGPR => 2 blocks/CU
// (4 waves/SIMD): independent per-block barriers let one block's MFMA cover
// the other's stage-drain and epilogue VALU.  Math identical to v4/v5.
// ---------------------------------------------------------------------------
__global__ __launch_bounds__(512, 2) void argmin_f16v8_kernel(
        const float* __restrict__ X, const f16* __restrict__ ET,
        const float* __restrict__ enorm,
        int* __restrict__ idx1o, int* __restrict__ idx2o, int* __restrict__ flago) {
    __shared__ char smem[65536];   // X-stage [0,64K) -> dbuf 2x32KB; merge [0,6K)

    const int tid = threadIdx.x;          // 0..511
    const int w   = tid >> 6;             // wave 0..7
    const int l   = tid & 63;
    const int l15 = l & 15, l4 = l >> 4;
    const int h   = w & 1;                // row half (64 rows)
    const int cs  = w >> 1;               // code strip (16 codes)
    const int r0  = blockIdx.x * 128;

    // ---- Phase A: stage X rows [r0, r0+128) as f16 [128][256] in LDS ----
    // 128 rows x 64 float4/row = 8192 float4; 512 thr -> 16 iterations.
    {
        const float4* X4 = (const float4*)(X + (size_t)r0 * DIM);
        f16* xs = (f16*)smem;
#pragma unroll
        for (int i = 0; i < 16; ++i) {
            int flat4 = tid + i * 512;            // 0..8191
            float4 v = X4[flat4];                 // coalesced
            int row = flat4 >> 6, d4 = flat4 & 63;
            f16x4 p = {(f16)v.x, (f16)v.y, (f16)v.z, (f16)v.w};
            *(f16x4*)(xs + row * 256 + d4 * 4) = p;
        }
    }
    __syncthreads();

    // ---- A fragments: rows r0 + h*64 + mt*16 + l15 ----
    f16x8 Afr[4][8];
    {
        const f16* xs = (const f16*)smem;
#pragma unroll
        for (int mt = 0; mt < 4; ++mt)
#pragma unroll
            for (int c = 0; c < 8; ++c)
                Afr[mt][c] = *(const f16x8*)(xs + (h * 64 + mt * 16 + l15) * 256 + c * 32 + l4 * 8);
    }
    __syncthreads();   // X region free; dbuf overwrites it

    float m1v[4][4], m2v[4][4];
    int   i1v[4][4];
#pragma unroll
    for (int mt = 0; mt < 4; ++mt)
#pragma unroll
        for (int rg = 0; rg < 4; ++rg) {
            m1v[mt][rg] = 3.4e38f; m2v[mt][rg] = 3.4e38f; i1v[mt][rg] = 0x7fffffff;
        }

    // stage tile kt (64 codes x 256 dims = 32KB): wave w stages codes
    // [w*8, w*8+8): 4 calls x 2 code rows (1KB each), XOR-(code&7) swizzle.
    auto stage = [&](int kt, int buf) {
#pragma unroll
        for (int j = 0; j < 4; ++j) {
            const int code = w * 8 + j * 2 + (l >> 5);         // local code 0..63
            const f16* src = ET + ((size_t)kt * 64 + code) * 256
                               + (((l & 31) ^ (code & 7)) << 3);
            char* dst = smem + buf * 32768 + (w * 8 + j * 2) * 512;  // wave-uniform
            gload_lds16(src, dst);
        }
    };

    const int codeL = cs * 16 + l15;
    stage(0, 0);
    int p = 0;
    for (int kt = 0; kt < 128; ++kt) {
        __syncthreads();                             // buf[p] staged
        if (kt + 1 < 128) stage(kt + 1, p ^ 1);

        f32x4 acc[4];
#pragma unroll
        for (int mt = 0; mt < 4; ++mt) acc[mt] = (f32x4){0.f, 0.f, 0.f, 0.f};

        const f16* bb = (const f16*)(smem + p * 32768);
#pragma unroll
        for (int c = 0; c < 8; ++c) {
            const int g = (c * 4 + l4) ^ (l15 & 7);  // swizzled granule
            f16x8 b = *(const f16x8*)(bb + codeL * 256 + g * 8);
#pragma unroll
            for (int mt = 0; mt < 4; ++mt)
                acc[mt] = __builtin_amdgcn_mfma_f32_16x16x32_f16(Afr[mt][c], b, acc[mt], 0, 0, 0);
        }

        const int code = kt * 64 + codeL;            // ascending per lane
        const float en = enorm[code];
#pragma unroll
        for (int mt = 0; mt < 4; ++mt)
#pragma unroll
            for (int rg = 0; rg < 4; ++rg) {
                float v = fmaf(-2.f, acc[mt][rg], en);
                bool cl = v < m1v[mt][rg];
                m2v[mt][rg] = fminf(m2v[mt][rg], fmaxf(m1v[mt][rg], v));
                i1v[mt][rg] = cl ? code : i1v[mt][rg];
                m1v[mt][rg] = fminf(m1v[mt][rg], v);
            }
        p ^= 1;
    }

    // ---- merge step 1: shfl_xor butterfly over l15 within 16-lane groups ----
#pragma unroll
    for (int off = 1; off < 16; off <<= 1) {
#pragma unroll
        for (int mt = 0; mt < 4; ++mt)
#pragma unroll
            for (int rg = 0; rg < 4; ++rg) {
                float om1 = __shfl_xor(m1v[mt][rg], off);
                int   oi1 = __shfl_xor(i1v[mt][rg], off);
                float om2 = __shfl_xor(m2v[mt][rg], off);
                bool sw = (om1 < m1v[mt][rg]) ||
                          (om1 == m1v[mt][rg] && oi1 < i1v[mt][rg]);
                float hi = sw ? m1v[mt][rg] : om1;
                m1v[mt][rg] = sw ? om1 : m1v[mt][rg];
                i1v[mt][rg] = sw ? oi1 : i1v[mt][rg];
                m2v[mt][rg] = fminf(fminf(m2v[mt][rg], om2), hi);
            }
    }

    // ---- merge step 2: 6KB LDS cross-strip (4 cs) merge ----
    __syncthreads();   // all dbuf reads done; safe to alias [0,6K)
    float* sm1 = (float*)smem;              // [128][4]
    int*   si1 = (int*)(smem + 2048);
    float* sm2 = (float*)(smem + 4096);
    if (l15 == 0) {
#pragma unroll
        for (int mt = 0; mt < 4; ++mt)
#pragma unroll
            for (int rg = 0; rg < 4; ++rg) {
                int row = h * 64 + mt * 16 + l4 * 4 + rg;   // 0..127
                sm1[row * 4 + cs] = m1v[mt][rg];
                si1[row * 4 + cs] = i1v[mt][rg];
                sm2[row * 4 + cs] = m2v[mt][rg];
            }
    }
    __syncthreads();
    if (tid < 128) {
        float M1 = 3.4e38f, M2 = 3.4e38f;
        int   I1 = 0x7fffffff;
#pragma unroll
        for (int e = 0; e < 4; ++e) {
            float v = sm1[tid * 4 + e]; int vi = si1[tid * 4 + e];
            if (v < M1 || (v == M1 && vi < I1)) { M2 = M1; M1 = v; I1 = vi; }
            else M2 = fminf(M2, v);
            M2 = fminf(M2, sm2[tid * 4 + e]);
        }
        int r = r0 + tid;
        idx1o[r] = I1;
        idx2o[r] = I1;
        flago[r] = (M2 - M1 < MARGIN_A) ? -1 : 0;
    }
}

// ---------------------------------------------------------------------------
// Kernel 4: deterministic ordered compaction of flagged (-1) rows.
// ---------------------------------------------------------------------------
__global__ __launch_bounds__(256) void compact_kernel(const int* __restrict__ flago,
        int* __restrict__ list, int* __restrict__ countp) {
    __shared__ int cnts[256], bases[256];
    const int tid = threadIdx.x;
    int c = 0;
    for (int i = 0; i < N_TOK / 256; ++i)
        c += (flago[tid * (N_TOK / 256) + i] < 0) ? 1 : 0;
    cnts[tid] = c;
    __syncthreads();
    if (tid == 0) {
        int run = 0;
        for (int t = 0; t < 256; ++t) { bases[t] = run; run += cnts[t]; }
        countp[0] = run;
    }
    __syncthreads();
    int o = bases[tid];
    for (int i = 0; i < N_TOK / 256; ++i) {
        int r = tid * (N_TOK / 256) + i;
        if (flago[r] < 0) list[o++] = r;
    }
}

// ---------------------------------------------------------------------------
// Kernel 5 (path A): f16 two-split MFMA rescan (top-3 + top-2 idx) — proven.
// ---------------------------------------------------------------------------
__global__ __launch_bounds__(512) void rescan_split_kernel(
        const float* __restrict__ X, const f16* __restrict__ ET,
        const f16* __restrict__ ETlo, const float* __restrict__ enorm,
        const int* __restrict__ list, const int* __restrict__ countp,
        float* __restrict__ pm1, float* __restrict__ pm2, float* __restrict__ pm3,
        int* __restrict__ pi1, int* __restrict__ pi2) {
    __shared__ char smem[131072];
    const int cnt = countp[0];
    const int rb  = blockIdx.x >> 3;
    const int ks  = blockIdx.x & 7;
    if (rb * 64 >= cnt) return;

    const int tid = threadIdx.x, w = tid >> 6, l = tid & 63;
    const int l15 = l & 15, l4 = l >> 4;
    const int h = w & 1, cs = w >> 1;

    f16x8 Ah[2][8], Al[2][8];
#pragma unroll
    for (int mt = 0; mt < 2; ++mt) {
        int jg  = rb * 64 + h * 32 + mt * 16 + l15;
        int row = list[jg < cnt ? jg : cnt - 1];
        const float* xp = X + (size_t)row * DIM + l4 * 8;
#pragma unroll
        for (int c = 0; c < 8; ++c) {
            float4 v0 = *(const float4*)(xp + c * 32);
            float4 v1 = *(const float4*)(xp + c * 32 + 4);
            float xv[8] = {v0.x, v0.y, v0.z, v0.w, v1.x, v1.y, v1.z, v1.w};
            f16x8 hi, lo;
#pragma unroll
            for (int i = 0; i < 8; ++i) {
                f16 hv = (f16)xv[i];
                hi[i] = hv;
                lo[i] = (f16)(xv[i] - (float)hv);
            }
            Ah[mt][c] = hi; Al[mt][c] = lo;
        }
    }

    float m1v[2][4], m2v[2][4], m3v[2][4];
    int   i1v[2][4], i2v[2][4];
#pragma unroll
    for (int mt = 0; mt < 2; ++mt)
#pragma unroll
        for (int rg = 0; rg < 4; ++rg) {
            m1v[mt][rg] = 3.4e38f; m2v[mt][rg] = 3.4e38f; m3v[mt][rg] = 3.4e38f;
            i1v[mt][rg] = 0x7fffffff; i2v[mt][rg] = 0x7fffffff;
        }

    auto stage = [&](int kt, int buf) {        // kt local 0..15
        const int tile = ks * 16 + kt;
#pragma unroll
        for (int j = 0; j < 4; ++j) {
            const int code = w * 8 + j * 2 + (l >> 5);
            size_t off = ((size_t)tile * 64 + code) * 256 + (((l & 31) ^ (code & 7)) << 3);
            char* dsth = smem + buf * 65536 + (w * 8 + j * 2) * 512;
            gload_lds16(ET + off, dsth);
            gload_lds16(ETlo + off, dsth + 32768);
        }
    };

    const int codeL = cs * 16 + l15;
    stage(0, 0);
    int p = 0;
    for (int kt = 0; kt < 16; ++kt) {
        __syncthreads();
        if (kt + 1 < 16) stage(kt + 1, p ^ 1);

        f32x4 acc[2];
#pragma unroll
        for (int mt = 0; mt < 2; ++mt) acc[mt] = (f32x4){0.f, 0.f, 0.f, 0.f};

        const f16* bh = (const f16*)(smem + p * 65536);
        const f16* bl = (const f16*)(smem + p * 65536 + 32768);
#pragma unroll
        for (int c = 0; c < 8; ++c) {
            const int g = (c * 4 + l4) ^ (l15 & 7);
            f16x8 vh = *(const f16x8*)(bh + codeL * 256 + g * 8);
            f16x8 vl = *(const f16x8*)(bl + codeL * 256 + g * 8);
#pragma unroll
            for (int mt = 0; mt < 2; ++mt) {
                acc[mt] = __builtin_amdgcn_mfma_f32_16x16x32_f16(Ah[mt][c], vh, acc[mt], 0, 0, 0);
                acc[mt] = __builtin_amdgcn_mfma_f32_16x16x32_f16(Ah[mt][c], vl, acc[mt], 0, 0, 0);
                acc[mt] = __builtin_amdgcn_mfma_f32_16x16x32_f16(Al[mt][c], vh, acc[mt], 0, 0, 0);
            }
        }

        const int code = (ks * 16 + kt) * 64 + codeL;
        const float en = enorm[code];
#pragma unroll
        for (int mt = 0; mt < 2; ++mt)
#pragma unroll
            for (int rg = 0; rg < 4; ++rg) {
                float v = fmaf(-2.f, acc[mt][rg], en);
                if (v < m1v[mt][rg]) {
                    m3v[mt][rg] = m2v[mt][rg];
                    m2v[mt][rg] = m1v[mt][rg]; i2v[mt][rg] = i1v[mt][rg];
                    m1v[mt][rg] = v;           i1v[mt][rg] = code;
                } else if (v < m2v[mt][rg]) {
                    m3v[mt][rg] = m2v[mt][rg];
                    m2v[mt][rg] = v;           i2v[mt][rg] = code;
                } else if (v < m3v[mt][rg]) {
                    m3v[mt][rg] = v;
                }
            }
        p ^= 1;
    }

    __syncthreads();
    float* Mm1 = (float*)smem;                 // [64][64]
    int*   Mi1 = (int*)(smem + 16384);
    float* Mm2 = (float*)(smem + 32768);
    int*   Mi2 = (int*)(smem + 49152);
    float* Mm3 = (float*)(smem + 65536);
#pragma unroll
    for (int mt = 0; mt < 2; ++mt)
#pragma unroll
        for (int rg = 0; rg < 4; ++rg) {
            int row = h * 32 + mt * 16 + l4 * 4 + rg;   // 0..63
            int e   = cs * 16 + l15;
            Mm1[row * 64 + e] = m1v[mt][rg];
            Mi1[row * 64 + e] = i1v[mt][rg];
            Mm2[row * 64 + e] = m2v[mt][rg];
            Mi2[row * 64 + e] = i2v[mt][rg];
            Mm3[row * 64 + e] = m3v[mt][rg];
        }
    __syncthreads();
    if (tid < 64) {
        float a1 = 3.4e38f, a2 = 3.4e38f, a3 = 3.4e38f;
        int   ai1 = 0x7fffffff, ai2 = 0x7fffffff;
        for (int e = 0; e < 64; ++e) {
            float b1 = Mm1[tid * 64 + e], b2 = Mm2[tid * 64 + e], b3 = Mm3[tid * 64 + e];
            int   bi1 = Mi1[tid * 64 + e], bi2 = Mi2[tid * 64 + e];
            if (b1 < a1 || (b1 == a1 && bi1 < ai1)) { a3 = a2; a2 = a1; ai2 = ai1; a1 = b1; ai1 = bi1; }
            else if (b1 < a2 || (b1 == a2 && bi1 < ai2)) { a3 = a2; a2 = b1; ai2 = bi1; }
            else if (b1 < a3) a3 = b1;
            if (b2 < a1 || (b2 == a1 && bi2 < ai1)) { a3 = a2; a2 = a1; ai2 = ai1; a1 = b2; ai1 = bi2; }
            else if (b2 < a2 || (b2 == a2 && bi2 < ai2)) { a3 = a2; a2 = b2; ai2 = bi2; }
            else if (b2 < a3) a3 = b2;
            if (b3 < a3) a3 = b3;
        }
        int jg = rb * 64 + tid;
        if (jg < cnt) {
            pm1[jg * 8 + ks] = a1; pm2[jg * 8 + ks] = a2; pm3[jg * 8 + ks] = a3;
            pi1[jg * 8 + ks] = ai1; pi2[jg * 8 + ks] = ai2;
        }
    }
}

// ---------------------------------------------------------------------------
// Kernel 6 (path A): merge 8 code-split top-3 partials -> flags 0/1/2.
// ---------------------------------------------------------------------------
__global__ void merge3_kernel(const int* __restrict__ list, const int* __restrict__ countp,
        const float* __restrict__ pm1, const float* __restrict__ pm2,
        const float* __restrict__ pm3,
        const int* __restrict__ pi1, const int* __restrict__ pi2,
        int* __restrict__ idx1o, int* __restrict__ idx2o, int* __restrict__ flago) {
    const int gid = blockIdx.x * 256 + threadIdx.x;
    if (gid >= countp[0]) return;
    float a1 = 3.4e38f, a2 = 3.4e38f, a3 = 3.4e38f;
    int   ai1 = 0x7fffffff, ai2 = 0x7fffffff;
#pragma unroll
    for (int ks = 0; ks < 8; ++ks) {
        float b1 = pm1[gid * 8 + ks], b2 = pm2[gid * 8 + ks], b3 = pm3[gid * 8 + ks];
        int   bi1 = pi1[gid * 8 + ks], bi2 = pi2[gid * 8 + ks];
        if (b1 < a1 || (b1 == a1 && bi1 < ai1)) { a3 = a2; a2 = a1; ai2 = ai1; a1 = b1; ai1 = bi1; }
        else if (b1 < a2 || (b1 == a2 && bi1 < ai2)) { a3 = a2; a2 = b1; ai2 = bi1; }
        else if (b1 < a3) a3 = b1;
        if (b2 < a1 || (b2 == a1 && bi2 < ai1)) { a3 = a2; a2 = a1; ai2 = ai1; a1 = b2; ai1 = bi2; }
        else if (b2 < a2 || (b2 == a2 && bi2 < ai2)) { a3 = a2; a2 = b2; ai2 = bi2; }
        else if (b2 < a3) a3 = b2;
        if (b3 < a3) a3 = b3;
    }
    const int row = list[gid];
    int fl = 0;
    if (a2 - a1 < MARGIN_T2) fl = (a3 - a1 < MARGIN_T2) ? 2 : 1;
    idx1o[row] = ai1; idx2o[row] = ai2; flago[row] = fl;
}

// ---------------------------------------------------------------------------
// Kernel 5B/6B (path B, proven): grouped fp32 rescan + merge.
// ---------------------------------------------------------------------------
__global__ __launch_bounds__(256) void rescan_group_kernel(
        const float* __restrict__ X, const float* __restrict__ E,
        const float* __restrict__ enorm,
        const int* __restrict__ list, const int* __restrict__ countp,
        float* __restrict__ pm1, float* __restrict__ pm2, float* __restrict__ pm3,
        int* __restrict__ pi1, int* __restrict__ pi2) {
    const int cnt = countp[0];
    const int rc  = blockIdx.x >> 2;
    const int ks  = blockIdx.x & 3;
    if (rc * GROUP >= cnt) return;
    const int tid = threadIdx.x;
    __shared__ int rows_s[GROUP];
    __shared__ float sm1[256], sm2[256], sm3[256];
    __shared__ int   si1[256], si2[256];
    if (tid < GROUP) {
        int j = rc * GROUP + tid;
        rows_s[tid] = list[j < cnt ? j : cnt - 1];
    }
    __syncthreads();
    int rowsg[GROUP];
#pragma unroll
    for (int rr = 0; rr < GROUP; ++rr)
        rowsg[rr] = __builtin_amdgcn_readfirstlane(rows_s[rr]);

    float m1[GROUP], m2[GROUP], m3[GROUP];
    int   i1[GROUP], i2[GROUP];
#pragma unroll
    for (int rr = 0; rr < GROUP; ++rr) {
        m1[rr] = 3.4e38f; m2[rr] = 3.4e38f; m3[rr] = 3.4e38f;
        i1[rr] = 0x7fffffff; i2[rr] = 0x7fffffff;
    }
    for (int j = 0; j < 8; ++j) {
        const int k = ks * 2048 + j * 256 + tid;
        float acc[GROUP];
#pragma unroll
        for (int rr = 0; rr < GROUP; ++rr) acc[rr] = 0.f;
#pragma unroll 1
        for (int dc = 0; dc < 8; ++dc) {
            float ev[32];
#pragma unroll
            for (int i = 0; i < 32; ++i) ev[i] = E[(size_t)(dc * 32 + i) * NEMB + k];
#pragma unroll
            for (int rr = 0; rr < GROUP; ++rr) {
                const float* xp = X + (size_t)rowsg[rr] * DIM + dc * 32;
#pragma unroll
                for (int i = 0; i < 32; ++i) acc[rr] = fmaf(ev[i], xp[i], acc[rr]);
            }
        }
        const float en = enorm[k];
#pragma unroll
        for (int rr = 0; rr < GROUP; ++rr) {
            float v = fmaf(-2.f, acc[rr], en);
            if (v < m1[rr])      { m3[rr] = m2[rr]; m2[rr] = m1[rr]; i2[rr] = i1[rr]; m1[rr] = v; i1[rr] = k; }
            else if (v < m2[rr]) { m3[rr] = m2[rr]; m2[rr] = v; i2[rr] = k; }
            else if (v < m3[rr]) { m3[rr] = v; }
        }
    }
#pragma unroll 1
    for (int rr = 0; rr < GROUP; ++rr) {
        sm1[tid] = m1[rr]; sm2[tid] = m2[rr]; sm3[tid] = m3[rr];
        si1[tid] = i1[rr]; si2[tid] = i2[rr];
        __syncthreads();
        for (int st = 128; st > 0; st >>= 1) {
            if (tid < st) {
                float a1 = sm1[tid], a2 = sm2[tid], a3 = sm3[tid];
                int   ai1 = si1[tid], ai2 = si2[tid];
                float b1 = sm1[tid + st], b2 = sm2[tid + st], b3 = sm3[tid + st];
                int   bi1 = si1[tid + st], bi2 = si2[tid + st];
                if (b1 < a1 || (b1 == a1 && bi1 < ai1)) { a3 = a2; a2 = a1; ai2 = ai1; a1 = b1; ai1 = bi1; }
                else if (b1 < a2 || (b1 == a2 && bi1 < ai2)) { a3 = a2; a2 = b1; ai2 = bi1; }
                else if (b1 < a3) a3 = b1;
                if (b2 < a1 || (b2 == a1 && bi2 < ai1)) { a3 = a2; a2 = a1; ai2 = ai1; a1 = b2; ai1 = bi2; }
                else if (b2 < a2 || (b2 == a2 && bi2 < ai2)) { a3 = a2; a2 = b2; ai2 = bi2; }
                else if (b2 < a3) a3 = b2;
                if (b3 < a3) a3 = b3;
                sm1[tid] = a1; sm2[tid] = a2; sm3[tid] = a3; si1[tid] = ai1; si2[tid] = ai2;
            }
            __syncthreads();
        }
        if (tid == 0) {
            int jg = rc * GROUP + rr;
            if (jg < cnt) {
                pm1[jg * KSPLIT + ks] = sm1[0]; pm2[jg * KSPLIT + ks] = sm2[0];
                pm3[jg * KSPLIT + ks] = sm3[0];
                pi1[jg * KSPLIT + ks] = si1[0]; pi2[jg * KSPLIT + ks] = si2[0];
            }
        }
        __syncthreads();
    }
}

__global__ void merge_kernel(const int* __restrict__ list, const int* __restrict__ countp,
        const float* __restrict__ pm1, const float* __restrict__ pm2,
        const float* __restrict__ pm3,
        const int* __restrict__ pi1, const int* __restrict__ pi2,
        int* __restrict__ idx1o, int* __restrict__ idx2o, int* __restrict__ flago) {
    const int gid = blockIdx.x * 256 + threadIdx.x;
    if (gid >= countp[0]) return;
    float a1 = 3.4e38f, a2 = 3.4e38f, a3 = 3.4e38f;
    int   ai1 = 0x7fffffff, ai2 = 0x7fffffff;
#pragma unroll
    for (int ks = 0; ks < KSPLIT; ++ks) {
        float b1 = pm1[gid * KSPLIT + ks], b2 = pm2[gid * KSPLIT + ks], b3 = pm3[gid * KSPLIT + ks];
        int   bi1 = pi1[gid * KSPLIT + ks], bi2 = pi2[gid * KSPLIT + ks];
        if (b1 < a1 || (b1 == a1 && bi1 < ai1)) { a3 = a2; a2 = a1; ai2 = ai1; a1 = b1; ai1 = bi1; }
        else if (b1 < a2 || (b1 == a2 && bi1 < ai2)) { a3 = a2; a2 = b1; ai2 = bi1; }
        else if (b1 < a3) a3 = b1;
        if (b2 < a1 || (b2 == a1 && bi2 < ai1)) { a3 = a2; a2 = a1; ai2 = ai1; a1 = b2; ai1 = bi2; }
        else if (b2 < a2 || (b2 == a2 && bi2 < ai2)) { a3 = a2; a2 = b2; ai2 = bi2; }
        else if (b2 < a3) a3 = b2;
        if (b3 < a3) a3 = b3;
    }
    const int row = list[gid];
    int fl = 0;
    if (a2 - a1 < MARGIN_B) fl = (a3 - a1 < MARGIN_B) ? 2 : 1;
    idx1o[row] = ai1; idx2o[row] = ai2; flago[row] = fl;
}

// ---------------------------------------------------------------------------
// Fallback fp32 argmin (round-1, proven) — used only if ws is tiny.
// ---------------------------------------------------------------------------
#define BM 64
#define BN 128
#define DC 32
#define TM 4
#define TN 8
__global__ __launch_bounds__(256, 2) void argmin_f32_kernel(
        const float* __restrict__ X, const float* __restrict__ E,
        const float* __restrict__ enorm,
        int* __restrict__ idx1o, int* __restrict__ idx2o, int* __restrict__ flago) {
    __shared__ float As[DIM * BM];
    __shared__ float Bs[DC * BN];
    const int tid = threadIdx.x;
    const int r0  = blockIdx.x * BM;
    {
        const float4* X4 = (const float4*)(X + (size_t)r0 * DIM);
#pragma unroll
        for (int i = 0; i < 16; ++i) {
            int flat = tid + i * 256;
            int row = flat >> 6, c4 = flat & 63;
            float4 v = X4[flat];
            int d = c4 * 4;
            As[(d + 0) * BM + row] = v.x;
            As[(d + 1) * BM + row] = v.y;
            As[(d + 2) * BM + row] = v.z;
            As[(d + 3) * BM + row] = v.w;
        }
    }
    const int tc = tid & 15;
    const int tr = tid >> 4;
    float m1[TM], m2[TM], m3[TM];
    int   i1[TM], i2[TM];
#pragma unroll
    for (int j = 0; j < TM; ++j) { m1[j] = m2[j] = m3[j] = 3.4e38f; i1[j] = i2[j] = 0x7fffffff; }
    for (int kt = 0; kt < NEMB; kt += BN) {
        float acc[TM][TN];
#pragma unroll
        for (int j = 0; j < TM; ++j)
#pragma unroll
            for (int i = 0; i < TN; ++i) acc[j][i] = 0.f;
        for (int dc = 0; dc < DIM; dc += DC) {
            __syncthreads();
            const float4* E4 = (const float4*)E;
#pragma unroll
            for (int i = 0; i < 4; ++i) {
                int flat = tid + i * 256;
                int dd = flat >> 5, k4 = flat & 31;
                float4 v = E4[(size_t)(dc + dd) * (NEMB / 4) + (kt >> 2) + k4];
                *(float4*)&Bs[dd * BN + k4 * 4] = v;
            }
            __syncthreads();
#pragma unroll
            for (int dd = 0; dd < DC; ++dd) {
                float4 av = *(const float4*)&As[(dc + dd) * BM + tr * TM];
                float4 b0 = *(const float4*)&Bs[dd * BN + tc * TN];
                float4 b1 = *(const float4*)&Bs[dd * BN + tc * TN + 4];
                float a[TM] = {av.x, av.y, av.z, av.w};
                float b[TN] = {b0.x, b0.y, b0.z, b0.w, b1.x, b1.y, b1.z, b1.w};
#pragma unroll
                for (int j = 0; j < TM; ++j)
#pragma unroll
                    for (int i = 0; i < TN; ++i)
                        acc[j][i] = fmaf(a[j], b[i], acc[j][i]);
            }
        }
        float4 e0 = *(const float4*)&enorm[kt + tc * TN];
        float4 e1 = *(const float4*)&enorm[kt + tc * TN + 4];
        float en[TN] = {e0.x, e0.y, e0.z, e0.w, e1.x, e1.y, e1.z, e1.w};
#pragma unroll
        for (int j = 0; j < TM; ++j) {
#pragma unroll
            for (int i = 0; i < TN; ++i) {
                float v = en[i] - 2.f * acc[j][i];
                int k = kt + tc * TN + i;
                if (v < m1[j]) { m3[j] = m2[j]; m2[j] = m1[j]; i2[j] = i1[j]; m1[j] = v; i1[j] = k; }
                else if (v < m2[j]) { m3[j] = m2[j]; m2[j] = v; i2[j] = k; }
                else if (v < m3[j]) { m3[j] = v; }
            }
        }
    }
    __syncthreads();
    float* Mm1 = As;
    float* Mm2 = As + 1024;
    float* Mm3 = As + 2048;
    int*   Mi1 = (int*)(As + 3072);
    int*   Mi2 = (int*)(As + 4096);
#pragma unroll
    for (int j = 0; j < TM; ++j) {
        int row = tr * TM + j;
        Mm1[row * 16 + tc] = m1[j];
        Mm2[row * 16 + tc] = m2[j];
        Mm3[row * 16 + tc] = m3[j];
        Mi1[row * 16 + tc] = i1[j];
        Mi2[row * 16 + tc] = i2[j];
    }
    __syncthreads();
    if (tid < BM) {
        float M1 = 3.4e38f, M2 = 3.4e38f, M3 = 3.4e38f;
        int I1 = 0x7fffffff, I2 = 0x7fffffff;
        for (int e = 0; e < 16; ++e) {
            float v = Mm1[tid * 16 + e]; int vi = Mi1[tid * 16 + e];
            if (v < M1 || (v == M1 && vi < I1)) { M3 = M2; M2 = M1; I2 = I1; M1 = v; I1 = vi; }
            else if (v < M2 || (v == M2 && vi < I2)) { M3 = M2; M2 = v; I2 = vi; }
            else if (v < M3) { M3 = v; }
            v = Mm2[tid * 16 + e]; vi = Mi2[tid * 16 + e];
            if (v < M1 || (v == M1 && vi < I1)) { M3 = M2; M2 = M1; I2 = I1; M1 = v; I1 = vi; }
            else if (v < M2 || (v == M2 && vi < I2)) { M3 = M2; M2 = v; I2 = vi; }
            else if (v < M3) { M3 = v; }
            v = Mm3[tid * 16 + e];
            if (v < M3) M3 = v;
        }
        int r = r0 + tid;
        int fl = 0;
        if (M2 - M1 < MARGIN_B) fl = (M3 - M1 < MARGIN_B) ? 2 : 1;
        idx1o[r] = I1; idx2o[r] = I2; flago[r] = fl;
    }
}

// ---------------------------------------------------------------------------
// Kernel 7: f64 refinement (flag 1 = 2-candidate, 2 = full row rescan).
// ---------------------------------------------------------------------------
__global__ __launch_bounds__(256) void refine_kernel(
        const float* __restrict__ X, const float* __restrict__ E,
        int* __restrict__ idx1o, const int* __restrict__ idx2o,
        const int* __restrict__ flago) {
    __shared__ double redA[256];
    __shared__ double redB[256];
    __shared__ int    redI[256];
    const int tid = threadIdx.x;
    for (int rr = 0; rr < 8; ++rr) {
        int r = blockIdx.x * 8 + rr;
        int flag = flago[r];
        if (flag == 0) continue;
        if (flag == 1) {
            int a = idx1o[r], b = idx2o[r];
            double x  = (double)X[(size_t)r * DIM + tid];
            double ea = (double)E[(size_t)tid * NEMB + a];
            double eb = (double)E[(size_t)tid * NEMB + b];
            redA[tid] = ea * (ea - 2.0 * x);
            redB[tid] = eb * (eb - 2.0 * x);
            __syncthreads();
            for (int s = 128; s > 0; s >>= 1) {
                if (tid < s) { redA[tid] += redA[tid + s]; redB[tid] += redB[tid + s]; }
                __syncthreads();
            }
            if (tid == 0) {
                double sa = redA[0], sb = redB[0];
                idx1o[r] = (sb < sa || (sb == sa && b < a)) ? b : a;
            }
            __syncthreads();
        } else {
            double bm = 1e300; int bi = 0x7fffffff;
            for (int k = tid; k < NEMB; k += 256) {
                double s = 0.0;
                for (int d = 0; d < DIM; ++d) {
                    double e = (double)E[(size_t)d * NEMB + k];
                    double x = (double)X[(size_t)r * DIM + d];
                    s += e * (e - 2.0 * x);
                }
                if (s < bm) { bm = s; bi = k; }
            }
            redA[tid] = bm; redI[tid] = bi;
            __syncthreads();
            for (int s = 128; s > 0; s >>= 1) {
                if (tid < s) {
                    if (redA[tid + s] < redA[tid] ||
                        (redA[tid + s] == redA[tid] && redI[tid + s] < redI[tid])) {
                        redA[tid] = redA[tid + s]; redI[tid] = redI[tid + s];
                    }
                }
                __syncthreads();
            }
            if (tid == 0) idx1o[r] = redI[0];
            __syncthreads();
        }
    }
}

// ---------------------------------------------------------------------------
// Kernel 8: gather + loss partials.  v1: strided E columns (fallback).
// ---------------------------------------------------------------------------
__global__ __launch_bounds__(256) void gather_kernel(
        const float* __restrict__ X, const float* __restrict__ E,
        const int* __restrict__ idx,
        float* __restrict__ outq, float* __restrict__ outidxf,
        double* __restrict__ partials) {
    __shared__ double red[256];
    const int tid = threadIdx.x;
    const int row = blockIdx.x * 4 + (tid >> 6);
    const int d0  = (tid & 63) * 4;
    const int k   = idx[row];
    float4 x = *(const float4*)&X[(size_t)row * DIM + d0];
    float q0 = E[(size_t)(d0 + 0) * NEMB + k];
    float q1 = E[(size_t)(d0 + 1) * NEMB + k];
    float q2 = E[(size_t)(d0 + 2) * NEMB + k];
    float q3 = E[(size_t)(d0 + 3) * NEMB + k];
    float4 q = {q0, q1, q2, q3};
    *(float4*)&outq[(size_t)row * DIM + d0] = q;
    if ((tid & 63) == 0) outidxf[row] = (float)k;
    double s = 0.0, t;
    t = (double)q0 - (double)x.x; s += t * t;
    t = (double)q1 - (double)x.y; s += t * t;
    t = (double)q2 - (double)x.z; s += t * t;
    t = (double)q3 - (double)x.w; s += t * t;
    red[tid] = s;
    __syncthreads();
    for (int st = 128; st > 0; st >>= 1) {
        if (tid < st) red[tid] += red[tid + st];
        __syncthreads();
    }
    if (tid == 0) partials[blockIdx.x] = red[0];
}

// v2: coalesced reads from transposed f32 copy ET32 [8192][256].
__global__ __launch_bounds__(256) void gather2_kernel(
        const float* __restrict__ X, const float* __restrict__ ET32,
        const int* __restrict__ idx,
        float* __restrict__ outq, float* __restrict__ outidxf,
        double* __restrict__ partials) {
    __shared__ double red[256];
    const int tid = threadIdx.x;
    const int row = blockIdx.x * 4 + (tid >> 6);
    const int d0  = (tid & 63) * 4;
    const int k   = idx[row];
    float4 x = *(const float4*)&X[(size_t)row * DIM + d0];
    float4 q = *(const float4*)&ET32[(size_t)k * DIM + d0];   // coalesced row read
    *(float4*)&outq[(size_t)row * DIM + d0] = q;
    if ((tid & 63) == 0) outidxf[row] = (float)k;
    double s = 0.0, t;
    t = (double)q.x - (double)x.x; s += t * t;
    t = (double)q.y - (double)x.y; s += t * t;
    t = (double)q.z - (double)x.z; s += t * t;
    t = (double)q.w - (double)x.w; s += t * t;
    red[tid] = s;
    __syncthreads();
    for (int st = 128; st > 0; st >>= 1) {
        if (tid < st) red[tid] += red[tid + st];
        __syncthreads();
    }
    if (tid == 0) partials[blockIdx.x] = red[0];
}

// ---------------------------------------------------------------------------
// Kernel 9: deterministic final loss reduction.
// ---------------------------------------------------------------------------
__global__ __launch_bounds__(256) void loss_kernel(const double* __restrict__ partials,
                                                   float* __restrict__ outloss) {
    __shared__ double red[256];
    const int tid = threadIdx.x;
    double s = 0.0;
    for (int i = tid; i < N_TOK / 4; i += 256) s += partials[i];
    red[tid] = s;
    __syncthreads();
    for (int st = 128; st > 0; st >>= 1) {
        if (tid < st) red[tid] += red[tid + st];
        __syncthreads();
    }
    if (tid == 0)
        outloss[0] = (float)(0.25 * red[0] / (double)((size_t)N_TOK * DIM));
}

// ---------------------------------------------------------------------------
extern "C" void kernel_launch(void* const* d_in, const int* in_sizes, int n_in,
                              void* d_out, int out_size, void* d_ws, size_t ws_size,
                              hipStream_t stream) {
    const float* X = (const float*)d_in[0];   // [32768, 256]
    const float* E = (const float*)d_in[1];   // [256, 8192]

    float* outq    = (float*)d_out;
    float* outloss = outq + (size_t)N_TOK * DIM;
    float* outidx  = outloss + 1;

    char* base = (char*)d_ws;
    float*  enorm    = (float*)base;                          // 32 KB
    int*    idx1     = (int*)(base + 32768);                  // 128 KB
    int*    idx2     = (int*)(base + 163840);                 // 128 KB
    int*    flag     = (int*)(base + 294912);                 // 128 KB
    double* partials = (double*)(base + 425984);              // 64 KB
    f16*    ET       = (f16*)(base + 524288);                 // 4 MB
    // path B aliases (overlay ET region post-argmin)
    char*   etbase   = base + 524288;
    int*    listB    = (int*)etbase;
    int*    countB   = (int*)(etbase + 131072);
    float*  pm1B     = (float*)(etbase + 132096);
    float*  pm2B     = (float*)(etbase + 132096 + 524288);
    float*  pm3B     = (float*)(etbase + 132096 + 1048576);
    int*    pi1B     = (int*)  (etbase + 132096 + 1572864);
    int*    pi2B     = (int*)  (etbase + 132096 + 2097152);
    // path A extras
    f16*    ETlo     = (f16*)(base + 4718592);                // 4 MB
    int*    listA    = (int*)(base + 8912896);                // 128 KB
    int*    countA   = (int*)(base + 9043968);                // 1 KB
    float*  ET32     = (float*)(base + 9044992);              // 8 MB (optional)
    // path A partial top-3 arrays: scratch in d_out's outq region (32 MB,
    // overwritten by gather afterwards).
    float*  pm1A     = outq;
    float*  pm2A     = outq + 262144;
    float*  pm3A     = outq + 524288;
    int*    pi1A     = (int*)(outq + 786432);
    int*    pi2A     = (int*)(outq + 1048576);
    const size_t NEED_B  = 4718592;
    const size_t NEED_A  = 12190720;
    const size_t NEED_A2 = 9044992 + (size_t)NEMB * DIM * sizeof(float); // 17433600

    enorm_kernel<<<NEMB / 256, 256, 0, stream>>>(E, enorm);
    if (ws_size >= NEED_A) {
        const int wf32 = (ws_size >= NEED_A2) ? 1 : 0;
        cvt3_kernel        <<<512,        256, 0, stream>>>(E, ET, ETlo, ET32, 1, wf32);
        argmin_f16v8_kernel<<<N_TOK / 128, 512, 0, stream>>>(X, ET, enorm, idx1, idx2, flag);
        compact_kernel     <<<1,          256, 0, stream>>>(flag, listA, countA);
        rescan_split_kernel<<<512 * 8,    512, 0, stream>>>(X, ET, ETlo, enorm, listA, countA,
                                                            pm1A, pm2A, pm3A, pi1A, pi2A);
        merge3_kernel      <<<N_TOK / 256, 256, 0, stream>>>(listA, countA, pm1A, pm2A, pm3A,
                                                             pi1A, pi2A, idx1, idx2, flag);
        refine_kernel<<<N_TOK / 8, 256, 0, stream>>>(X, E, idx1, idx2, flag);
        if (wf32)
            gather2_kernel<<<N_TOK / 4, 256, 0, stream>>>(X, ET32, idx1, outq, outidx, partials);
        else
            gather_kernel <<<N_TOK / 4, 256, 0, stream>>>(X, E, idx1, outq, outidx, partials);
    } else if (ws_size >= NEED_B) {
        cvt3_kernel        <<<512,        256, 0, stream>>>(E, ET, ET, (float*)ET, 0, 0);
        argmin_f16v8_kernel<<<N_TOK / 128, 512, 0, stream>>>(X, ET, enorm, idx1, idx2, flag);
        compact_kernel     <<<1,          256, 0, stream>>>(flag, listB, countB);
        rescan_group_kernel<<<(N_TOK / GROUP) * KSPLIT, 256, 0, stream>>>(X, E, enorm, listB, countB,
                                                                          pm1B, pm2B, pm3B, pi1B, pi2B);
        merge_kernel       <<<N_TOK / 256, 256, 0, stream>>>(listB, countB, pm1B, pm2B, pm3B,
                                                             pi1B, pi2B, idx1, idx2, flag);
        refine_kernel<<<N_TOK / 8, 256, 0, stream>>>(X, E, idx1, idx2, flag);
        gather_kernel<<<N_TOK / 4, 256, 0, stream>>>(X, E, idx1, outq, outidx, partials);
    } else {
        argmin_f32_kernel  <<<N_TOK / BM, 256, 0, stream>>>(X, E, enorm, idx1, idx2, flag);
        refine_kernel<<<N_TOK / 8, 256, 0, stream>>>(X, E, idx1, idx2, flag);
        gather_kernel<<<N_TOK / 4, 256, 0, stream>>>(X, E, idx1, outq, outidx, partials);
    }
    loss_kernel  <<<1,         256, 0, stream>>>(partials, outloss);
}

// Round 13
// 276.531 us; speedup vs baseline: 3.8491x; 1.0797x over previous
//
#include <hip/hip_runtime.h>

#define N_TOK 32768
#define DIM   256
#define NEMB  8192

#define MARGIN_A  0.2f    // f16-MFMA tier: provable-trust margin
#define MARGIN_T2 0.008f  // f16-2split tier: worst-case error ~2e-3 -> 2eps < 0.008
#define MARGIN_B  0.0625f // fp32 tier (path B): flag for f64 refine below this
#define GROUP 8
#define KSPLIT 4

typedef _Float16 f16;
typedef __attribute__((ext_vector_type(4))) _Float16 f16x4;
typedef __attribute__((ext_vector_type(8))) _Float16 f16x8;
typedef __attribute__((ext_vector_type(4))) float     f32x4;

// ---------------------------------------------------------------------------
// Kernel 1: per-code squared norms  enorm[k] = sum_d E[d][k]^2   (f32, exact)
// ---------------------------------------------------------------------------
__global__ void enorm_kernel(const float* __restrict__ E, float* __restrict__ enorm) {
    int k = blockIdx.x * blockDim.x + threadIdx.x;
    float s = 0.f;
#pragma unroll 8
    for (int d = 0; d < DIM; ++d) {
        float e = E[d * NEMB + k];
        s = fmaf(e, e, s);
    }
    enorm[k] = s;
}

// ---------------------------------------------------------------------------
// Kernel 2: transpose E [256][8192] f32 -> ET [8192][256] f16 (hi),
// optional ETlo = f16(E - hi), optional ET32 = f32 transposed copy (gather).
// Also zeroes the compaction counter (single writer, pre-argmin).
// ---------------------------------------------------------------------------
__global__ __launch_bounds__(256) void cvt3_kernel(const float* __restrict__ E,
                                                   f16* __restrict__ ET,
                                                   f16* __restrict__ ETlo,
                                                   float* __restrict__ ET32,
                                                   int* __restrict__ countz,
                                                   int wlo, int wf32) {
    __shared__ float shf[64][65];
    const int tid = threadIdx.x;
    if (blockIdx.x == 0 && tid == 0) countz[0] = 0;
    const int k0 = (blockIdx.x & 127) * 64;
    const int d0 = (blockIdx.x >> 7) * 64;
#pragma unroll
    for (int i = 0; i < 16; ++i) {
        int flat = i * 256 + tid;
        int k = flat & 63, d = flat >> 6;
        shf[k][d] = E[(size_t)(d0 + d) * NEMB + k0 + k];   // coalesced in k
    }
    __syncthreads();
#pragma unroll
    for (int i = 0; i < 16; ++i) {
        int flat = i * 256 + tid;
        int d = flat & 63, kk = flat >> 6;
        float v = shf[kk][d];
        f16 hi = (f16)v;
        ET[(size_t)(k0 + kk) * DIM + d0 + d] = hi;               // coalesced in d
        if (wlo)  ETlo[(size_t)(k0 + kk) * DIM + d0 + d] = (f16)(v - (float)hi);
        if (wf32) ET32[(size_t)(k0 + kk) * DIM + d0 + d] = v;
    }
}

// ---------------------------------------------------------------------------
__device__ __forceinline__ void gload_lds16(const void* g, void* l) {
    __builtin_amdgcn_global_load_lds(
        (const __attribute__((address_space(1))) unsigned int*)g,
        (__attribute__((address_space(3))) unsigned int*)l, 16, 0, 0);
}

// ---------------------------------------------------------------------------
// Kernel 3: f16 MFMA GEMM-argmin v9.
// 256 blocks x 1024 thr (16 waves = 4 waves/SIMD GUARANTEED in one block).
// BM=128 rows, 64 codes/tile (32KB), 2x32KB dbuf, X-stage aliased (64KB LDS).
// Wave w: row-group h=w&3 (32 rows, mt=2) x code-strip cs=w>>2 (16 codes).
// Afr[2][8]=64 VGPR -> total live ~110 <= 128 cap from (1024,1).
// Same tile/swizzle/epilogue math as proven v4/v5/v8 -> identical results.
// Fused compaction: ballot + atomicAdd (list order provably irrelevant).
// ---------------------------------------------------------------------------
__global__ __launch_bounds__(1024, 1) void argmin_f16v9_kernel(
        const float* __restrict__ X, const f16* __restrict__ ET,
        const float* __restrict__ enorm,
        int* __restrict__ idx1o, int* __restrict__ idx2o, int* __restrict__ flago,
        int* __restrict__ list, int* __restrict__ countp) {
    __shared__ char smem[65536];   // X-stage [0,64K) -> dbuf 2x32KB; merge [0,6K)

    const int tid = threadIdx.x;          // 0..1023
    const int w   = tid >> 6;             // wave 0..15
    const int l   = tid & 63;
    const int l15 = l & 15, l4 = l >> 4;
    const int h   = w & 3;                // row group (32 rows)
    const int cs  = w >> 2;               // code strip (16 codes)
    const int r0  = blockIdx.x * 128;

    // ---- Phase A: stage X rows [r0, r0+128) as f16 [128][256] in LDS ----
    // 128 rows x 64 float4/row = 8192 float4; 1024 thr -> 8 iterations.
    {
        const float4* X4 = (const float4*)(X + (size_t)r0 * DIM);
        f16* xs = (f16*)smem;
#pragma unroll
        for (int i = 0; i < 8; ++i) {
            int flat4 = tid + i * 1024;           // 0..8191
            float4 v = X4[flat4];                 // coalesced
            int row = flat4 >> 6, d4 = flat4 & 63;
            f16x4 p = {(f16)v.x, (f16)v.y, (f16)v.z, (f16)v.w};
            *(f16x4*)(xs + row * 256 + d4 * 4) = p;
        }
    }
    __syncthreads();

    // ---- A fragments: rows r0 + h*32 + mt*16 + l15 ----
    f16x8 Afr[2][8];
    {
        const f16* xs = (const f16*)smem;
#pragma unroll
        for (int mt = 0; mt < 2; ++mt)
#pragma unroll
            for (int c = 0; c < 8; ++c)
                Afr[mt][c] = *(const f16x8*)(xs + (h * 32 + mt * 16 + l15) * 256 + c * 32 + l4 * 8);
    }
    __syncthreads();   // X region free; dbuf overwrites it

    float m1v[2][4], m2v[2][4];
    int   i1v[2][4];
#pragma unroll
    for (int mt = 0; mt < 2; ++mt)
#pragma unroll
        for (int rg = 0; rg < 4; ++rg) {
            m1v[mt][rg] = 3.4e38f; m2v[mt][rg] = 3.4e38f; i1v[mt][rg] = 0x7fffffff;
        }

    // stage tile kt (64 codes x 256 dims = 32KB): wave w stages codes
    // [w*4, w*4+4): 2 calls x 2 code rows (1KB each), XOR-(code&7) swizzle.
    auto stage = [&](int kt, int buf) {
#pragma unroll
        for (int j = 0; j < 2; ++j) {
            const int code = w * 4 + j * 2 + (l >> 5);         // local code 0..63
            const f16* src = ET + ((size_t)kt * 64 + code) * 256
                               + (((l & 31) ^ (code & 7)) << 3);
            char* dst = smem + buf * 32768 + (w * 4 + j * 2) * 512;  // wave-uniform
            gload_lds16(src, dst);
        }
    };

    const int codeL = cs * 16 + l15;
    stage(0, 0);
    int p = 0;
    for (int kt = 0; kt < 128; ++kt) {
        __syncthreads();                             // buf[p] staged
        if (kt + 1 < 128) stage(kt + 1, p ^ 1);

        f32x4 acc[2];
#pragma unroll
        for (int mt = 0; mt < 2; ++mt) acc[mt] = (f32x4){0.f, 0.f, 0.f, 0.f};

        const f16* bb = (const f16*)(smem + p * 32768);
#pragma unroll
        for (int c = 0; c < 8; ++c) {
            const int g = (c * 4 + l4) ^ (l15 & 7);  // swizzled granule
            f16x8 b = *(const f16x8*)(bb + codeL * 256 + g * 8);
#pragma unroll
            for (int mt = 0; mt < 2; ++mt)
                acc[mt] = __builtin_amdgcn_mfma_f32_16x16x32_f16(Afr[mt][c], b, acc[mt], 0, 0, 0);
        }

        const int code = kt * 64 + codeL;            // ascending per lane
        const float en = enorm[code];
#pragma unroll
        for (int mt = 0; mt < 2; ++mt)
#pragma unroll
            for (int rg = 0; rg < 4; ++rg) {
                float v = fmaf(-2.f, acc[mt][rg], en);
                bool cl = v < m1v[mt][rg];
                m2v[mt][rg] = fminf(m2v[mt][rg], fmaxf(m1v[mt][rg], v));
                i1v[mt][rg] = cl ? code : i1v[mt][rg];
                m1v[mt][rg] = fminf(m1v[mt][rg], v);
            }
        p ^= 1;
    }

    // ---- merge step 1: shfl_xor butterfly over l15 within 16-lane groups ----
#pragma unroll
    for (int off = 1; off < 16; off <<= 1) {
#pragma unroll
        for (int mt = 0; mt < 2; ++mt)
#pragma unroll
            for (int rg = 0; rg < 4; ++rg) {
                float om1 = __shfl_xor(m1v[mt][rg], off);
                int   oi1 = __shfl_xor(i1v[mt][rg], off);
                float om2 = __shfl_xor(m2v[mt][rg], off);
                bool sw = (om1 < m1v[mt][rg]) ||
                          (om1 == m1v[mt][rg] && oi1 < i1v[mt][rg]);
                float hi = sw ? m1v[mt][rg] : om1;
                m1v[mt][rg] = sw ? om1 : m1v[mt][rg];
                i1v[mt][rg] = sw ? oi1 : i1v[mt][rg];
                m2v[mt][rg] = fminf(fminf(m2v[mt][rg], om2), hi);
            }
    }

    // ---- merge step 2: 6KB LDS cross-strip (4 cs) merge ----
    __syncthreads();   // all dbuf reads done; safe to alias [0,6K)
    float* sm1 = (float*)smem;              // [128][4]
    int*   si1 = (int*)(smem + 2048);
    float* sm2 = (float*)(smem + 4096);
    if (l15 == 0) {
#pragma unroll
        for (int mt = 0; mt < 2; ++mt)
#pragma unroll
            for (int rg = 0; rg < 4; ++rg) {
                int row = h * 32 + mt * 16 + l4 * 4 + rg;   // 0..127
                sm1[row * 4 + cs] = m1v[mt][rg];
                si1[row * 4 + cs] = i1v[mt][rg];
                sm2[row * 4 + cs] = m2v[mt][rg];
            }
    }
    __syncthreads();
    if (tid < 128) {
        float M1 = 3.4e38f, M2 = 3.4e38f;
        int   I1 = 0x7fffffff;
#pragma unroll
        for (int e = 0; e < 4; ++e) {
            float v = sm1[tid * 4 + e]; int vi = si1[tid * 4 + e];
            if (v < M1 || (v == M1 && vi < I1)) { M2 = M1; M1 = v; I1 = vi; }
            else M2 = fminf(M2, v);
            M2 = fminf(M2, sm2[tid * 4 + e]);
        }
        int r = r0 + tid;
        bool pred = (M2 - M1 < MARGIN_A);
        idx1o[r] = I1;
        idx2o[r] = I1;
        flago[r] = pred ? -1 : 0;
        // fused compaction (order-free: each listed row computed independently)
        unsigned long long mask = __ballot(pred);
        int lane = tid & 63;
        int base = 0;
        if (lane == 0) base = atomicAdd(countp, (int)__popcll(mask));
        base = __shfl(base, 0);
        if (pred) {
            int off = (int)__popcll(mask & ((1ull << lane) - 1ull));
            list[base + off] = r;
        }
    }
}

// ---------------------------------------------------------------------------
// Kernel 4 (path B only): deterministic ordered compaction of flagged rows.
// ---------------------------------------------------------------------------
__global__ __launch_bounds__(256) void compact_kernel(const int* __restrict__ flago,
        int* __restrict__ list, int* __restrict__ countp) {
    __shared__ int cnts[256], bases[256];
    const int tid = threadIdx.x;
    int c = 0;
    for (int i = 0; i < N_TOK / 256; ++i)
        c += (flago[tid * (N_TOK / 256) + i] < 0) ? 1 : 0;
    cnts[tid] = c;
    __syncthreads();
    if (tid == 0) {
        int run = 0;
        for (int t = 0; t < 256; ++t) { bases[t] = run; run += cnts[t]; }
        countp[0] = run;
    }
    __syncthreads();
    int o = bases[tid];
    for (int i = 0; i < N_TOK / 256; ++i) {
        int r = tid * (N_TOK / 256) + i;
        if (flago[r] < 0) list[o++] = r;
    }
}

// ---------------------------------------------------------------------------
// Kernel 5 (path A): f16 two-split MFMA rescan (top-3 + top-2 idx) — proven.
// ---------------------------------------------------------------------------
__global__ __launch_bounds__(512) void rescan_split_kernel(
        const float* __restrict__ X, const f16* __restrict__ ET,
        const f16* __restrict__ ETlo, const float* __restrict__ enorm,
        const int* __restrict__ list, const int* __restrict__ countp,
        float* __restrict__ pm1, float* __restrict__ pm2, float* __restrict__ pm3,
        int* __restrict__ pi1, int* __restrict__ pi2) {
    __shared__ char smem[131072];
    const int cnt = countp[0];
    const int rb  = blockIdx.x >> 3;
    const int ks  = blockIdx.x & 7;
    if (rb * 64 >= cnt) return;

    const int tid = threadIdx.x, w = tid >> 6, l = tid & 63;
    const int l15 = l & 15, l4 = l >> 4;
    const int h = w & 1, cs = w >> 1;

    f16x8 Ah[2][8], Al[2][8];
#pragma unroll
    for (int mt = 0; mt < 2; ++mt) {
        int jg  = rb * 64 + h * 32 + mt * 16 + l15;
        int row = list[jg < cnt ? jg : cnt - 1];
        const float* xp = X + (size_t)row * DIM + l4 * 8;
#pragma unroll
        for (int c = 0; c < 8; ++c) {
            float4 v0 = *(const float4*)(xp + c * 32);
            float4 v1 = *(const float4*)(xp + c * 32 + 4);
            float xv[8] = {v0.x, v0.y, v0.z, v0.w, v1.x, v1.y, v1.z, v1.w};
            f16x8 hi, lo;
#pragma unroll
            for (int i = 0; i < 8; ++i) {
                f16 hv = (f16)xv[i];
                hi[i] = hv;
                lo[i] = (f16)(xv[i] - (float)hv);
            }
            Ah[mt][c] = hi; Al[mt][c] = lo;
        }
    }

    float m1v[2][4], m2v[2][4], m3v[2][4];
    int   i1v[2][4], i2v[2][4];
#pragma unroll
    for (int mt = 0; mt < 2; ++mt)
#pragma unroll
        for (int rg = 0; rg < 4; ++rg) {
            m1v[mt][rg] = 3.4e38f; m2v[mt][rg] = 3.4e38f; m3v[mt][rg] = 3.4e38f;
            i1v[mt][rg] = 0x7fffffff; i2v[mt][rg] = 0x7fffffff;
        }

    auto stage = [&](int kt, int buf) {        // kt local 0..15
        const int tile = ks * 16 + kt;
#pragma unroll
        for (int j = 0; j < 4; ++j) {
            const int code = w * 8 + j * 2 + (l >> 5);
            size_t off = ((size_t)tile * 64 + code) * 256 + (((l & 31) ^ (code & 7)) << 3);
            char* dsth = smem + buf * 65536 + (w * 8 + j * 2) * 512;
            gload_lds16(ET + off, dsth);
            gload_lds16(ETlo + off, dsth + 32768);
        }
    };

    const int codeL = cs * 16 + l15;
    stage(0, 0);
    int p = 0;
    for (int kt = 0; kt < 16; ++kt) {
        __syncthreads();
        if (kt + 1 < 16) stage(kt + 1, p ^ 1);

        f32x4 acc[2];
#pragma unroll
        for (int mt = 0; mt < 2; ++mt) acc[mt] = (f32x4){0.f, 0.f, 0.f, 0.f};

        const f16* bh = (const f16*)(smem + p * 65536);
        const f16* bl = (const f16*)(smem + p * 65536 + 32768);
#pragma unroll
        for (int c = 0; c < 8; ++c) {
            const int g = (c * 4 + l4) ^ (l15 & 7);
            f16x8 vh = *(const f16x8*)(bh + codeL * 256 + g * 8);
            f16x8 vl = *(const f16x8*)(bl + codeL * 256 + g * 8);
#pragma unroll
            for (int mt = 0; mt < 2; ++mt) {
                acc[mt] = __builtin_amdgcn_mfma_f32_16x16x32_f16(Ah[mt][c], vh, acc[mt], 0, 0, 0);
                acc[mt] = __builtin_amdgcn_mfma_f32_16x16x32_f16(Ah[mt][c], vl, acc[mt], 0, 0, 0);
                acc[mt] = __builtin_amdgcn_mfma_f32_16x16x32_f16(Al[mt][c], vh, acc[mt], 0, 0, 0);
            }
        }

        const int code = (ks * 16 + kt) * 64 + codeL;
        const float en = enorm[code];
#pragma unroll
        for (int mt = 0; mt < 2; ++mt)
#pragma unroll
            for (int rg = 0; rg < 4; ++rg) {
                float v = fmaf(-2.f, acc[mt][rg], en);
                if (v < m1v[mt][rg]) {
                    m3v[mt][rg] = m2v[mt][rg];
                    m2v[mt][rg] = m1v[mt][rg]; i2v[mt][rg] = i1v[mt][rg];
                    m1v[mt][rg] = v;           i1v[mt][rg] = code;
                } else if (v < m2v[mt][rg]) {
                    m3v[mt][rg] = m2v[mt][rg];
                    m2v[mt][rg] = v;           i2v[mt][rg] = code;
                } else if (v < m3v[mt][rg]) {
                    m3v[mt][rg] = v;
                }
            }
        p ^= 1;
    }

    __syncthreads();
    float* Mm1 = (float*)smem;                 // [64][64]
    int*   Mi1 = (int*)(smem + 16384);
    float* Mm2 = (float*)(smem + 32768);
    int*   Mi2 = (int*)(smem + 49152);
    float* Mm3 = (float*)(smem + 65536);
#pragma unroll
    for (int mt = 0; mt < 2; ++mt)
#pragma unroll
        for (int rg = 0; rg < 4; ++rg) {
            int row = h * 32 + mt * 16 + l4 * 4 + rg;   // 0..63
            int e   = cs * 16 + l15;
            Mm1[row * 64 + e] = m1v[mt][rg];
            Mi1[row * 64 + e] = i1v[mt][rg];
            Mm2[row * 64 + e] = m2v[mt][rg];
            Mi2[row * 64 + e] = i2v[mt][rg];
            Mm3[row * 64 + e] = m3v[mt][rg];
        }
    __syncthreads();
    if (tid < 64) {
        float a1 = 3.4e38f, a2 = 3.4e38f, a3 = 3.4e38f;
        int   ai1 = 0x7fffffff, ai2 = 0x7fffffff;
        for (int e = 0; e < 64; ++e) {
            float b1 = Mm1[tid * 64 + e], b2 = Mm2[tid * 64 + e], b3 = Mm3[tid * 64 + e];
            int   bi1 = Mi1[tid * 64 + e], bi2 = Mi2[tid * 64 + e];
            if (b1 < a1 || (b1 == a1 && bi1 < ai1)) { a3 = a2; a2 = a1; ai2 = ai1; a1 = b1; ai1 = bi1; }
            else if (b1 < a2 || (b1 == a2 && bi1 < ai2)) { a3 = a2; a2 = b1; ai2 = bi1; }
            else if (b1 < a3) a3 = b1;
            if (b2 < a1 || (b2 == a1 && bi2 < ai1)) { a3 = a2; a2 = a1; ai2 = ai1; a1 = b2; ai1 = bi2; }
            else if (b2 < a2 || (b2 == a2 && bi2 < ai2)) { a3 = a2; a2 = b2; ai2 = bi2; }
            else if (b2 < a3) a3 = b2;
            if (b3 < a3) a3 = b3;
        }
        int jg = rb * 64 + tid;
        if (jg < cnt) {
            pm1[jg * 8 + ks] = a1; pm2[jg * 8 + ks] = a2; pm3[jg * 8 + ks] = a3;
            pi1[jg * 8 + ks] = ai1; pi2[jg * 8 + ks] = ai2;
        }
    }
}

// ---------------------------------------------------------------------------
// Kernel 6 (path A): merge 8 code-split top-3 partials -> flags 0/1/2.
// ---------------------------------------------------------------------------
__global__ void merge3_kernel(const int* __restrict__ list, const int* __restrict__ countp,
        const float* __restrict__ pm1, const float* __restrict__ pm2,
        const float* __restrict__ pm3,
        const int* __restrict__ pi1, const int* __restrict__ pi2,
        int* __restrict__ idx1o, int* __restrict__ idx2o, int* __restrict__ flago) {
    const int gid = blockIdx.x * 256 + threadIdx.x;
    if (gid >= countp[0]) return;
    float a1 = 3.4e38f, a2 = 3.4e38f, a3 = 3.4e38f;
    int   ai1 = 0x7fffffff, ai2 = 0x7fffffff;
#pragma unroll
    for (int ks = 0; ks < 8; ++ks) {
        float b1 = pm1[gid * 8 + ks], b2 = pm2[gid * 8 + ks], b3 = pm3[gid * 8 + ks];
        int   bi1 = pi1[gid * 8 + ks], bi2 = pi2[gid * 8 + ks];
        if (b1 < a1 || (b1 == a1 && bi1 < ai1)) { a3 = a2; a2 = a1; ai2 = ai1; a1 = b1; ai1 = bi1; }
        else if (b1 < a2 || (b1 == a2 && bi1 < ai2)) { a3 = a2; a2 = b1; ai2 = bi1; }
        else if (b1 < a3) a3 = b1;
        if (b2 < a1 || (b2 == a1 && bi2 < ai1)) { a3 = a2; a2 = a1; ai2 = ai1; a1 = b2; ai1 = bi2; }
        else if (b2 < a2 || (b2 == a2 && bi2 < ai2)) { a3 = a2; a2 = b2; ai2 = bi2; }
        else if (b2 < a3) a3 = b2;
        if (b3 < a3) a3 = b3;
    }
    const int row = list[gid];
    int fl = 0;
    if (a2 - a1 < MARGIN_T2) fl = (a3 - a1 < MARGIN_T2) ? 2 : 1;
    idx1o[row] = ai1; idx2o[row] = ai2; flago[row] = fl;
}

// ---------------------------------------------------------------------------
// Kernel 5B/6B (path B, proven): grouped fp32 rescan + merge.
// ---------------------------------------------------------------------------
__global__ __launch_bounds__(256) void rescan_group_kernel(
        const float* __restrict__ X, const float* __restrict__ E,
        const float* __restrict__ enorm,
        const int* __restrict__ list, const int* __restrict__ countp,
        float* __restrict__ pm1, float* __restrict__ pm2, float* __restrict__ pm3,
        int* __restrict__ pi1, int* __restrict__ pi2) {
    const int cnt = countp[0];
    const int rc  = blockIdx.x >> 2;
    const int ks  = blockIdx.x & 3;
    if (rc * GROUP >= cnt) return;
    const int tid = threadIdx.x;
    __shared__ int rows_s[GROUP];
    __shared__ float sm1[256], sm2[256], sm3[256];
    __shared__ int   si1[256], si2[256];
    if (tid < GROUP) {
        int j = rc * GROUP + tid;
        rows_s[tid] = list[j < cnt ? j : cnt - 1];
    }
    __syncthreads();
    int rowsg[GROUP];
#pragma unroll
    for (int rr = 0; rr < GROUP; ++rr)
        rowsg[rr] = __builtin_amdgcn_readfirstlane(rows_s[rr]);

    float m1[GROUP], m2[GROUP], m3[GROUP];
    int   i1[GROUP], i2[GROUP];
#pragma unroll
    for (int rr = 0; rr < GROUP; ++rr) {
        m1[rr] = 3.4e38f; m2[rr] = 3.4e38f; m3[rr] = 3.4e38f;
        i1[rr] = 0x7fffffff; i2[rr] = 0x7fffffff;
    }
    for (int j = 0; j < 8; ++j) {
        const int k = ks * 2048 + j * 256 + tid;
        float acc[GROUP];
#pragma unroll
        for (int rr = 0; rr < GROUP; ++rr) acc[rr] = 0.f;
#pragma unroll 1
        for (int dc = 0; dc < 8; ++dc) {
            float ev[32];
#pragma unroll
            for (int i = 0; i < 32; ++i) ev[i] = E[(size_t)(dc * 32 + i) * NEMB + k];
#pragma unroll
            for (int rr = 0; rr < GROUP; ++rr) {
                const float* xp = X + (size_t)rowsg[rr] * DIM + dc * 32;
#pragma unroll
                for (int i = 0; i < 32; ++i) acc[rr] = fmaf(ev[i], xp[i], acc[rr]);
            }
        }
        const float en = enorm[k];
#pragma unroll
        for (int rr = 0; rr < GROUP; ++rr) {
            float v = fmaf(-2.f, acc[rr], en);
            if (v < m1[rr])      { m3[rr] = m2[rr]; m2[rr] = m1[rr]; i2[rr] = i1[rr]; m1[rr] = v; i1[rr] = k; }
            else if (v < m2[rr]) { m3[rr] = m2[rr]; m2[rr] = v; i2[rr] = k; }
            else if (v < m3[rr]) { m3[rr] = v; }
        }
    }
#pragma unroll 1
    for (int rr = 0; rr < GROUP; ++rr) {
        sm1[tid] = m1[rr]; sm2[tid] = m2[rr]; sm3[tid] = m3[rr];
        si1[tid] = i1[rr]; si2[tid] = i2[rr];
        __syncthreads();
        for (int st = 128; st > 0; st >>= 1) {
            if (tid < st) {
                float a1 = sm1[tid], a2 = sm2[tid], a3 = sm3[tid];
                int   ai1 = si1[tid], ai2 = si2[tid];
                float b1 = sm1[tid + st], b2 = sm2[tid + st], b3 = sm3[tid + st];
                int   bi1 = si1[tid + st], bi2 = si2[tid + st];
                if (b1 < a1 || (b1 == a1 && bi1 < ai1)) { a3 = a2; a2 = a1; ai2 = ai1; a1 = b1; ai1 = bi1; }
                else if (b1 < a2 || (b1 == a2 && bi1 < ai2)) { a3 = a2; a2 = b1; ai2 = bi1; }
                else if (b1 < a3) a3 = b1;
                if (b2 < a1 || (b2 == a1 && bi2 < ai1)) { a3 = a2; a2 = a1; ai2 = ai1; a1 = b2; ai1 = bi2; }
                else if (b2 < a2 || (b2 == a2 && bi2 < ai2)) { a3 = a2; a2 = b2; ai2 = bi2; }
                else if (b2 < a3) a3 = b2;
                if (b3 < a3) a3 = b3;
                sm1[tid] = a1; sm2[tid] = a2; sm3[tid] = a3; si1[tid] = ai1; si2[tid] = ai2;
            }
            __syncthreads();
        }
        if (tid == 0) {
            int jg = rc * GROUP + rr;
            if (jg < cnt) {
                pm1[jg * KSPLIT + ks] = sm1[0]; pm2[jg * KSPLIT + ks] = sm2[0];
                pm3[jg * KSPLIT + ks] = sm3[0];
                pi1[jg * KSPLIT + ks] = si1[0]; pi2[jg * KSPLIT + ks] = si2[0];
            }
        }
        __syncthreads();
    }
}

__global__ void merge_kernel(const int* __restrict__ list, const int* __restrict__ countp,
        const float* __restrict__ pm1, const float* __restrict__ pm2,
        const float* __restrict__ pm3,
        const int* __restrict__ pi1, const int* __restrict__ pi2,
        int* __restrict__ idx1o, int* __restrict__ idx2o, int* __restrict__ flago) {
    const int gid = blockIdx.x * 256 + threadIdx.x;
    if (gid >= countp[0]) return;
    float a1 = 3.4e38f, a2 = 3.4e38f, a3 = 3.4e38f;
    int   ai1 = 0x7fffffff, ai2 = 0x7fffffff;
#pragma unroll
    for (int ks = 0; ks < KSPLIT; ++ks) {
        float b1 = pm1[gid * KSPLIT + ks], b2 = pm2[gid * KSPLIT + ks], b3 = pm3[gid * KSPLIT + ks];
        int   bi1 = pi1[gid * KSPLIT + ks], bi2 = pi2[gid * KSPLIT + ks];
        if (b1 < a1 || (b1 == a1 && bi1 < ai1)) { a3 = a2; a2 = a1; ai2 = ai1; a1 = b1; ai1 = bi1; }
        else if (b1 < a2 || (b1 == a2 && bi1 < ai2)) { a3 = a2; a2 = b1; ai2 = bi1; }
        else if (b1 < a3) a3 = b1;
        if (b2 < a1 || (b2 == a1 && bi2 < ai1)) { a3 = a2; a2 = a1; ai2 = ai1; a1 = b2; ai1 = bi2; }
        else if (b2 < a2 || (b2 == a2 && bi2 < ai2)) { a3 = a2; a2 = b2; ai2 = bi2; }
        else if (b2 < a3) a3 = b2;
        if (b3 < a3) a3 = b3;
    }
    const int row = list[gid];
    int fl = 0;
    if (a2 - a1 < MARGIN_B) fl = (a3 - a1 < MARGIN_B) ? 2 : 1;
    idx1o[row] = ai1; idx2o[row] = ai2; flago[row] = fl;
}

// ---------------------------------------------------------------------------
// Fallback fp32 argmin (round-1, proven) — used only if ws is tiny.
// ---------------------------------------------------------------------------
#define BM 64
#define BN 128
#define DC 32
#define TM 4
#define TN 8
__global__ __launch_bounds__(256, 2) void argmin_f32_kernel(
        const float* __restrict__ X, const float* __restrict__ E,
        const float* __restrict__ enorm,
        int* __restrict__ idx1o, int* __restrict__ idx2o, int* __restrict__ flago) {
    __shared__ float As[DIM * BM];
    __shared__ float Bs[DC * BN];
    const int tid = threadIdx.x;
    const int r0  = blockIdx.x * BM;
    {
        const float4* X4 = (const float4*)(X + (size_t)r0 * DIM);
#pragma unroll
        for (int i = 0; i < 16; ++i) {
            int flat = tid + i * 256;
            int row = flat >> 6, c4 = flat & 63;
            float4 v = X4[flat];
            int d = c4 * 4;
            As[(d + 0) * BM + row] = v.x;
            As[(d + 1) * BM + row] = v.y;
            As[(d + 2) * BM + row] = v.z;
            As[(d + 3) * BM + row] = v.w;
        }
    }
    const int tc = tid & 15;
    const int tr = tid >> 4;
    float m1[TM], m2[TM], m3[TM];
    int   i1[TM], i2[TM];
#pragma unroll
    for (int j = 0; j < TM; ++j) { m1[j] = m2[j] = m3[j] = 3.4e38f; i1[j] = i2[j] = 0x7fffffff; }
    for (int kt = 0; kt < NEMB; kt += BN) {
        float acc[TM][TN];
#pragma unroll
        for (int j = 0; j < TM; ++j)
#pragma unroll
            for (int i = 0; i < TN; ++i) acc[j][i] = 0.f;
        for (int dc = 0; dc < DIM; dc += DC) {
            __syncthreads();
            const float4* E4 = (const float4*)E;
#pragma unroll
            for (int i = 0; i < 4; ++i) {
                int flat = tid + i * 256;
                int dd = flat >> 5, k4 = flat & 31;
                float4 v = E4[(size_t)(dc + dd) * (NEMB / 4) + (kt >> 2) + k4];
                *(float4*)&Bs[dd * BN + k4 * 4] = v;
            }
            __syncthreads();
#pragma unroll
            for (int dd = 0; dd < DC; ++dd) {
                float4 av = *(const float4*)&As[(dc + dd) * BM + tr * TM];
                float4 b0 = *(const float4*)&Bs[dd * BN + tc * TN];
                float4 b1 = *(const float4*)&Bs[dd * BN + tc * TN + 4];
                float a[TM] = {av.x, av.y, av.z, av.w};
                float b[TN] = {b0.x, b0.y, b0.z, b0.w, b1.x, b1.y, b1.z, b1.w};
#pragma unroll
                for (int j = 0; j < TM; ++j)
#pragma unroll
                    for (int i = 0; i < TN; ++i)
                        acc[j][i] = fmaf(a[j], b[i], acc[j][i]);
            }
        }
        float4 e0 = *(const float4*)&enorm[kt + tc * TN];
        float4 e1 = *(const float4*)&enorm[kt + tc * TN + 4];
        float en[TN] = {e0.x, e0.y, e0.z, e0.w, e1.x, e1.y, e1.z, e1.w};
#pragma unroll
        for (int j = 0; j < TM; ++j) {
#pragma unroll
            for (int i = 0; i < TN; ++i) {
                float v = en[i] - 2.f * acc[j][i];
                int k = kt + tc * TN + i;
                if (v < m1[j]) { m3[j] = m2[j]; m2[j] = m1[j]; i2[j] = i1[j]; m1[j] = v; i1[j] = k; }
                else if (v < m2[j]) { m3[j] = m2[j]; m2[j] = v; i2[j] = k; }
                else if (v < m3[j]) { m3[j] = v; }
            }
        }
    }
    __syncthreads();
    float* Mm1 = As;
    float* Mm2 = As + 1024;
    float* Mm3 = As + 2048;
    int*   Mi1 = (int*)(As + 3072);
    int*   Mi2 = (int*)(As + 4096);
#pragma unroll
    for (int j = 0; j < TM; ++j) {
        int row = tr * TM + j;
        Mm1[row * 16 + tc] = m1[j];
        Mm2[row * 16 + tc] = m2[j];
        Mm3[row * 16 + tc] = m3[j];
        Mi1[row * 16 + tc] = i1[j];
        Mi2[row * 16 + tc] = i2[j];
    }
    __syncthreads();
    if (tid < BM) {
        float M1 = 3.4e38f, M2 = 3.4e38f, M3 = 3.4e38f;
        int I1 = 0x7fffffff, I2 = 0x7fffffff;
        for (int e = 0; e < 16; ++e) {
            float v = Mm1[tid * 16 + e]; int vi = Mi1[tid * 16 + e];
            if (v < M1 || (v == M1 && vi < I1)) { M3 = M2; M2 = M1; I2 = I1; M1 = v; I1 = vi; }
            else if (v < M2 || (v == M2 && vi < I2)) { M3 = M2; M2 = v; I2 = vi; }
            else if (v < M3) { M3 = v; }
            v = Mm2[tid * 16 + e]; vi = Mi2[tid * 16 + e];
            if (v < M1 || (v == M1 && vi < I1)) { M3 = M2; M2 = M1; I2 = I1; M1 = v; I1 = vi; }
            else if (v < M2 || (v == M2 && vi < I2)) { M3 = M2; M2 = v; I2 = vi; }
            else if (v < M3) { M3 = v; }
            v = Mm3[tid * 16 + e];
            if (v < M3) M3 = v;
        }
        int r = r0 + tid;
        int fl = 0;
        if (M2 - M1 < MARGIN_B) fl = (M3 - M1 < MARGIN_B) ? 2 : 1;
        idx1o[r] = I1; idx2o[r] = I2; flago[r] = fl;
    }
}

// ---------------------------------------------------------------------------
// Kernel 7: f64 refinement (flag 1 = 2-candidate, 2 = full row rescan).
// ---------------------------------------------------------------------------
__global__ __launch_bounds__(256) void refine_kernel(
        const float* __restrict__ X, const float* __restrict__ E,
        int* __restrict__ idx1o, const int* __restrict__ idx2o,
        const int* __restrict__ flago) {
    __shared__ double redA[256];
    __shared__ double redB[256];
    __shared__ int    redI[256];
    const int tid = threadIdx.x;
    for (int rr = 0; rr < 8; ++rr) {
        int r = blockIdx.x * 8 + rr;
        int flag = flago[r];
        if (flag == 0) continue;
        if (flag == 1) {
            int a = idx1o[r], b = idx2o[r];
            double x  = (double)X[(size_t)r * DIM + tid];
            double ea = (double)E[(size_t)tid * NEMB + a];
            double eb = (double)E[(size_t)tid * NEMB + b];
            redA[tid] = ea * (ea - 2.0 * x);
            redB[tid] = eb * (eb - 2.0 * x);
            __syncthreads();
            for (int s = 128; s > 0; s >>= 1) {
                if (tid < s) { redA[tid] += redA[tid + s]; redB[tid] += redB[tid + s]; }
                __syncthreads();
            }
            if (tid == 0) {
                double sa = redA[0], sb = redB[0];
                idx1o[r] = (sb < sa || (sb == sa && b < a)) ? b : a;
            }
            __syncthreads();
        } else {
            double bm = 1e300; int bi = 0x7fffffff;
            for (int k = tid; k < NEMB; k += 256) {
                double s = 0.0;
                for (int d = 0; d < DIM; ++d) {
                    double e = (double)E[(size_t)d * NEMB + k];
                    double x = (double)X[(size_t)r * DIM + d];
                    s += e * (e - 2.0 * x);
                }
                if (s < bm) { bm = s; bi = k; }
            }
            redA[tid] = bm; redI[tid] = bi;
            __syncthreads();
            for (int s = 128; s > 0; s >>= 1) {
                if (tid < s) {
                    if (redA[tid + s] < redA[tid] ||
                        (redA[tid + s] == redA[tid] && redI[tid + s] < redI[tid])) {
                        redA[tid] = redA[tid + s]; redI[tid] = redI[tid + s];
                    }
                }
                __syncthreads();
            }
            if (tid == 0) idx1o[r] = redI[0];
            __syncthreads();
        }
    }
}

// ---------------------------------------------------------------------------
// Kernel 8: gather + loss partials.  v1: strided E columns (fallback).
// ---------------------------------------------------------------------------
__global__ __launch_bounds__(256) void gather_kernel(
        const float* __restrict__ X, const float* __restrict__ E,
        const int* __restrict__ idx,
        float* __restrict__ outq, float* __restrict__ outidxf,
        double* __restrict__ partials) {
    __shared__ double red[256];
    const int tid = threadIdx.x;
    const int row = blockIdx.x * 4 + (tid >> 6);
    const int d0  = (tid & 63) * 4;
    const int k   = idx[row];
    float4 x = *(const float4*)&X[(size_t)row * DIM + d0];
    float q0 = E[(size_t)(d0 + 0) * NEMB + k];
    float q1 = E[(size_t)(d0 + 1) * NEMB + k];
    float q2 = E[(size_t)(d0 + 2) * NEMB + k];
    float q3 = E[(size_t)(d0 + 3) * NEMB + k];
    float4 q = {q0, q1, q2, q3};
    *(float4*)&outq[(size_t)row * DIM + d0] = q;
    if ((tid & 63) == 0) outidxf[row] = (float)k;
    double s = 0.0, t;
    t = (double)q0 - (double)x.x; s += t * t;
    t = (double)q1 - (double)x.y; s += t * t;
    t = (double)q2 - (double)x.z; s += t * t;
    t = (double)q3 - (double)x.w; s += t * t;
    red[tid] = s;
    __syncthreads();
    for (int st = 128; st > 0; st >>= 1) {
        if (tid < st) red[tid] += red[tid + st];
        __syncthreads();
    }
    if (tid == 0) partials[blockIdx.x] = red[0];
}

// v2: coalesced reads from transposed f32 copy ET32 [8192][256].
__global__ __launch_bounds__(256) void gather2_kernel(
        const float* __restrict__ X, const float* __restrict__ ET32,
        const int* __restrict__ idx,
        float* __restrict__ outq, float* __restrict__ outidxf,
        double* __restrict__ partials) {
    __shared__ double red[256];
    const int tid = threadIdx.x;
    const int row = blockIdx.x * 4 + (tid >> 6);
    const int d0  = (tid & 63) * 4;
    const int k   = idx[row];
    float4 x = *(const float4*)&X[(size_t)row * DIM + d0];
    float4 q = *(const float4*)&ET32[(size_t)k * DIM + d0];   // coalesced row read
    *(float4*)&outq[(size_t)row * DIM + d0] = q;
    if ((tid & 63) == 0) outidxf[row] = (float)k;
    double s = 0.0, t;
    t = (double)q.x - (double)x.x; s += t * t;
    t = (double)q.y - (double)x.y; s += t * t;
    t = (double)q.z - (double)x.z; s += t * t;
    t = (double)q.w - (double)x.w; s += t * t;
    red[tid] = s;
    __syncthreads();
    for (int st = 128; st > 0; st >>= 1) {
        if (tid < st) red[tid] += red[tid + st];
        __syncthreads();
    }
    if (tid == 0) partials[blockIdx.x] = red[0];
}

// ---------------------------------------------------------------------------
// Kernel 9: deterministic final loss reduction.
// ---------------------------------------------------------------------------
__global__ __launch_bounds__(256) void loss_kernel(const double* __restrict__ partials,
                                                   float* __restrict__ outloss) {
    __shared__ double red[256];
    const int tid = threadIdx.x;
    double s = 0.0;
    for (int i = tid; i < N_TOK / 4; i += 256) s += partials[i];
    red[tid] = s;
    __syncthreads();
    for (int st = 128; st > 0; st >>= 1) {
        if (tid < st) red[tid] += red[tid + st];
        __syncthreads();
    }
    if (tid == 0)
        outloss[0] = (float)(0.25 * red[0] / (double)((size_t)N_TOK * DIM));
}

// ---------------------------------------------------------------------------
extern "C" void kernel_launch(void* const* d_in, const int* in_sizes, int n_in,
                              void* d_out, int out_size, void* d_ws, size_t ws_size,
                              hipStream_t stream) {
    const float* X = (const float*)d_in[0];   // [32768, 256]
    const float* E = (const float*)d_in[1];   // [256, 8192]

    float* outq    = (float*)d_out;
    float* outloss = outq + (size_t)N_TOK * DIM;
    float* outidx  = outloss + 1;

    char* base = (char*)d_ws;
    float*  enorm    = (float*)base;                          // 32 KB
    int*    idx1     = (int*)(base + 32768);                  // 128 KB
    int*    idx2     = (int*)(base + 163840);                 // 128 KB
    int*    flag     = (int*)(base + 294912);                 // 128 KB
    double* partials = (double*)(base + 425984);              // 64 KB
    f16*    ET       = (f16*)(base + 524288);                 // 4 MB
    // path B aliases (overlay ET region post-argmin)
    char*   etbase   = base + 524288;
    int*    listB    = (int*)etbase;
    int*    countB   = (int*)(etbase + 131072);
    float*  pm1B     = (float*)(etbase + 132096);
    float*  pm2B     = (float*)(etbase + 132096 + 524288);
    float*  pm3B     = (float*)(etbase + 132096 + 1048576);
    int*    pi1B     = (int*)  (etbase + 132096 + 1572864);
    int*    pi2B     = (int*)  (etbase + 132096 + 2097152);
    // path A extras
    f16*    ETlo     = (f16*)(base + 4718592);                // 4 MB
    int*    listA    = (int*)(base + 8912896);                // 128 KB
    int*    countA   = (int*)(base + 9043968);                // 1 KB
    float*  ET32     = (float*)(base + 9044992);              // 8 MB (optional)
    // path A partial top-3 arrays: scratch in d_out's outq region (32 MB,
    // overwritten by gather afterwards).
    float*  pm1A     = outq;
    float*  pm2A     = outq + 262144;
    float*  pm3A     = outq + 524288;
    int*    pi1A     = (int*)(outq + 786432);
    int*    pi2A     = (int*)(outq + 1048576);
    const size_t NEED_B  = 4718592;
    const size_t NEED_A  = 12190720;
    const size_t NEED_A2 = 9044992 + (size_t)NEMB * DIM * sizeof(float); // 17433600

    enorm_kernel<<<NEMB / 256, 256, 0, stream>>>(E, enorm);
    if (ws_size >= NEED_A) {
        const int wf32 = (ws_size >= NEED_A2) ? 1 : 0;
        cvt3_kernel        <<<512,        256, 0, stream>>>(E, ET, ETlo, ET32, countA, 1, wf32);
        argmin_f16v9_kernel<<<N_TOK / 128, 1024, 0, stream>>>(X, ET, enorm, idx1, idx2, flag,
                                                              listA, countA);
        rescan_split_kernel<<<512 * 8,    512, 0, stream>>>(X, ET, ETlo, enorm, listA, countA,
                                                            pm1A, pm2A, pm3A, pi1A, pi2A);
        merge3_kernel      <<<N_TOK / 256, 256, 0, stream>>>(listA, countA, pm1A, pm2A, pm3A,
                                                             pi1A, pi2A, idx1, idx2, flag);
        refine_kernel<<<N_TOK / 8, 256, 0, stream>>>(X, E, idx1, idx2, flag);
        if (wf32)
            gather2_kernel<<<N_TOK / 4, 256, 0, stream>>>(X, ET32, idx1, outq, outidx, partials);
        else
            gather_kernel <<<N_TOK / 4, 256, 0, stream>>>(X, E, idx1, outq, outidx, partials);
    } else if (ws_size >= NEED_B) {
        cvt3_kernel        <<<512,        256, 0, stream>>>(E, ET, ET, (float*)ET, countB, 0, 0);
        argmin_f16v9_kernel<<<N_TOK / 128, 1024, 0, stream>>>(X, ET, enorm, idx1, idx2, flag,
                                                              listB, countB);
        compact_kernel     <<<1,          256, 0, stream>>>(flag, listB, countB);
        rescan_group_kernel<<<(N_TOK / GROUP) * KSPLIT, 256, 0, stream>>>(X, E, enorm, listB, countB,
                                                                          pm1B, pm2B, pm3B, pi1B, pi2B);
        merge_kernel       <<<N_TOK / 256, 256, 0, stream>>>(listB, countB, pm1B, pm2B, pm3B,
                                                             pi1B, pi2B, idx1, idx2, flag);
        refine_kernel<<<N_TOK / 8, 256, 0, stream>>>(X, E, idx1, idx2, flag);
        gather_kernel<<<N_TOK / 4, 256, 0, stream>>>(X, E, idx1, outq, outidx, partials);
    } else {
        argmin_f32_kernel  <<<N_TOK / BM, 256, 0, stream>>>(X, E, enorm, idx1, idx2, flag);
        refine_kernel<<<N_TOK / 8, 256, 0, stream>>>(X, E, idx1, idx2, flag);
        gather_kernel<<<N_TOK / 4, 256, 0, stream>>>(X, E, idx1, outq, outidx, partials);
    }
    loss_kernel  <<<1,         256, 0, stream>>>(partials, outloss);
}